// Round 3
// baseline (1035.331 us; speedup 1.0000x reference)
//
#include <hip/hip_runtime.h>
#include <math.h>

#define DEV static __device__ __forceinline__

constexpr int NN = 8192;    // nodes
constexpr int NE = 32768;   // edges
constexpr int NB = 32;      // graphs

DEV int lidx_of(int c) { return (c == 0) ? 0 : (c < 4) ? 1 : (c < 9) ? 2 : 3; }

DEV void real_sh_f(float x, float y, float z, float* Y) {
  const float s3  = 1.7320508075688772f;
  const float s5  = 2.23606797749979f;
  const float s15 = 3.872983346207417f;
  Y[0] = 1.f;
  Y[1] = s3 * y;  Y[2] = s3 * z;  Y[3] = s3 * x;
  Y[4] = s15 * x * y;
  Y[5] = s15 * y * z;
  Y[6] = 0.5f * s5 * (3.f * z * z - 1.f);
  Y[7] = s15 * x * z;
  Y[8] = 0.5f * s15 * (x * x - y * y);
  Y[9]  = 2.091650066335189f * y * (3.f * x * x - y * y);
  Y[10] = 10.246950765959598f * x * y * z;
  Y[11] = 1.6201851746019651f * y * (5.f * z * z - 1.f);
  Y[12] = 1.3228756555322954f * (5.f * z * z * z - 3.f * z);
  Y[13] = 1.6201851746019651f * x * (5.f * z * z - 1.f);
  Y[14] = 5.123475382979799f * (x * x - y * y) * z;
  Y[15] = 2.091650066335189f * x * (x * x - 3.f * y * y);
}

// ---------------- edge geometry: Y, u, cut + degree histogram ----------------
__global__ __launch_bounds__(256) void k_edge_prep(
    const float* __restrict__ pos, const int* __restrict__ esrc,
    const int* __restrict__ edst, float* __restrict__ u_, float* __restrict__ cut_,
    float* __restrict__ Y_, int* __restrict__ cnt) {
  const int e = blockIdx.x * 256 + threadIdx.x;
  if (e >= NE) return;
  const int s = esrc[e], t = edst[e];
  const float ex = pos[t * 3 + 0] - pos[s * 3 + 0];
  const float ey = pos[t * 3 + 1] - pos[s * 3 + 1];
  const float ez = pos[t * 3 + 2] - pos[s * 3 + 2];
  const float d = sqrtf(ex * ex + ey * ey + ez * ez) + 1e-9f;
  const float inv = 1.f / d;
  float Y[16];
  real_sh_f(ex * inv, ey * inv, ez * inv, Y);
#pragma unroll
  for (int c = 0; c < 16; ++c) Y_[(size_t)e * 16 + c] = Y[c];
  const float u = d / 3.5f;
  u_[e] = u;
  cut_[e] = (u < 1.f) ? 0.5f * (cosf(3.14159265358979323846f * u) + 1.f) : 0.f;
  atomicAdd(&cnt[t], 1);
}

// ---------------- CSR build: scan + fill ----------------
__global__ __launch_bounds__(256) void k_scan(const int* __restrict__ cnt,
                                              int* __restrict__ offs,
                                              int* __restrict__ cursor) {
  __shared__ int part[256];
  const int t = threadIdx.x;
  int s = 0;
  for (int i = 0; i < 32; ++i) s += cnt[t * 32 + i];
  part[t] = s;
  __syncthreads();
  if (t == 0) {
    int run = 0;
    for (int i = 0; i < 256; ++i) { int v = part[i]; part[i] = run; run += v; }
    offs[NN] = run;
  }
  __syncthreads();
  int run = part[t];
  for (int i = 0; i < 32; ++i) {
    const int idx = t * 32 + i;
    offs[idx] = run;
    cursor[idx] = run;
    run += cnt[idx];
  }
}

__global__ __launch_bounds__(256) void k_fill(const int* __restrict__ edst,
                                              int* __restrict__ cursor,
                                              int* __restrict__ elist) {
  const int e = blockIdx.x * 256 + threadIdx.x;
  if (e < NE) {
    const int p = atomicAdd(&cursor[edst[e]], 1);
    elist[p] = e;
  }
}

// ---------------- per-edge bilinear GEMM: t[e][128] (and optional self[e][128]) ----
template <bool IS2>
__global__ __launch_bounds__(256) void k_msg(
    const float* __restrict__ u_, const float* __restrict__ cut_,
    const float* __restrict__ W1, const float* __restrict__ bvec,
    const float* __restrict__ W2, const float* __restrict__ feat16,
    const int* __restrict__ esrc, float* __restrict__ t_, float* __restrict__ self_) {
  __shared__ __align__(16) float hhL[64][65];
  __shared__ __align__(16) float nfL[64][17];
  __shared__ __align__(16) float BL[64][128];
  __shared__ float uL[64], cL[64];
  __shared__ int sL[64];
  const int tid = threadIdx.x;
  const int e0 = blockIdx.x * 64;
  if (tid < 64) {
    uL[tid] = u_[e0 + tid];
    cL[tid] = cut_[e0 + tid];
    sL[tid] = esrc[e0 + tid];
  }
  __syncthreads();
  for (int i = tid; i < 64 * 64; i += 256) {
    const int e = i >> 6, k = i & 63;
    hhL[e][k] = fmaxf(fmaf(uL[e], W1[k], bvec[k]), 0.f) * cL[e];
  }
  for (int i = tid; i < 64 * 16; i += 256) {
    const int e = i >> 4, f = i & 15;
    nfL[e][f] = feat16[(size_t)sL[e] * 16 + f];
  }
  const int ty = tid >> 4, tx = tid & 15;
  float acc[4][8];
#pragma unroll
  for (int a = 0; a < 4; ++a)
#pragma unroll
    for (int o = 0; o < 8; ++o) acc[a][o] = 0.f;

  for (int ch = 0; ch < 16; ++ch) {
    __syncthreads();
#pragma unroll
    for (int j = 0; j < 8; ++j) {
      const int q = tid + j * 256;
      const int row = q >> 5, c4 = (q & 31) << 2;
      const int kf = ch * 64 + row;
      size_t gaddr;
      if (IS2) gaddr = (size_t)(kf >> 4) * 2176 + (size_t)(kf & 15) * 128 + c4;
      else     gaddr = (size_t)kf * 128 + c4;
      *(float4*)&BL[row][c4] = *(const float4*)(W2 + gaddr);
    }
    __syncthreads();
#pragma unroll
    for (int kk = 0; kk < 4; ++kk) {
      const int k = ch * 4 + kk;
      float ha[4];
#pragma unroll
      for (int a = 0; a < 4; ++a) ha[a] = hhL[ty * 4 + a][k];
#pragma unroll
      for (int f = 0; f < 16; ++f) {
        float av[4];
#pragma unroll
        for (int a = 0; a < 4; ++a) av[a] = ha[a] * nfL[ty * 4 + a][f];
        const float* Br = &BL[kk * 16 + f][tx * 8];
#pragma unroll
        for (int o = 0; o < 8; ++o) {
          const float bv = Br[o];
#pragma unroll
          for (int a = 0; a < 4; ++a) acc[a][o] = fmaf(av[a], bv, acc[a][o]);
        }
      }
    }
  }
#pragma unroll
  for (int a = 0; a < 4; ++a) {
    float* op = &t_[(size_t)(e0 + ty * 4 + a) * 128 + tx * 8];
#pragma unroll
    for (int o = 0; o < 8; ++o) op[o] = acc[a][o] * 0.125f;  // 1/sqrt(F)/deg
  }

  if (IS2) {
    __syncthreads();
#pragma unroll
    for (int j = 0; j < 8; ++j) {
      const int q = tid + j * 256;
      const int row = q >> 5, c4 = (q & 31) << 2;
      *(float4*)&BL[row][c4] = *(const float4*)(W2 + (size_t)row * 2176 + 2048 + c4);
    }
    __syncthreads();
    float sacc[4][8];
#pragma unroll
    for (int a = 0; a < 4; ++a)
#pragma unroll
      for (int o = 0; o < 8; ++o) sacc[a][o] = 0.f;
    for (int k = 0; k < 64; ++k) {
      float ha[4];
#pragma unroll
      for (int a = 0; a < 4; ++a) ha[a] = hhL[ty * 4 + a][k];
      const float* Br = &BL[k][tx * 8];
#pragma unroll
      for (int o = 0; o < 8; ++o) {
        const float bv = Br[o];
#pragma unroll
        for (int a = 0; a < 4; ++a) sacc[a][o] = fmaf(ha[a], bv, sacc[a][o]);
      }
    }
#pragma unroll
    for (int a = 0; a < 4; ++a) {
      float* op = &self_[(size_t)(e0 + ty * 4 + a) * 128 + tx * 8];
#pragma unroll
      for (int o = 0; o < 8; ++o) op[o] = sacc[a][o] * 0.5f;  // 1/deg
    }
  }
}

// ---------------- gather (segment sum over incoming edges) + gate ----------------
__global__ __launch_bounds__(256) void k_gather1(
    const float* __restrict__ t_, const float* __restrict__ Y_,
    const int* __restrict__ offs, const int* __restrict__ elist,
    float* __restrict__ h1, float* __restrict__ h1s) {
  __shared__ float tL[128], YL[16], sG[32];
  const int n = blockIdx.x, tid = threadIdx.x;
  const int beg = offs[n], end = offs[n + 1];
  const int cc = tid & 15;
  const int lx = lidx_of(cc);
  const int o0 = ((tid >> 4) << 2) + lx;
  const int o1 = o0 + 64;
  float a0 = 0.f, a1 = 0.f;
  for (int ei = beg; ei < end; ++ei) {
    const int e = elist[ei];
    __syncthreads();
    if (tid < 128) tL[tid] = t_[(size_t)e * 128 + tid];
    else if (tid < 144) YL[tid - 128] = Y_[(size_t)e * 16 + tid - 128];
    __syncthreads();
    const float yv = YL[cc];
    a0 = fmaf(tL[o0], yv, a0);
    a1 = fmaf(tL[o1], yv, a1);
  }
  if (cc == 0) { sG[tid >> 4] = a0; sG[(tid >> 4) + 16] = a1; }
  __syncthreads();
  const float s0 = sG[tid >> 4], s1 = sG[(tid >> 4) + 16];
  const float r0 = (cc == 0) ? fmaxf(a0, 0.f) : a0 * (1.f / (1.f + expf(-s0)));
  const float r1 = (cc == 0) ? fmaxf(a1, 0.f) : a1 * (1.f / (1.f + expf(-s1)));
  h1[(size_t)n * 512 + tid] = r0;
  h1[(size_t)n * 512 + tid + 256] = r1;
  if ((tid & 31) == 0) {
    h1s[n * 16 + (tid >> 5)] = r0;       // g = 0..7  (p=0,c=0)
    h1s[n * 16 + (tid >> 5) + 8] = r1;   // g = 8..15
  }
}

__global__ __launch_bounds__(256) void k_gather2(
    const float* __restrict__ t_, const float* __restrict__ self_,
    const float* __restrict__ Y_, const float* __restrict__ h1,
    const int* __restrict__ offs, const int* __restrict__ elist,
    const int* __restrict__ esrc, float* __restrict__ h2) {
  __shared__ float tL[128], wL[128], YL[16], sG[32];
  const int n = blockIdx.x, tid = threadIdx.x;
  const int beg = offs[n], end = offs[n + 1];
  const int cc = tid & 15;
  const int lx = lidx_of(cc);
  const int o0 = ((tid >> 4) << 2) + lx;
  const int o1 = o0 + 64;
  float a0 = 0.f, a1 = 0.f;
  for (int ei = beg; ei < end; ++ei) {
    const int e = elist[ei];
    __syncthreads();
    if (tid < 128) tL[tid] = t_[(size_t)e * 128 + tid];
    else wL[tid - 128] = self_[(size_t)e * 128 + tid - 128];
    if (tid < 16) YL[tid] = Y_[(size_t)e * 16 + tid];
    __syncthreads();
    const int src = esrc[e];
    const float* hr = &h1[(size_t)src * 512];
    const float yv = YL[cc];
    a0 += tL[o0] * yv + hr[tid] * wL[o0];
    a1 += tL[o1] * yv + hr[tid + 256] * wL[o1];
  }
  if (cc == 0) { sG[tid >> 4] = a0; sG[(tid >> 4) + 16] = a1; }
  __syncthreads();
  const float s0 = sG[tid >> 4], s1 = sG[(tid >> 4) + 16];
  const float r0 = (cc == 0) ? fmaxf(a0, 0.f) : a0 * (1.f / (1.f + expf(-s0)));
  const float r1 = (cc == 0) ? fmaxf(a1, 0.f) : a1 * (1.f / (1.f + expf(-s1)));
  h2[(size_t)n * 512 + tid] = r0;
  h2[(size_t)n * 512 + tid + 256] = r1;
}

// ---------------- mean pool over each graph's 256 nodes ----------------
__global__ __launch_bounds__(256) void k_pool(const float* __restrict__ h2,
                                              float* __restrict__ enc) {
  const int b = blockIdx.x, tid = threadIdx.x;
  float a0 = 0.f, a1 = 0.f;
  for (int i = 0; i < 256; ++i) {
    const float* row = &h2[(size_t)(b * 256 + i) * 512];
    a0 += row[tid];
    a1 += row[tid + 256];
  }
  enc[b * 512 + tid] = a0 * (1.f / 256.f);
  enc[b * 512 + tid + 256] = a1 * (1.f / 256.f);
}

// ---------------- z = per-l linear mix of enc (B,32,16) -> (B,16,84) ----------------
__global__ __launch_bounds__(256) void k_zproj(const float* __restrict__ enc,
                                               const float* __restrict__ Wlin,
                                               float* __restrict__ z) {
  __shared__ float eL[512];
  const int b = blockIdx.x, tid = threadIdx.x;
  eL[tid] = enc[b * 512 + tid];
  eL[tid + 256] = enc[b * 512 + tid + 256];
  __syncthreads();
  for (int idx = tid; idx < 16 * 84; idx += 256) {
    const int g = idx / 84, d3 = idx % 84;
    int o0, m0, mo;
    if (d3 < 1)       { o0 = 0;  m0 = 1; mo = 0; }
    else if (d3 < 10) { o0 = 1;  m0 = 3; mo = 1; }
    else if (d3 < 35) { o0 = 10; m0 = 5; mo = 4; }
    else              { o0 = 35; m0 = 7; mo = 9; }
    const int rem = d3 - o0;
    const int jj = rem / m0;
    const int cc2 = rem - jj * m0;
    float a = 0.f;
    for (int mu = 0; mu < 32; ++mu)
      a = fmaf(eL[mu * 16 + mo + cc2], Wlin[(mu * 16 + g) * 16 + mo + jj], a);
    z[(size_t)(b * 16 + g) * 84 + d3] = a * 0.17677669529663687f;  // 1/sqrt(32)
  }
}

// ---------------- SO3 conv: per-l matmul ----------------
template <int M, int FI, int FO>
DEV void conv_item(const float* xL, const float* __restrict__ psi, int b, int g,
                   int o0, int j, float* __restrict__ out, float scale) {
  float acc[M];
#pragma unroll
  for (int c = 0; c < M; ++c) acc[c] = 0.f;
  for (int f = 0; f < FI; ++f) {
    const float* xr = &xL[f * 84 + o0];
    const float* pr = &psi[((size_t)f * FO + g) * 84 + o0 + j];
#pragma unroll
    for (int i = 0; i < M; ++i) {
      const float pv = pr[i * M];
#pragma unroll
      for (int c = 0; c < M; ++c) acc[c] = fmaf(xr[i * M + c], pv, acc[c]);
    }
  }
  float* op = &out[((size_t)b * FO + g) * 84 + o0 + j * M];
#pragma unroll
  for (int c = 0; c < M; ++c) op[c] = acc[c] * scale;
}

template <int FI, int FO>
__global__ __launch_bounds__(256) void k_conv(const float* __restrict__ x,
                                              const float* __restrict__ psi,
                                              float* __restrict__ out) {
  __shared__ float xL[FI * 84];
  const int tid = threadIdx.x, b = blockIdx.x;
  for (int i = tid; i < FI * 84; i += 256) xL[i] = x[(size_t)b * FI * 84 + i];
  __syncthreads();
  const int g0 = blockIdx.y * 16;
  if (tid < 16) {
    conv_item<1, FI, FO>(xL, psi, b, g0 + tid, 0, 0, out, 1.f / sqrtf((float)(FI * 1)));
  } else if (tid < 64) {
    const int q = tid - 16;
    conv_item<3, FI, FO>(xL, psi, b, g0 + q / 3, 1, q % 3, out, 1.f / sqrtf((float)(FI * 3)));
  } else if (tid < 144) {
    const int q = tid - 64;
    conv_item<5, FI, FO>(xL, psi, b, g0 + q / 5, 10, q % 5, out, 1.f / sqrtf((float)(FI * 5)));
  } else {
    const int q = tid - 144;
    conv_item<7, FI, FO>(xL, psi, b, g0 + q / 7, 35, q % 7, out, 1.f / sqrtf((float)(FI * 7)));
  }
}

// ---------------- SO3 act (fused, partial over g-splits), RB=16 ----------------
// phase1: 256 threads, chunk of 512 g-cols, thread owns cols (tid, tid+256): fa[16][2]
// phase2: 8 groups x 32 lanes; group owns 64 g of the chunk; acc[16][3]
// reduce: shfl_xor(32) wave-pair combine -> 4-wave LDS tree
template <int GSPLIT>
__global__ __launch_bounds__(256) void k_act_part(
    const float* __restrict__ x, const float* __restrict__ Gt,
    const float* __restrict__ Gf, float* __restrict__ part,
    float* __restrict__ outp) {
  constexpr int RB = 16;
  constexpr int NCHUNK = 8 / GSPLIT;  // chunks of 512 g-cols
  __shared__ float sm[16 * 84 + 16 * 516];  // 9600 floats = 38.4 KB
  float* yL = sm;          // [16][84]
  float* gch = sm + 1344;  // [16][516]
  const int tid = threadIdx.x;
  const int gs = blockIdx.y;
  const int row0 = blockIdx.x * RB;
  const int nrows = gridDim.x * RB;

  for (int i = tid; i < RB * 84; i += 256) yL[i] = x[(size_t)row0 * 84 + i];

  const int gp = tid >> 5, j = tid & 31;
  float acc[RB][3];
#pragma unroll
  for (int r = 0; r < RB; ++r) { acc[r][0] = 0.f; acc[r][1] = 0.f; acc[r][2] = 0.f; }
  __syncthreads();

  for (int cc = gs * NCHUNK; cc < (gs + 1) * NCHUNK; ++cc) {
    const int g0 = cc * 512;
    // ---- phase 1: fa[r][2] = x rows @ Gt cols (g0+tid, g0+256+tid)
    float fa[RB][2];
#pragma unroll
    for (int r = 0; r < RB; ++r) { fa[r][0] = 0.f; fa[r][1] = 0.f; }
    for (int dq = 0; dq < 21; ++dq) {
      float gt0[4], gt1[4];
#pragma unroll
      for (int i = 0; i < 4; ++i) {
        const size_t db = (size_t)(dq * 4 + i) * 4096 + g0 + tid;
        gt0[i] = Gt[db];
        gt1[i] = Gt[db + 256];
      }
#pragma unroll
      for (int r = 0; r < RB; ++r) {
        const float4 y4 = *(const float4*)&yL[r * 84 + dq * 4];
        fa[r][0] = fmaf(y4.x, gt0[0], fa[r][0]);
        fa[r][0] = fmaf(y4.y, gt0[1], fa[r][0]);
        fa[r][0] = fmaf(y4.z, gt0[2], fa[r][0]);
        fa[r][0] = fmaf(y4.w, gt0[3], fa[r][0]);
        fa[r][1] = fmaf(y4.x, gt1[0], fa[r][1]);
        fa[r][1] = fmaf(y4.y, gt1[1], fa[r][1]);
        fa[r][1] = fmaf(y4.z, gt1[2], fa[r][1]);
        fa[r][1] = fmaf(y4.w, gt1[3], fa[r][1]);
      }
    }
    __syncthreads();  // previous phase2 done reading gch
#pragma unroll
    for (int r = 0; r < RB; ++r) {
      gch[r * 516 + tid] = fmaxf(fa[r][0], 0.f);
      gch[r * 516 + tid + 256] = fmaxf(fa[r][1], 0.f);
    }
    __syncthreads();
    // ---- phase 2: group gp owns g in [gp*64, gp*64+64)
    for (int q = 0; q < 16; ++q) {
      const int g2 = gp * 64 + q * 4;
      float gf[4][3];
#pragma unroll
      for (int i = 0; i < 4; ++i) {
        const size_t gidx = (size_t)(g0 + g2 + i) * 84;
        gf[i][0] = Gf[gidx + j];
        gf[i][1] = Gf[gidx + 32 + j];
        gf[i][2] = (j < 20) ? Gf[gidx + 64 + j] : 0.f;
      }
#pragma unroll
      for (int r = 0; r < RB; ++r) {
        const float4 p4 = *(const float4*)&gch[r * 516 + g2];
        acc[r][0] = fmaf(p4.x, gf[0][0], acc[r][0]);
        acc[r][1] = fmaf(p4.x, gf[0][1], acc[r][1]);
        acc[r][2] = fmaf(p4.x, gf[0][2], acc[r][2]);
        acc[r][0] = fmaf(p4.y, gf[1][0], acc[r][0]);
        acc[r][1] = fmaf(p4.y, gf[1][1], acc[r][1]);
        acc[r][2] = fmaf(p4.y, gf[1][2], acc[r][2]);
        acc[r][0] = fmaf(p4.z, gf[2][0], acc[r][0]);
        acc[r][1] = fmaf(p4.z, gf[2][1], acc[r][1]);
        acc[r][2] = fmaf(p4.z, gf[2][2], acc[r][2]);
        acc[r][0] = fmaf(p4.w, gf[3][0], acc[r][0]);
        acc[r][1] = fmaf(p4.w, gf[3][1], acc[r][1]);
        acc[r][2] = fmaf(p4.w, gf[3][2], acc[r][2]);
      }
    }
  }
  // ---- reduce: combine group pairs within each wave via shfl_xor(32)
  __syncthreads();  // all phase2 reads of gch done; sm reusable
  const int w = tid >> 6;  // wave id 0..3
#pragma unroll
  for (int r = 0; r < RB; ++r)
#pragma unroll
    for (int c = 0; c < 3; ++c) {
      const float v = acc[r][c] + __shfl_xor(acc[r][c], 32, 64);
      if ((tid & 63) < 32) sm[((w * RB + r) * 32 + j) * 3 + c] = v;
    }
  __syncthreads();
  const float SC = 1.f / (9.16515138991168f * 64.f);  // 1/(sqrt(84)*64)
  for (int o = tid; o < RB * 84; o += 256) {
    const int r = o / 84, d = o % 84;
    const int jj = d & 31, c = d >> 5;
    float s = 0.f;
#pragma unroll
    for (int ww = 0; ww < 4; ++ww) s += sm[((ww * RB + r) * 32 + jj) * 3 + c];
    if (GSPLIT == 1) outp[((size_t)row0 + r) * 84 + d] = s * SC;
    else part[((size_t)gs * nrows + row0 + r) * 84 + d] = s;
  }
}

template <int GSPLIT>
__global__ __launch_bounds__(256) void k_act_reduce(const float* __restrict__ part,
                                                    float* __restrict__ out, int total) {
  const int i = blockIdx.x * 256 + threadIdx.x;
  if (i < total) {
    float s = part[i];
#pragma unroll
    for (int g = 1; g < GSPLIT; ++g) s += part[(size_t)g * total + i];
    out[i] = s * (1.f / (9.16515138991168f * 64.f));
  }
}

// ---------------- final: Ws2 contraction + orientation SH dot ----------------
__global__ __launch_bounds__(256) void k_final(const float* __restrict__ x,
                                               const float* __restrict__ Ws2,
                                               const float* __restrict__ orient,
                                               float* __restrict__ outp) {
  __shared__ float red[256][16];
  const int b = blockIdx.x, tid = threadIdx.x;
  const float* xr = &x[(size_t)(b * 256 + tid) * 84];
  const float* wr = &Ws2[tid * 16];
  float acc[16];
#pragma unroll
  for (int c = 0; c < 16; ++c) acc[c] = 0.f;
  acc[0] = fmaf(xr[0], wr[0], acc[0]);
#pragma unroll
  for (int i = 0; i < 3; ++i) {
    const float w = wr[1 + i];
#pragma unroll
    for (int c = 0; c < 3; ++c) acc[1 + c] = fmaf(xr[1 + i * 3 + c], w, acc[1 + c]);
  }
#pragma unroll
  for (int i = 0; i < 5; ++i) {
    const float w = wr[4 + i];
#pragma unroll
    for (int c = 0; c < 5; ++c) acc[4 + c] = fmaf(xr[10 + i * 5 + c], w, acc[4 + c]);
  }
#pragma unroll
  for (int i = 0; i < 7; ++i) {
    const float w = wr[9 + i];
#pragma unroll
    for (int c = 0; c < 7; ++c) acc[9 + c] = fmaf(xr[35 + i * 7 + c], w, acc[9 + c]);
  }
#pragma unroll
  for (int c = 0; c < 16; ++c) red[tid][c] = acc[c];
  __syncthreads();
  for (int off = 128; off > 0; off >>= 1) {
    if (tid < off)
#pragma unroll
      for (int c = 0; c < 16; ++c) red[tid][c] += red[tid + off][c];
    __syncthreads();
  }
  if (tid == 0) {
    const float aa = orient[b * 2 + 0], rr = orient[b * 2 + 1];
    float Y[16];
    real_sh_f(-sinf(aa) * cosf(rr), -sinf(aa) * sinf(rr), -cosf(aa), Y);
    const float sc1 = 1.f / 16.f;
    const float sc3 = 1.f / (16.f * 1.7320508075688772f);
    const float sc5 = 1.f / (16.f * 2.23606797749979f);
    const float sc7 = 1.f / (16.f * 2.6457513110645907f);
    float o = red[0][0] * sc1 * Y[0];
#pragma unroll
    for (int c = 1; c < 4; ++c) o += red[0][c] * sc3 * Y[c];
#pragma unroll
    for (int c = 4; c < 9; ++c) o += red[0][c] * sc5 * Y[c];
#pragma unroll
    for (int c = 9; c < 16; ++c) o += red[0][c] * sc7 * Y[c];
    outp[b] = o;
  }
}

extern "C" void kernel_launch(void* const* d_in, const int* in_sizes, int n_in,
                              void* d_out, int out_size, void* d_ws, size_t ws_size,
                              hipStream_t stream) {
  const float* node_feat = (const float*)d_in[0];
  const float* pos       = (const float*)d_in[1];
  const float* orient    = (const float*)d_in[2];
  const float* rad1_W1   = (const float*)d_in[3];
  const float* rad1_b    = (const float*)d_in[4];
  const float* rad1_W2   = (const float*)d_in[5];
  const float* rad2_W1   = (const float*)d_in[6];
  const float* rad2_b    = (const float*)d_in[7];
  const float* rad2_W2   = (const float*)d_in[8];
  const float* Wlin      = (const float*)d_in[9];
  const float* psi1      = (const float*)d_in[10];
  const float* psi2      = (const float*)d_in[11];
  const float* psi3      = (const float*)d_in[12];
  const float* G_to      = (const float*)d_in[13];
  const float* G_from    = (const float*)d_in[14];
  const float* Ws2       = (const float*)d_in[15];
  const int*   esrc      = (const int*)d_in[16];
  const int*   edst      = (const int*)d_in[17];

  float* w = (float*)d_ws;
  size_t off = 0;
  float* u_    = w + off; off += NE;
  float* cut_  = w + off; off += NE;
  float* Y_    = w + off; off += (size_t)NE * 16;
  float* t_    = w + off; off += (size_t)NE * 128;   // t1, then reused for t2
  float* self_ = w + off; off += (size_t)NE * 128;   // also reused as act partials
  float* h1    = w + off; off += (size_t)NN * 512;
  float* h1s   = w + off; off += (size_t)NN * 16;
  float* h2    = w + off; off += (size_t)NN * 512;
  float* enc   = w + off; off += (size_t)NB * 512;
  float* z     = w + off; off += (size_t)NB * 16 * 84;
  float* xb1   = w + off; off += (size_t)NB * 256 * 84;
  float* xb2   = w + off; off += (size_t)NB * 256 * 84;
  int* cnt    = (int*)(w + off); off += NN;
  int* offs   = (int*)(w + off); off += NN + 1;
  int* cursor = (int*)(w + off); off += NN;
  int* elist  = (int*)(w + off); off += NE;

  float* part = self_;  // dead after k_gather2

  hipMemsetAsync(cnt, 0, NN * sizeof(int), stream);
  k_edge_prep<<<NE / 256, 256, 0, stream>>>(pos, esrc, edst, u_, cut_, Y_, cnt);
  k_scan<<<1, 256, 0, stream>>>(cnt, offs, cursor);
  k_fill<<<NE / 256, 256, 0, stream>>>(edst, cursor, elist);
  k_msg<false><<<NE / 64, 256, 0, stream>>>(u_, cut_, rad1_W1, rad1_b, rad1_W2,
                                            node_feat, esrc, t_, nullptr);
  k_gather1<<<NN, 256, 0, stream>>>(t_, Y_, offs, elist, h1, h1s);
  k_msg<true><<<NE / 64, 256, 0, stream>>>(u_, cut_, rad2_W1, rad2_b, rad2_W2,
                                           h1s, esrc, t_, self_);
  k_gather2<<<NN, 256, 0, stream>>>(t_, self_, Y_, h1, offs, elist, esrc, h2);
  k_pool<<<NB, 256, 0, stream>>>(h2, enc);
  k_zproj<<<NB, 256, 0, stream>>>(enc, Wlin, z);

  k_conv<16, 64><<<dim3(NB, 4), 256, 0, stream>>>(z, psi1, xb1);
  k_act_part<4><<<dim3(2048 / 16, 4), 256, 0, stream>>>(xb1, G_to, G_from, part, nullptr);
  k_act_reduce<4><<<(2048 * 84 + 255) / 256, 256, 0, stream>>>(part, xb2, 2048 * 84);

  k_conv<64, 128><<<dim3(NB, 8), 256, 0, stream>>>(xb2, psi2, xb1);
  k_act_part<2><<<dim3(4096 / 16, 2), 256, 0, stream>>>(xb1, G_to, G_from, part, nullptr);
  k_act_reduce<2><<<(4096 * 84 + 255) / 256, 256, 0, stream>>>(part, xb2, 4096 * 84);

  k_conv<128, 256><<<dim3(NB, 16), 256, 0, stream>>>(xb2, psi3, xb1);
  k_act_part<1><<<dim3(8192 / 16, 1), 256, 0, stream>>>(xb1, G_to, G_from, nullptr, xb2);

  k_final<<<NB, 256, 0, stream>>>(xb2, Ws2, orient, (float*)d_out);
}

// Round 4
// 918.418 us; speedup vs baseline: 1.1273x; 1.1273x over previous
//
#include <hip/hip_runtime.h>
#include <math.h>

#define DEV static __device__ __forceinline__

constexpr int NN = 8192;    // nodes
constexpr int NE = 32768;   // edges
constexpr int NB = 32;      // graphs

DEV int lidx_of(int c) { return (c == 0) ? 0 : (c < 4) ? 1 : (c < 9) ? 2 : 3; }

DEV void real_sh_f(float x, float y, float z, float* Y) {
  const float s3  = 1.7320508075688772f;
  const float s5  = 2.23606797749979f;
  const float s15 = 3.872983346207417f;
  Y[0] = 1.f;
  Y[1] = s3 * y;  Y[2] = s3 * z;  Y[3] = s3 * x;
  Y[4] = s15 * x * y;
  Y[5] = s15 * y * z;
  Y[6] = 0.5f * s5 * (3.f * z * z - 1.f);
  Y[7] = s15 * x * z;
  Y[8] = 0.5f * s15 * (x * x - y * y);
  Y[9]  = 2.091650066335189f * y * (3.f * x * x - y * y);
  Y[10] = 10.246950765959598f * x * y * z;
  Y[11] = 1.6201851746019651f * y * (5.f * z * z - 1.f);
  Y[12] = 1.3228756555322954f * (5.f * z * z * z - 3.f * z);
  Y[13] = 1.6201851746019651f * x * (5.f * z * z - 1.f);
  Y[14] = 5.123475382979799f * (x * x - y * y) * z;
  Y[15] = 2.091650066335189f * x * (x * x - 3.f * y * y);
}

// ---------------- edge geometry: Y, u, cut + degree histogram ----------------
__global__ __launch_bounds__(256) void k_edge_prep(
    const float* __restrict__ pos, const int* __restrict__ esrc,
    const int* __restrict__ edst, float* __restrict__ u_, float* __restrict__ cut_,
    float* __restrict__ Y_, int* __restrict__ cnt) {
  const int e = blockIdx.x * 256 + threadIdx.x;
  if (e >= NE) return;
  const int s = esrc[e], t = edst[e];
  const float ex = pos[t * 3 + 0] - pos[s * 3 + 0];
  const float ey = pos[t * 3 + 1] - pos[s * 3 + 1];
  const float ez = pos[t * 3 + 2] - pos[s * 3 + 2];
  const float d = sqrtf(ex * ex + ey * ey + ez * ez) + 1e-9f;
  const float inv = 1.f / d;
  float Y[16];
  real_sh_f(ex * inv, ey * inv, ez * inv, Y);
#pragma unroll
  for (int c = 0; c < 16; ++c) Y_[(size_t)e * 16 + c] = Y[c];
  const float u = d / 3.5f;
  u_[e] = u;
  cut_[e] = (u < 1.f) ? 0.5f * (cosf(3.14159265358979323846f * u) + 1.f) : 0.f;
  atomicAdd(&cnt[t], 1);
}

// ---------------- CSR build: scan + fill ----------------
__global__ __launch_bounds__(256) void k_scan(const int* __restrict__ cnt,
                                              int* __restrict__ offs,
                                              int* __restrict__ cursor) {
  __shared__ int part[256];
  const int t = threadIdx.x;
  int s = 0;
  for (int i = 0; i < 32; ++i) s += cnt[t * 32 + i];
  part[t] = s;
  __syncthreads();
  if (t == 0) {
    int run = 0;
    for (int i = 0; i < 256; ++i) { int v = part[i]; part[i] = run; run += v; }
    offs[NN] = run;
  }
  __syncthreads();
  int run = part[t];
  for (int i = 0; i < 32; ++i) {
    const int idx = t * 32 + i;
    offs[idx] = run;
    cursor[idx] = run;
    run += cnt[idx];
  }
}

__global__ __launch_bounds__(256) void k_fill(const int* __restrict__ edst,
                                              int* __restrict__ cursor,
                                              int* __restrict__ elist) {
  const int e = blockIdx.x * 256 + threadIdx.x;
  if (e < NE) {
    const int p = atomicAdd(&cursor[edst[e]], 1);
    elist[p] = e;
  }
}

// ---------------- per-edge bilinear GEMM: t[e][128] (and optional self[e][128]) ----
template <bool IS2>
__global__ __launch_bounds__(256) void k_msg(
    const float* __restrict__ u_, const float* __restrict__ cut_,
    const float* __restrict__ W1, const float* __restrict__ bvec,
    const float* __restrict__ W2, const float* __restrict__ feat16,
    const int* __restrict__ esrc, float* __restrict__ t_, float* __restrict__ self_) {
  __shared__ __align__(16) float hhL[64][65];
  __shared__ __align__(16) float nfL[64][17];
  __shared__ __align__(16) float BL[64][128];
  __shared__ float uL[64], cL[64];
  __shared__ int sL[64];
  const int tid = threadIdx.x;
  const int e0 = blockIdx.x * 64;
  if (tid < 64) {
    uL[tid] = u_[e0 + tid];
    cL[tid] = cut_[e0 + tid];
    sL[tid] = esrc[e0 + tid];
  }
  __syncthreads();
  for (int i = tid; i < 64 * 64; i += 256) {
    const int e = i >> 6, k = i & 63;
    hhL[e][k] = fmaxf(fmaf(uL[e], W1[k], bvec[k]), 0.f) * cL[e];
  }
  for (int i = tid; i < 64 * 16; i += 256) {
    const int e = i >> 4, f = i & 15;
    nfL[e][f] = feat16[(size_t)sL[e] * 16 + f];
  }
  const int ty = tid >> 4, tx = tid & 15;
  float acc[4][8];
#pragma unroll
  for (int a = 0; a < 4; ++a)
#pragma unroll
    for (int o = 0; o < 8; ++o) acc[a][o] = 0.f;

  for (int ch = 0; ch < 16; ++ch) {
    __syncthreads();
#pragma unroll
    for (int j = 0; j < 8; ++j) {
      const int q = tid + j * 256;
      const int row = q >> 5, c4 = (q & 31) << 2;
      const int kf = ch * 64 + row;
      size_t gaddr;
      if (IS2) gaddr = (size_t)(kf >> 4) * 2176 + (size_t)(kf & 15) * 128 + c4;
      else     gaddr = (size_t)kf * 128 + c4;
      *(float4*)&BL[row][c4] = *(const float4*)(W2 + gaddr);
    }
    __syncthreads();
#pragma unroll
    for (int kk = 0; kk < 4; ++kk) {
      const int k = ch * 4 + kk;
      float ha[4];
#pragma unroll
      for (int a = 0; a < 4; ++a) ha[a] = hhL[ty * 4 + a][k];
#pragma unroll
      for (int f = 0; f < 16; ++f) {
        float av[4];
#pragma unroll
        for (int a = 0; a < 4; ++a) av[a] = ha[a] * nfL[ty * 4 + a][f];
        const float* Br = &BL[kk * 16 + f][tx * 8];
#pragma unroll
        for (int o = 0; o < 8; ++o) {
          const float bv = Br[o];
#pragma unroll
          for (int a = 0; a < 4; ++a) acc[a][o] = fmaf(av[a], bv, acc[a][o]);
        }
      }
    }
  }
#pragma unroll
  for (int a = 0; a < 4; ++a) {
    float* op = &t_[(size_t)(e0 + ty * 4 + a) * 128 + tx * 8];
#pragma unroll
    for (int o = 0; o < 8; ++o) op[o] = acc[a][o] * 0.125f;  // 1/sqrt(F)/deg
  }

  if (IS2) {
    __syncthreads();
#pragma unroll
    for (int j = 0; j < 8; ++j) {
      const int q = tid + j * 256;
      const int row = q >> 5, c4 = (q & 31) << 2;
      *(float4*)&BL[row][c4] = *(const float4*)(W2 + (size_t)row * 2176 + 2048 + c4);
    }
    __syncthreads();
    float sacc[4][8];
#pragma unroll
    for (int a = 0; a < 4; ++a)
#pragma unroll
      for (int o = 0; o < 8; ++o) sacc[a][o] = 0.f;
    for (int k = 0; k < 64; ++k) {
      float ha[4];
#pragma unroll
      for (int a = 0; a < 4; ++a) ha[a] = hhL[ty * 4 + a][k];
      const float* Br = &BL[k][tx * 8];
#pragma unroll
      for (int o = 0; o < 8; ++o) {
        const float bv = Br[o];
#pragma unroll
        for (int a = 0; a < 4; ++a) sacc[a][o] = fmaf(ha[a], bv, sacc[a][o]);
      }
    }
#pragma unroll
    for (int a = 0; a < 4; ++a) {
      float* op = &self_[(size_t)(e0 + ty * 4 + a) * 128 + tx * 8];
#pragma unroll
      for (int o = 0; o < 8; ++o) op[o] = sacc[a][o] * 0.5f;  // 1/deg
    }
  }
}

// ---------------- gather (segment sum over incoming edges) + gate ----------------
__global__ __launch_bounds__(256) void k_gather1(
    const float* __restrict__ t_, const float* __restrict__ Y_,
    const int* __restrict__ offs, const int* __restrict__ elist,
    float* __restrict__ h1, float* __restrict__ h1s) {
  __shared__ float tL[128], YL[16], sG[32];
  const int n = blockIdx.x, tid = threadIdx.x;
  const int beg = offs[n], end = offs[n + 1];
  const int cc = tid & 15;
  const int lx = lidx_of(cc);
  const int o0 = ((tid >> 4) << 2) + lx;
  const int o1 = o0 + 64;
  float a0 = 0.f, a1 = 0.f;
  for (int ei = beg; ei < end; ++ei) {
    const int e = elist[ei];
    __syncthreads();
    if (tid < 128) tL[tid] = t_[(size_t)e * 128 + tid];
    else if (tid < 144) YL[tid - 128] = Y_[(size_t)e * 16 + tid - 128];
    __syncthreads();
    const float yv = YL[cc];
    a0 = fmaf(tL[o0], yv, a0);
    a1 = fmaf(tL[o1], yv, a1);
  }
  if (cc == 0) { sG[tid >> 4] = a0; sG[(tid >> 4) + 16] = a1; }
  __syncthreads();
  const float s0 = sG[tid >> 4], s1 = sG[(tid >> 4) + 16];
  const float r0 = (cc == 0) ? fmaxf(a0, 0.f) : a0 * (1.f / (1.f + expf(-s0)));
  const float r1 = (cc == 0) ? fmaxf(a1, 0.f) : a1 * (1.f / (1.f + expf(-s1)));
  h1[(size_t)n * 512 + tid] = r0;
  h1[(size_t)n * 512 + tid + 256] = r1;
  if ((tid & 31) == 0) {
    h1s[n * 16 + (tid >> 5)] = r0;       // g = 0..7  (p=0,c=0)
    h1s[n * 16 + (tid >> 5) + 8] = r1;   // g = 8..15
  }
}

__global__ __launch_bounds__(256) void k_gather2(
    const float* __restrict__ t_, const float* __restrict__ self_,
    const float* __restrict__ Y_, const float* __restrict__ h1,
    const int* __restrict__ offs, const int* __restrict__ elist,
    const int* __restrict__ esrc, float* __restrict__ h2) {
  __shared__ float tL[128], wL[128], YL[16], sG[32];
  const int n = blockIdx.x, tid = threadIdx.x;
  const int beg = offs[n], end = offs[n + 1];
  const int cc = tid & 15;
  const int lx = lidx_of(cc);
  const int o0 = ((tid >> 4) << 2) + lx;
  const int o1 = o0 + 64;
  float a0 = 0.f, a1 = 0.f;
  for (int ei = beg; ei < end; ++ei) {
    const int e = elist[ei];
    __syncthreads();
    if (tid < 128) tL[tid] = t_[(size_t)e * 128 + tid];
    else wL[tid - 128] = self_[(size_t)e * 128 + tid - 128];
    if (tid < 16) YL[tid] = Y_[(size_t)e * 16 + tid];
    __syncthreads();
    const int src = esrc[e];
    const float* hr = &h1[(size_t)src * 512];
    const float yv = YL[cc];
    a0 += tL[o0] * yv + hr[tid] * wL[o0];
    a1 += tL[o1] * yv + hr[tid + 256] * wL[o1];
  }
  if (cc == 0) { sG[tid >> 4] = a0; sG[(tid >> 4) + 16] = a1; }
  __syncthreads();
  const float s0 = sG[tid >> 4], s1 = sG[(tid >> 4) + 16];
  const float r0 = (cc == 0) ? fmaxf(a0, 0.f) : a0 * (1.f / (1.f + expf(-s0)));
  const float r1 = (cc == 0) ? fmaxf(a1, 0.f) : a1 * (1.f / (1.f + expf(-s1)));
  h2[(size_t)n * 512 + tid] = r0;
  h2[(size_t)n * 512 + tid + 256] = r1;
}

// ---------------- mean pool over each graph's 256 nodes ----------------
__global__ __launch_bounds__(256) void k_pool(const float* __restrict__ h2,
                                              float* __restrict__ enc) {
  const int b = blockIdx.x, tid = threadIdx.x;
  float a0 = 0.f, a1 = 0.f;
  for (int i = 0; i < 256; ++i) {
    const float* row = &h2[(size_t)(b * 256 + i) * 512];
    a0 += row[tid];
    a1 += row[tid + 256];
  }
  enc[b * 512 + tid] = a0 * (1.f / 256.f);
  enc[b * 512 + tid + 256] = a1 * (1.f / 256.f);
}

// ---------------- z = per-l linear mix of enc (B,32,16) -> (B,16,84) ----------------
__global__ __launch_bounds__(256) void k_zproj(const float* __restrict__ enc,
                                               const float* __restrict__ Wlin,
                                               float* __restrict__ z) {
  __shared__ float eL[512];
  const int b = blockIdx.x, tid = threadIdx.x;
  eL[tid] = enc[b * 512 + tid];
  eL[tid + 256] = enc[b * 512 + tid + 256];
  __syncthreads();
  for (int idx = tid; idx < 16 * 84; idx += 256) {
    const int g = idx / 84, d3 = idx % 84;
    int o0, m0, mo;
    if (d3 < 1)       { o0 = 0;  m0 = 1; mo = 0; }
    else if (d3 < 10) { o0 = 1;  m0 = 3; mo = 1; }
    else if (d3 < 35) { o0 = 10; m0 = 5; mo = 4; }
    else              { o0 = 35; m0 = 7; mo = 9; }
    const int rem = d3 - o0;
    const int jj = rem / m0;
    const int cc2 = rem - jj * m0;
    float a = 0.f;
    for (int mu = 0; mu < 32; ++mu)
      a = fmaf(eL[mu * 16 + mo + cc2], Wlin[(mu * 16 + g) * 16 + mo + jj], a);
    z[(size_t)(b * 16 + g) * 84 + d3] = a * 0.17677669529663687f;  // 1/sqrt(32)
  }
}

// ---------------- SO3 conv: per-l matmul ----------------
template <int M, int FI, int FO>
DEV void conv_item(const float* xL, const float* __restrict__ psi, int b, int g,
                   int o0, int j, float* __restrict__ out, float scale) {
  float acc[M];
#pragma unroll
  for (int c = 0; c < M; ++c) acc[c] = 0.f;
  for (int f = 0; f < FI; ++f) {
    const float* xr = &xL[f * 84 + o0];
    const float* pr = &psi[((size_t)f * FO + g) * 84 + o0 + j];
#pragma unroll
    for (int i = 0; i < M; ++i) {
      const float pv = pr[i * M];
#pragma unroll
      for (int c = 0; c < M; ++c) acc[c] = fmaf(xr[i * M + c], pv, acc[c]);
    }
  }
  float* op = &out[((size_t)b * FO + g) * 84 + o0 + j * M];
#pragma unroll
  for (int c = 0; c < M; ++c) op[c] = acc[c] * scale;
}

template <int FI, int FO>
__global__ __launch_bounds__(256) void k_conv(const float* __restrict__ x,
                                              const float* __restrict__ psi,
                                              float* __restrict__ out) {
  __shared__ float xL[FI * 84];
  const int tid = threadIdx.x, b = blockIdx.x;
  for (int i = tid; i < FI * 84; i += 256) xL[i] = x[(size_t)b * FI * 84 + i];
  __syncthreads();
  const int g0 = blockIdx.y * 16;
  if (tid < 16) {
    conv_item<1, FI, FO>(xL, psi, b, g0 + tid, 0, 0, out, 1.f / sqrtf((float)(FI * 1)));
  } else if (tid < 64) {
    const int q = tid - 16;
    conv_item<3, FI, FO>(xL, psi, b, g0 + q / 3, 1, q % 3, out, 1.f / sqrtf((float)(FI * 3)));
  } else if (tid < 144) {
    const int q = tid - 64;
    conv_item<5, FI, FO>(xL, psi, b, g0 + q / 5, 10, q % 5, out, 1.f / sqrtf((float)(FI * 5)));
  } else {
    const int q = tid - 144;
    conv_item<7, FI, FO>(xL, psi, b, g0 + q / 7, 35, q % 7, out, 1.f / sqrtf((float)(FI * 7)));
  }
}

// ---------------- SO3 act (fused, partial over g-splits), RB=16 ----------------
// grid = (rows/16, GSPLIT) chosen so total blocks = 1024 (4/CU).
// phase1: 256 threads, chunk of 512 g-cols, thread owns cols (tid, tid+256): fa[16][2]
// phase2: 8 groups x 32 lanes; group owns 64 g of the chunk; acc[16][3]
// reduce: shfl_xor(32) wave-pair combine -> 4-wave LDS tree -> partial buffer
template <int GSPLIT>
__global__ __launch_bounds__(256) void k_act_part(
    const float* __restrict__ x, const float* __restrict__ Gt,
    const float* __restrict__ Gf, float* __restrict__ part) {
  constexpr int RB = 16;
  constexpr int NCHUNK = 8 / GSPLIT;  // chunks of 512 g-cols per block
  __shared__ float sm[16 * 84 + 16 * 516];  // 9600 floats = 38.4 KB -> 4 blocks/CU
  float* yL = sm;          // [16][84]
  float* gch = sm + 1344;  // [16][516]
  const int tid = threadIdx.x;
  const int gs = blockIdx.y;
  const int row0 = blockIdx.x * RB;
  const int nrows = gridDim.x * RB;

  for (int i = tid; i < RB * 84; i += 256) yL[i] = x[(size_t)row0 * 84 + i];

  const int gp = tid >> 5, j = tid & 15 | (tid & 31);  // j = tid & 31
  const int jj31 = tid & 31;
  float acc[RB][3];
#pragma unroll
  for (int r = 0; r < RB; ++r) { acc[r][0] = 0.f; acc[r][1] = 0.f; acc[r][2] = 0.f; }
  __syncthreads();

  for (int cc = gs * NCHUNK; cc < (gs + 1) * NCHUNK; ++cc) {
    const int g0 = cc * 512;
    // ---- phase 1: fa[r][2] = x rows @ Gt cols (g0+tid, g0+256+tid)
    float fa[RB][2];
#pragma unroll
    for (int r = 0; r < RB; ++r) { fa[r][0] = 0.f; fa[r][1] = 0.f; }
    for (int dq = 0; dq < 21; ++dq) {
      float gt0[4], gt1[4];
#pragma unroll
      for (int i = 0; i < 4; ++i) {
        const size_t db = (size_t)(dq * 4 + i) * 4096 + g0 + tid;
        gt0[i] = Gt[db];
        gt1[i] = Gt[db + 256];
      }
#pragma unroll
      for (int r = 0; r < RB; ++r) {
        const float4 y4 = *(const float4*)&yL[r * 84 + dq * 4];
        fa[r][0] = fmaf(y4.x, gt0[0], fa[r][0]);
        fa[r][0] = fmaf(y4.y, gt0[1], fa[r][0]);
        fa[r][0] = fmaf(y4.z, gt0[2], fa[r][0]);
        fa[r][0] = fmaf(y4.w, gt0[3], fa[r][0]);
        fa[r][1] = fmaf(y4.x, gt1[0], fa[r][1]);
        fa[r][1] = fmaf(y4.y, gt1[1], fa[r][1]);
        fa[r][1] = fmaf(y4.z, gt1[2], fa[r][1]);
        fa[r][1] = fmaf(y4.w, gt1[3], fa[r][1]);
      }
    }
    __syncthreads();  // previous phase2 done reading gch
#pragma unroll
    for (int r = 0; r < RB; ++r) {
      gch[r * 516 + tid] = fmaxf(fa[r][0], 0.f);
      gch[r * 516 + tid + 256] = fmaxf(fa[r][1], 0.f);
    }
    __syncthreads();
    // ---- phase 2: group gp owns g in [gp*64, gp*64+64)
    for (int q = 0; q < 16; ++q) {
      const int g2 = gp * 64 + q * 4;
      float gf[4][3];
#pragma unroll
      for (int i = 0; i < 4; ++i) {
        const size_t gidx = (size_t)(g0 + g2 + i) * 84;
        gf[i][0] = Gf[gidx + jj31];
        gf[i][1] = Gf[gidx + 32 + jj31];
        gf[i][2] = (jj31 < 20) ? Gf[gidx + 64 + jj31] : 0.f;
      }
#pragma unroll
      for (int r = 0; r < RB; ++r) {
        const float4 p4 = *(const float4*)&gch[r * 516 + g2];
        acc[r][0] = fmaf(p4.x, gf[0][0], acc[r][0]);
        acc[r][1] = fmaf(p4.x, gf[0][1], acc[r][1]);
        acc[r][2] = fmaf(p4.x, gf[0][2], acc[r][2]);
        acc[r][0] = fmaf(p4.y, gf[1][0], acc[r][0]);
        acc[r][1] = fmaf(p4.y, gf[1][1], acc[r][1]);
        acc[r][2] = fmaf(p4.y, gf[1][2], acc[r][2]);
        acc[r][0] = fmaf(p4.z, gf[2][0], acc[r][0]);
        acc[r][1] = fmaf(p4.z, gf[2][1], acc[r][1]);
        acc[r][2] = fmaf(p4.z, gf[2][2], acc[r][2]);
        acc[r][0] = fmaf(p4.w, gf[3][0], acc[r][0]);
        acc[r][1] = fmaf(p4.w, gf[3][1], acc[r][1]);
        acc[r][2] = fmaf(p4.w, gf[3][2], acc[r][2]);
      }
    }
  }
  // ---- reduce: combine group pairs within each wave via shfl_xor(32)
  __syncthreads();  // all phase2 reads of gch done; sm reusable
  const int w = tid >> 6;  // wave id 0..3
#pragma unroll
  for (int r = 0; r < RB; ++r)
#pragma unroll
    for (int c = 0; c < 3; ++c) {
      const float v = acc[r][c] + __shfl_xor(acc[r][c], 32, 64);
      if ((tid & 63) < 32) sm[((w * RB + r) * 32 + jj31) * 3 + c] = v;
    }
  __syncthreads();
  for (int o = tid; o < RB * 84; o += 256) {
    const int r = o / 84, d = o % 84;
    const int dj = d & 31, c = d >> 5;
    float s = 0.f;
#pragma unroll
    for (int ww = 0; ww < 4; ++ww) s += sm[((ww * RB + r) * 32 + dj) * 3 + c];
    part[((size_t)gs * nrows + row0 + r) * 84 + d] = s;
  }
}

template <int GSPLIT>
__global__ __launch_bounds__(256) void k_act_reduce(const float* __restrict__ part,
                                                    float* __restrict__ out, int total) {
  const int i = blockIdx.x * 256 + threadIdx.x;
  if (i < total) {
    float s = part[i];
#pragma unroll
    for (int g = 1; g < GSPLIT; ++g) s += part[(size_t)g * total + i];
    out[i] = s * (1.f / (9.16515138991168f * 64.f));  // 1/(sqrt(84)*64)
  }
}

// ---------------- final: Ws2 contraction + orientation SH dot ----------------
__global__ __launch_bounds__(256) void k_final(const float* __restrict__ x,
                                               const float* __restrict__ Ws2,
                                               const float* __restrict__ orient,
                                               float* __restrict__ outp) {
  __shared__ float red[256][16];
  const int b = blockIdx.x, tid = threadIdx.x;
  const float* xr = &x[(size_t)(b * 256 + tid) * 84];
  const float* wr = &Ws2[tid * 16];
  float acc[16];
#pragma unroll
  for (int c = 0; c < 16; ++c) acc[c] = 0.f;
  acc[0] = fmaf(xr[0], wr[0], acc[0]);
#pragma unroll
  for (int i = 0; i < 3; ++i) {
    const float w = wr[1 + i];
#pragma unroll
    for (int c = 0; c < 3; ++c) acc[1 + c] = fmaf(xr[1 + i * 3 + c], w, acc[1 + c]);
  }
#pragma unroll
  for (int i = 0; i < 5; ++i) {
    const float w = wr[4 + i];
#pragma unroll
    for (int c = 0; c < 5; ++c) acc[4 + c] = fmaf(xr[10 + i * 5 + c], w, acc[4 + c]);
  }
#pragma unroll
  for (int i = 0; i < 7; ++i) {
    const float w = wr[9 + i];
#pragma unroll
    for (int c = 0; c < 7; ++c) acc[9 + c] = fmaf(xr[35 + i * 7 + c], w, acc[9 + c]);
  }
#pragma unroll
  for (int c = 0; c < 16; ++c) red[tid][c] = acc[c];
  __syncthreads();
  for (int off = 128; off > 0; off >>= 1) {
    if (tid < off)
#pragma unroll
      for (int c = 0; c < 16; ++c) red[tid][c] += red[tid + off][c];
    __syncthreads();
  }
  if (tid == 0) {
    const float aa = orient[b * 2 + 0], rr = orient[b * 2 + 1];
    float Y[16];
    real_sh_f(-sinf(aa) * cosf(rr), -sinf(aa) * sinf(rr), -cosf(aa), Y);
    const float sc1 = 1.f / 16.f;
    const float sc3 = 1.f / (16.f * 1.7320508075688772f);
    const float sc5 = 1.f / (16.f * 2.23606797749979f);
    const float sc7 = 1.f / (16.f * 2.6457513110645907f);
    float o = red[0][0] * sc1 * Y[0];
#pragma unroll
    for (int c = 1; c < 4; ++c) o += red[0][c] * sc3 * Y[c];
#pragma unroll
    for (int c = 4; c < 9; ++c) o += red[0][c] * sc5 * Y[c];
#pragma unroll
    for (int c = 9; c < 16; ++c) o += red[0][c] * sc7 * Y[c];
    outp[b] = o;
  }
}

extern "C" void kernel_launch(void* const* d_in, const int* in_sizes, int n_in,
                              void* d_out, int out_size, void* d_ws, size_t ws_size,
                              hipStream_t stream) {
  const float* node_feat = (const float*)d_in[0];
  const float* pos       = (const float*)d_in[1];
  const float* orient    = (const float*)d_in[2];
  const float* rad1_W1   = (const float*)d_in[3];
  const float* rad1_b    = (const float*)d_in[4];
  const float* rad1_W2   = (const float*)d_in[5];
  const float* rad2_W1   = (const float*)d_in[6];
  const float* rad2_b    = (const float*)d_in[7];
  const float* rad2_W2   = (const float*)d_in[8];
  const float* Wlin      = (const float*)d_in[9];
  const float* psi1      = (const float*)d_in[10];
  const float* psi2      = (const float*)d_in[11];
  const float* psi3      = (const float*)d_in[12];
  const float* G_to      = (const float*)d_in[13];
  const float* G_from    = (const float*)d_in[14];
  const float* Ws2       = (const float*)d_in[15];
  const int*   esrc      = (const int*)d_in[16];
  const int*   edst      = (const int*)d_in[17];

  float* w = (float*)d_ws;
  size_t off = 0;
  float* u_    = w + off; off += NE;
  float* cut_  = w + off; off += NE;
  float* Y_    = w + off; off += (size_t)NE * 16;
  float* t_    = w + off; off += (size_t)NE * 128;   // t1, then reused for t2
  float* self_ = w + off; off += (size_t)NE * 128;   // also reused as act partials
  float* h1    = w + off; off += (size_t)NN * 512;
  float* h1s   = w + off; off += (size_t)NN * 16;
  float* h2    = w + off; off += (size_t)NN * 512;
  float* enc   = w + off; off += (size_t)NB * 512;
  float* z     = w + off; off += (size_t)NB * 16 * 84;
  float* xb1   = w + off; off += (size_t)NB * 256 * 84;
  float* xb2   = w + off; off += (size_t)NB * 256 * 84;
  int* cnt    = (int*)(w + off); off += NN;
  int* offs   = (int*)(w + off); off += NN + 1;
  int* cursor = (int*)(w + off); off += NN;
  int* elist  = (int*)(w + off); off += NE;

  float* part = self_;  // dead after k_gather2; max use 8*2048*84 floats < NE*128

  hipMemsetAsync(cnt, 0, NN * sizeof(int), stream);
  k_edge_prep<<<NE / 256, 256, 0, stream>>>(pos, esrc, edst, u_, cut_, Y_, cnt);
  k_scan<<<1, 256, 0, stream>>>(cnt, offs, cursor);
  k_fill<<<NE / 256, 256, 0, stream>>>(edst, cursor, elist);
  k_msg<false><<<NE / 64, 256, 0, stream>>>(u_, cut_, rad1_W1, rad1_b, rad1_W2,
                                            node_feat, esrc, t_, nullptr);
  k_gather1<<<NN, 256, 0, stream>>>(t_, Y_, offs, elist, h1, h1s);
  k_msg<true><<<NE / 64, 256, 0, stream>>>(u_, cut_, rad2_W1, rad2_b, rad2_W2,
                                           h1s, esrc, t_, self_);
  k_gather2<<<NN, 256, 0, stream>>>(t_, self_, Y_, h1, offs, elist, esrc, h2);
  k_pool<<<NB, 256, 0, stream>>>(h2, enc);
  k_zproj<<<NB, 256, 0, stream>>>(enc, Wlin, z);

  // act grids: always 1024 blocks total (4 blocks/CU with 38.4 KB LDS)
  k_conv<16, 64><<<dim3(NB, 4), 256, 0, stream>>>(z, psi1, xb1);
  k_act_part<8><<<dim3(2048 / 16, 8), 256, 0, stream>>>(xb1, G_to, G_from, part);
  k_act_reduce<8><<<(2048 * 84 + 255) / 256, 256, 0, stream>>>(part, xb2, 2048 * 84);

  k_conv<64, 128><<<dim3(NB, 8), 256, 0, stream>>>(xb2, psi2, xb1);
  k_act_part<4><<<dim3(4096 / 16, 4), 256, 0, stream>>>(xb1, G_to, G_from, part);
  k_act_reduce<4><<<(4096 * 84 + 255) / 256, 256, 0, stream>>>(part, xb2, 4096 * 84);

  k_conv<128, 256><<<dim3(NB, 16), 256, 0, stream>>>(xb2, psi3, xb1);
  k_act_part<2><<<dim3(8192 / 16, 2), 256, 0, stream>>>(xb1, G_to, G_from, part);
  k_act_reduce<2><<<(8192 * 84 + 255) / 256, 256, 0, stream>>>(part, xb2, 8192 * 84);

  k_final<<<NB, 256, 0, stream>>>(xb2, Ws2, orient, (float*)d_out);
}

// Round 5
// 666.128 us; speedup vs baseline: 1.5543x; 1.3787x over previous
//
#include <hip/hip_runtime.h>
#include <math.h>

#define DEV static __device__ __forceinline__

constexpr int NN = 8192;    // nodes
constexpr int NE = 32768;   // edges
constexpr int NB = 32;      // graphs

using short8 = __attribute__((ext_vector_type(8))) short;
using f32x4  = __attribute__((ext_vector_type(4))) float;

DEV ushort f2bf(float f) {  // round-to-nearest-even f32 -> bf16 bits
  unsigned u = __float_as_uint(f);
  unsigned r = (u + 0x7FFFu + ((u >> 16) & 1u)) >> 16;
  return (ushort)r;
}

DEV int lidx_of(int c) { return (c == 0) ? 0 : (c < 4) ? 1 : (c < 9) ? 2 : 3; }

DEV void real_sh_f(float x, float y, float z, float* Y) {
  const float s3  = 1.7320508075688772f;
  const float s5  = 2.23606797749979f;
  const float s15 = 3.872983346207417f;
  Y[0] = 1.f;
  Y[1] = s3 * y;  Y[2] = s3 * z;  Y[3] = s3 * x;
  Y[4] = s15 * x * y;
  Y[5] = s15 * y * z;
  Y[6] = 0.5f * s5 * (3.f * z * z - 1.f);
  Y[7] = s15 * x * z;
  Y[8] = 0.5f * s15 * (x * x - y * y);
  Y[9]  = 2.091650066335189f * y * (3.f * x * x - y * y);
  Y[10] = 10.246950765959598f * x * y * z;
  Y[11] = 1.6201851746019651f * y * (5.f * z * z - 1.f);
  Y[12] = 1.3228756555322954f * (5.f * z * z * z - 3.f * z);
  Y[13] = 1.6201851746019651f * x * (5.f * z * z - 1.f);
  Y[14] = 5.123475382979799f * (x * x - y * y) * z;
  Y[15] = 2.091650066335189f * x * (x * x - 3.f * y * y);
}

// ---------------- edge geometry: Y, u, cut + degree histogram ----------------
__global__ __launch_bounds__(256) void k_edge_prep(
    const float* __restrict__ pos, const int* __restrict__ esrc,
    const int* __restrict__ edst, float* __restrict__ u_, float* __restrict__ cut_,
    float* __restrict__ Y_, int* __restrict__ cnt) {
  const int e = blockIdx.x * 256 + threadIdx.x;
  if (e >= NE) return;
  const int s = esrc[e], t = edst[e];
  const float ex = pos[t * 3 + 0] - pos[s * 3 + 0];
  const float ey = pos[t * 3 + 1] - pos[s * 3 + 1];
  const float ez = pos[t * 3 + 2] - pos[s * 3 + 2];
  const float d = sqrtf(ex * ex + ey * ey + ez * ez) + 1e-9f;
  const float inv = 1.f / d;
  float Y[16];
  real_sh_f(ex * inv, ey * inv, ez * inv, Y);
#pragma unroll
  for (int c = 0; c < 16; ++c) Y_[(size_t)e * 16 + c] = Y[c];
  const float u = d / 3.5f;
  u_[e] = u;
  cut_[e] = (u < 1.f) ? 0.5f * (cosf(3.14159265358979323846f * u) + 1.f) : 0.f;
  atomicAdd(&cnt[t], 1);
}

// ---------------- CSR build: scan + fill ----------------
__global__ __launch_bounds__(256) void k_scan(const int* __restrict__ cnt,
                                              int* __restrict__ offs,
                                              int* __restrict__ cursor) {
  __shared__ int part[256];
  const int t = threadIdx.x;
  int s = 0;
  for (int i = 0; i < 32; ++i) s += cnt[t * 32 + i];
  part[t] = s;
  __syncthreads();
  if (t == 0) {
    int run = 0;
    for (int i = 0; i < 256; ++i) { int v = part[i]; part[i] = run; run += v; }
    offs[NN] = run;
  }
  __syncthreads();
  int run = part[t];
  for (int i = 0; i < 32; ++i) {
    const int idx = t * 32 + i;
    offs[idx] = run;
    cursor[idx] = run;
    run += cnt[idx];
  }
}

__global__ __launch_bounds__(256) void k_fill(const int* __restrict__ edst,
                                              int* __restrict__ cursor,
                                              int* __restrict__ elist) {
  const int e = blockIdx.x * 256 + threadIdx.x;
  if (e < NE) {
    const int p = atomicAdd(&cursor[edst[e]], 1);
    elist[p] = e;
  }
}

// ---------------- per-edge bilinear GEMM: t[e][128] (and optional self[e][128]) ----
template <bool IS2>
__global__ __launch_bounds__(256) void k_msg(
    const float* __restrict__ u_, const float* __restrict__ cut_,
    const float* __restrict__ W1, const float* __restrict__ bvec,
    const float* __restrict__ W2, const float* __restrict__ feat16,
    const int* __restrict__ esrc, float* __restrict__ t_, float* __restrict__ self_) {
  __shared__ __align__(16) float hhL[64][65];
  __shared__ __align__(16) float nfL[64][17];
  __shared__ __align__(16) float BL[64][128];
  __shared__ float uL[64], cL[64];
  __shared__ int sL[64];
  const int tid = threadIdx.x;
  const int e0 = blockIdx.x * 64;
  if (tid < 64) {
    uL[tid] = u_[e0 + tid];
    cL[tid] = cut_[e0 + tid];
    sL[tid] = esrc[e0 + tid];
  }
  __syncthreads();
  for (int i = tid; i < 64 * 64; i += 256) {
    const int e = i >> 6, k = i & 63;
    hhL[e][k] = fmaxf(fmaf(uL[e], W1[k], bvec[k]), 0.f) * cL[e];
  }
  for (int i = tid; i < 64 * 16; i += 256) {
    const int e = i >> 4, f = i & 15;
    nfL[e][f] = feat16[(size_t)sL[e] * 16 + f];
  }
  const int ty = tid >> 4, tx = tid & 15;
  float acc[4][8];
#pragma unroll
  for (int a = 0; a < 4; ++a)
#pragma unroll
    for (int o = 0; o < 8; ++o) acc[a][o] = 0.f;

  for (int ch = 0; ch < 16; ++ch) {
    __syncthreads();
#pragma unroll
    for (int j = 0; j < 8; ++j) {
      const int q = tid + j * 256;
      const int row = q >> 5, c4 = (q & 31) << 2;
      const int kf = ch * 64 + row;
      size_t gaddr;
      if (IS2) gaddr = (size_t)(kf >> 4) * 2176 + (size_t)(kf & 15) * 128 + c4;
      else     gaddr = (size_t)kf * 128 + c4;
      *(float4*)&BL[row][c4] = *(const float4*)(W2 + gaddr);
    }
    __syncthreads();
#pragma unroll
    for (int kk = 0; kk < 4; ++kk) {
      const int k = ch * 4 + kk;
      float ha[4];
#pragma unroll
      for (int a = 0; a < 4; ++a) ha[a] = hhL[ty * 4 + a][k];
#pragma unroll
      for (int f = 0; f < 16; ++f) {
        float av[4];
#pragma unroll
        for (int a = 0; a < 4; ++a) av[a] = ha[a] * nfL[ty * 4 + a][f];
        const float* Br = &BL[kk * 16 + f][tx * 8];
#pragma unroll
        for (int o = 0; o < 8; ++o) {
          const float bv = Br[o];
#pragma unroll
          for (int a = 0; a < 4; ++a) acc[a][o] = fmaf(av[a], bv, acc[a][o]);
        }
      }
    }
  }
#pragma unroll
  for (int a = 0; a < 4; ++a) {
    float* op = &t_[(size_t)(e0 + ty * 4 + a) * 128 + tx * 8];
#pragma unroll
    for (int o = 0; o < 8; ++o) op[o] = acc[a][o] * 0.125f;  // 1/sqrt(F)/deg
  }

  if (IS2) {
    __syncthreads();
#pragma unroll
    for (int j = 0; j < 8; ++j) {
      const int q = tid + j * 256;
      const int row = q >> 5, c4 = (q & 31) << 2;
      *(float4*)&BL[row][c4] = *(const float4*)(W2 + (size_t)row * 2176 + 2048 + c4);
    }
    __syncthreads();
    float sacc[4][8];
#pragma unroll
    for (int a = 0; a < 4; ++a)
#pragma unroll
      for (int o = 0; o < 8; ++o) sacc[a][o] = 0.f;
    for (int k = 0; k < 64; ++k) {
      float ha[4];
#pragma unroll
      for (int a = 0; a < 4; ++a) ha[a] = hhL[ty * 4 + a][k];
      const float* Br = &BL[k][tx * 8];
#pragma unroll
      for (int o = 0; o < 8; ++o) {
        const float bv = Br[o];
#pragma unroll
        for (int a = 0; a < 4; ++a) sacc[a][o] = fmaf(ha[a], bv, sacc[a][o]);
      }
    }
#pragma unroll
    for (int a = 0; a < 4; ++a) {
      float* op = &self_[(size_t)(e0 + ty * 4 + a) * 128 + tx * 8];
#pragma unroll
      for (int o = 0; o < 8; ++o) op[o] = sacc[a][o] * 0.5f;  // 1/deg
    }
  }
}

// ---------------- gather (segment sum over incoming edges) + gate ----------------
__global__ __launch_bounds__(256) void k_gather1(
    const float* __restrict__ t_, const float* __restrict__ Y_,
    const int* __restrict__ offs, const int* __restrict__ elist,
    float* __restrict__ h1, float* __restrict__ h1s) {
  __shared__ float tL[128], YL[16], sG[32];
  const int n = blockIdx.x, tid = threadIdx.x;
  const int beg = offs[n], end = offs[n + 1];
  const int cc = tid & 15;
  const int lx = lidx_of(cc);
  const int o0 = ((tid >> 4) << 2) + lx;
  const int o1 = o0 + 64;
  float a0 = 0.f, a1 = 0.f;
  for (int ei = beg; ei < end; ++ei) {
    const int e = elist[ei];
    __syncthreads();
    if (tid < 128) tL[tid] = t_[(size_t)e * 128 + tid];
    else if (tid < 144) YL[tid - 128] = Y_[(size_t)e * 16 + tid - 128];
    __syncthreads();
    const float yv = YL[cc];
    a0 = fmaf(tL[o0], yv, a0);
    a1 = fmaf(tL[o1], yv, a1);
  }
  if (cc == 0) { sG[tid >> 4] = a0; sG[(tid >> 4) + 16] = a1; }
  __syncthreads();
  const float s0 = sG[tid >> 4], s1 = sG[(tid >> 4) + 16];
  const float r0 = (cc == 0) ? fmaxf(a0, 0.f) : a0 * (1.f / (1.f + expf(-s0)));
  const float r1 = (cc == 0) ? fmaxf(a1, 0.f) : a1 * (1.f / (1.f + expf(-s1)));
  h1[(size_t)n * 512 + tid] = r0;
  h1[(size_t)n * 512 + tid + 256] = r1;
  if ((tid & 31) == 0) {
    h1s[n * 16 + (tid >> 5)] = r0;       // g = 0..7  (p=0,c=0)
    h1s[n * 16 + (tid >> 5) + 8] = r1;   // g = 8..15
  }
}

__global__ __launch_bounds__(256) void k_gather2(
    const float* __restrict__ t_, const float* __restrict__ self_,
    const float* __restrict__ Y_, const float* __restrict__ h1,
    const int* __restrict__ offs, const int* __restrict__ elist,
    const int* __restrict__ esrc, float* __restrict__ h2) {
  __shared__ float tL[128], wL[128], YL[16], sG[32];
  const int n = blockIdx.x, tid = threadIdx.x;
  const int beg = offs[n], end = offs[n + 1];
  const int cc = tid & 15;
  const int lx = lidx_of(cc);
  const int o0 = ((tid >> 4) << 2) + lx;
  const int o1 = o0 + 64;
  float a0 = 0.f, a1 = 0.f;
  for (int ei = beg; ei < end; ++ei) {
    const int e = elist[ei];
    __syncthreads();
    if (tid < 128) tL[tid] = t_[(size_t)e * 128 + tid];
    else wL[tid - 128] = self_[(size_t)e * 128 + tid - 128];
    if (tid < 16) YL[tid] = Y_[(size_t)e * 16 + tid];
    __syncthreads();
    const int src = esrc[e];
    const float* hr = &h1[(size_t)src * 512];
    const float yv = YL[cc];
    a0 += tL[o0] * yv + hr[tid] * wL[o0];
    a1 += tL[o1] * yv + hr[tid + 256] * wL[o1];
  }
  if (cc == 0) { sG[tid >> 4] = a0; sG[(tid >> 4) + 16] = a1; }
  __syncthreads();
  const float s0 = sG[tid >> 4], s1 = sG[(tid >> 4) + 16];
  const float r0 = (cc == 0) ? fmaxf(a0, 0.f) : a0 * (1.f / (1.f + expf(-s0)));
  const float r1 = (cc == 0) ? fmaxf(a1, 0.f) : a1 * (1.f / (1.f + expf(-s1)));
  h2[(size_t)n * 512 + tid] = r0;
  h2[(size_t)n * 512 + tid + 256] = r1;
}

// ---------------- mean pool over each graph's 256 nodes ----------------
__global__ __launch_bounds__(256) void k_pool(const float* __restrict__ h2,
                                              float* __restrict__ enc) {
  const int b = blockIdx.x, tid = threadIdx.x;
  float a0 = 0.f, a1 = 0.f;
  for (int i = 0; i < 256; ++i) {
    const float* row = &h2[(size_t)(b * 256 + i) * 512];
    a0 += row[tid];
    a1 += row[tid + 256];
  }
  enc[b * 512 + tid] = a0 * (1.f / 256.f);
  enc[b * 512 + tid + 256] = a1 * (1.f / 256.f);
}

// ---------------- z = per-l linear mix of enc (B,32,16) -> (B,16,84) ----------------
__global__ __launch_bounds__(256) void k_zproj(const float* __restrict__ enc,
                                               const float* __restrict__ Wlin,
                                               float* __restrict__ z) {
  __shared__ float eL[512];
  const int b = blockIdx.x, tid = threadIdx.x;
  eL[tid] = enc[b * 512 + tid];
  eL[tid + 256] = enc[b * 512 + tid + 256];
  __syncthreads();
  for (int idx = tid; idx < 16 * 84; idx += 256) {
    const int g = idx / 84, d3 = idx % 84;
    int o0, m0, mo;
    if (d3 < 1)       { o0 = 0;  m0 = 1; mo = 0; }
    else if (d3 < 10) { o0 = 1;  m0 = 3; mo = 1; }
    else if (d3 < 35) { o0 = 10; m0 = 5; mo = 4; }
    else              { o0 = 35; m0 = 7; mo = 9; }
    const int rem = d3 - o0;
    const int jj = rem / m0;
    const int cc2 = rem - jj * m0;
    float a = 0.f;
    for (int mu = 0; mu < 32; ++mu)
      a = fmaf(eL[mu * 16 + mo + cc2], Wlin[(mu * 16 + g) * 16 + mo + jj], a);
    z[(size_t)(b * 16 + g) * 84 + d3] = a * 0.17677669529663687f;  // 1/sqrt(32)
  }
}

// ---------------- SO3 conv: per-l matmul ----------------
template <int M, int FI, int FO>
DEV void conv_item(const float* xL, const float* __restrict__ psi, int b, int g,
                   int o0, int j, float* __restrict__ out, float scale) {
  float acc[M];
#pragma unroll
  for (int c = 0; c < M; ++c) acc[c] = 0.f;
  for (int f = 0; f < FI; ++f) {
    const float* xr = &xL[f * 84 + o0];
    const float* pr = &psi[((size_t)f * FO + g) * 84 + o0 + j];
#pragma unroll
    for (int i = 0; i < M; ++i) {
      const float pv = pr[i * M];
#pragma unroll
      for (int c = 0; c < M; ++c) acc[c] = fmaf(xr[i * M + c], pv, acc[c]);
    }
  }
  float* op = &out[((size_t)b * FO + g) * 84 + o0 + j * M];
#pragma unroll
  for (int c = 0; c < M; ++c) op[c] = acc[c] * scale;
}

template <int FI, int FO>
__global__ __launch_bounds__(256) void k_conv(const float* __restrict__ x,
                                              const float* __restrict__ psi,
                                              float* __restrict__ out) {
  __shared__ float xL[FI * 84];
  const int tid = threadIdx.x, b = blockIdx.x;
  for (int i = tid; i < FI * 84; i += 256) xL[i] = x[(size_t)b * FI * 84 + i];
  __syncthreads();
  const int g0 = blockIdx.y * 16;
  if (tid < 16) {
    conv_item<1, FI, FO>(xL, psi, b, g0 + tid, 0, 0, out, 1.f / sqrtf((float)(FI * 1)));
  } else if (tid < 64) {
    const int q = tid - 16;
    conv_item<3, FI, FO>(xL, psi, b, g0 + q / 3, 1, q % 3, out, 1.f / sqrtf((float)(FI * 3)));
  } else if (tid < 144) {
    const int q = tid - 64;
    conv_item<5, FI, FO>(xL, psi, b, g0 + q / 5, 10, q % 5, out, 1.f / sqrtf((float)(FI * 5)));
  } else {
    const int q = tid - 144;
    conv_item<7, FI, FO>(xL, psi, b, g0 + q / 7, 35, q % 7, out, 1.f / sqrtf((float)(FI * 7)));
  }
}

// ---------------- weight prep for MFMA act ----------------
// GtT[g][k] = Gt[k][g], k padded 84->96 with zeros (bf16)
__global__ __launch_bounds__(256) void k_prep_gt(const float* __restrict__ Gt,
                                                 ushort* __restrict__ GtT) {
  const int idx = blockIdx.x * 256 + threadIdx.x;
  if (idx >= 4096 * 96) return;
  const int g = idx / 96, k = idx % 96;
  GtT[idx] = (k < 84) ? f2bf(Gt[(size_t)k * 4096 + g]) : (ushort)0;
}
// GfT[d][g] = Gf[g][d], d padded 84->96 with zeros (bf16)
__global__ __launch_bounds__(256) void k_prep_gf(const float* __restrict__ Gf,
                                                 ushort* __restrict__ GfT) {
  const int idx = blockIdx.x * 256 + threadIdx.x;
  if (idx >= 96 * 4096) return;
  const int d = idx / 4096, g = idx % 4096;
  GfT[idx] = (d < 84) ? f2bf(Gf[(size_t)g * 84 + d]) : (ushort)0;
}
// Xb[r][k] = bf16(x[r][k]), k padded 84->96
__global__ __launch_bounds__(256) void k_cvtx(const float* __restrict__ x,
                                              ushort* __restrict__ Xb, int total) {
  const int idx = blockIdx.x * 256 + threadIdx.x;
  if (idx >= total) return;
  const int r = idx / 96, k = idx % 96;
  Xb[idx] = (k < 84) ? f2bf(x[(size_t)r * 84 + k]) : (ushort)0;
}

// ---------------- SO3 act via bf16 MFMA (fused, g-split partials) ----------------
// Per block: 128 rows (4 waves x 32), CPB = 64/GS chunks of 64 g-columns.
// Per chunk: GEMM1 H = relu(X @ GtT-chunk)  [mfma 16x16x32, K=96]
//            GEMM2' acc2[d][r] += GfT-chunk @ H^T  [K=64]  (f32 accum)
// H is wave-private in LDS (rows m0..m0+31). Partials -> k_act_reduce (applies SC).
template <int GS>
__global__ __launch_bounds__(256) void k_act_mfma(
    const ushort* __restrict__ Xb, const ushort* __restrict__ GtT,
    const ushort* __restrict__ GfT, float* __restrict__ part, int NR) {
  constexpr int CPB = 64 / GS;
  __shared__ __align__(16) ushort ldsGt[64 * 104];  // [g][k pad 104]
  __shared__ __align__(16) ushort ldsH[128 * 72];   // [row][g pad 72]
  __shared__ __align__(16) ushort ldsGf[96 * 72];   // [d][g pad 72]
  const int tid = threadIdx.x;
  const int row0 = blockIdx.x * 128;
  const int gs = blockIdx.y;
  const int lane = tid & 63, wv = tid >> 6;
  const int lr = lane & 15, lg = lane >> 4;
  const int m0 = wv * 32;  // wave's row base within block

  // A1 frags (chunk-invariant): X[m0+mt*16+lr][ks*32 + lg*8 ..+7], 16B global loads
  short8 a1[2][3];
#pragma unroll
  for (int mt = 0; mt < 2; ++mt)
#pragma unroll
    for (int ks = 0; ks < 3; ++ks)
      a1[mt][ks] = *(const short8*)&Xb[(size_t)(row0 + m0 + mt * 16 + lr) * 96 +
                                       ks * 32 + lg * 8];

  f32x4 acc2[6][2];
#pragma unroll
  for (int m2 = 0; m2 < 6; ++m2)
#pragma unroll
    for (int n2 = 0; n2 < 2; ++n2) {
      f32x4 zz = {0.f, 0.f, 0.f, 0.f};
      acc2[m2][n2] = zz;
    }

  for (int ch = gs * CPB; ch < (gs + 1) * CPB; ++ch) {
    const int g0 = ch * 64;
    __syncthreads();  // previous chunk's LDS reads done
    // stage GtT chunk: 64 g-rows x 96 k (12 x 16B per row)
    for (int i = tid; i < 768; i += 256) {
      const int row = i / 12, c = i % 12;
      *(uint4*)&ldsGt[row * 104 + c * 8] =
          *(const uint4*)&GtT[(size_t)(g0 + row) * 96 + c * 8];
    }
    // stage GfT chunk: 96 d-rows x 64 g (8 x 16B per row)
    for (int i = tid; i < 768; i += 256) {
      const int row = i / 8, c = i % 8;
      *(uint4*)&ldsGf[row * 72 + c * 8] =
          *(const uint4*)&GfT[(size_t)row * 4096 + g0 + c * 8];
    }
    __syncthreads();
    // GEMM1 + relu + H-write (wave-private rows)
#pragma unroll
    for (int n = 0; n < 4; ++n) {
      short8 b[3];
#pragma unroll
      for (int ks = 0; ks < 3; ++ks)
        b[ks] = *(const short8*)&ldsGt[(n * 16 + lr) * 104 + ks * 32 + lg * 8];
#pragma unroll
      for (int mt = 0; mt < 2; ++mt) {
        f32x4 c1 = {0.f, 0.f, 0.f, 0.f};
#pragma unroll
        for (int ks = 0; ks < 3; ++ks)
          c1 = __builtin_amdgcn_mfma_f32_16x16x32_bf16(a1[mt][ks], b[ks], c1, 0, 0, 0);
        ushort* hp = &ldsH[(m0 + mt * 16 + lg * 4) * 72 + n * 16 + lr];
#pragma unroll
        for (int i = 0; i < 4; ++i) hp[i * 72] = f2bf(fmaxf(c1[i], 0.f));
      }
    }
    // GEMM2': acc2[d][r] += GfT-chunk @ H^T   (same wave's H rows; lgkm dep in-wave)
#pragma unroll
    for (int k2 = 0; k2 < 2; ++k2) {
      short8 bh[2];
#pragma unroll
      for (int n2 = 0; n2 < 2; ++n2)
        bh[n2] = *(const short8*)&ldsH[(m0 + n2 * 16 + lr) * 72 + k2 * 32 + lg * 8];
#pragma unroll
      for (int m2 = 0; m2 < 6; ++m2) {
        const short8 a2 = *(const short8*)&ldsGf[(m2 * 16 + lr) * 72 + k2 * 32 + lg * 8];
        acc2[m2][0] = __builtin_amdgcn_mfma_f32_16x16x32_bf16(a2, bh[0], acc2[m2][0], 0, 0, 0);
        acc2[m2][1] = __builtin_amdgcn_mfma_f32_16x16x32_bf16(a2, bh[1], acc2[m2][1], 0, 0, 0);
      }
    }
  }
  // store partials: C2 lane layout: r-col = lr, d-row = m2*16 + lg*4 + i
#pragma unroll
  for (int m2 = 0; m2 < 6; ++m2)
#pragma unroll
    for (int n2 = 0; n2 < 2; ++n2)
#pragma unroll
      for (int i = 0; i < 4; ++i) {
        const int d = m2 * 16 + lg * 4 + i;
        if (d < 84) {
          const int r = row0 + m0 + n2 * 16 + lr;
          part[((size_t)gs * NR + r) * 84 + d] = acc2[m2][n2][i];
        }
      }
}

template <int GS>
__global__ __launch_bounds__(256) void k_act_reduce(const float* __restrict__ part,
                                                    float* __restrict__ out, int total) {
  const int i = blockIdx.x * 256 + threadIdx.x;
  if (i < total) {
    float s = part[i];
#pragma unroll
    for (int g = 1; g < GS; ++g) s += part[(size_t)g * total + i];
    out[i] = s * (1.f / (9.16515138991168f * 64.f));  // 1/(sqrt(84)*64)
  }
}

// ---------------- final: Ws2 contraction + orientation SH dot ----------------
__global__ __launch_bounds__(256) void k_final(const float* __restrict__ x,
                                               const float* __restrict__ Ws2,
                                               const float* __restrict__ orient,
                                               float* __restrict__ outp) {
  __shared__ float red[256][16];
  const int b = blockIdx.x, tid = threadIdx.x;
  const float* xr = &x[(size_t)(b * 256 + tid) * 84];
  const float* wr = &Ws2[tid * 16];
  float acc[16];
#pragma unroll
  for (int c = 0; c < 16; ++c) acc[c] = 0.f;
  acc[0] = fmaf(xr[0], wr[0], acc[0]);
#pragma unroll
  for (int i = 0; i < 3; ++i) {
    const float w = wr[1 + i];
#pragma unroll
    for (int c = 0; c < 3; ++c) acc[1 + c] = fmaf(xr[1 + i * 3 + c], w, acc[1 + c]);
  }
#pragma unroll
  for (int i = 0; i < 5; ++i) {
    const float w = wr[4 + i];
#pragma unroll
    for (int c = 0; c < 5; ++c) acc[4 + c] = fmaf(xr[10 + i * 5 + c], w, acc[4 + c]);
  }
#pragma unroll
  for (int i = 0; i < 7; ++i) {
    const float w = wr[9 + i];
#pragma unroll
    for (int c = 0; c < 7; ++c) acc[9 + c] = fmaf(xr[35 + i * 7 + c], w, acc[9 + c]);
  }
#pragma unroll
  for (int c = 0; c < 16; ++c) red[tid][c] = acc[c];
  __syncthreads();
  for (int off = 128; off > 0; off >>= 1) {
    if (tid < off)
#pragma unroll
      for (int c = 0; c < 16; ++c) red[tid][c] += red[tid + off][c];
    __syncthreads();
  }
  if (tid == 0) {
    const float aa = orient[b * 2 + 0], rr = orient[b * 2 + 1];
    float Y[16];
    real_sh_f(-sinf(aa) * cosf(rr), -sinf(aa) * sinf(rr), -cosf(aa), Y);
    const float sc1 = 1.f / 16.f;
    const float sc3 = 1.f / (16.f * 1.7320508075688772f);
    const float sc5 = 1.f / (16.f * 2.23606797749979f);
    const float sc7 = 1.f / (16.f * 2.6457513110645907f);
    float o = red[0][0] * sc1 * Y[0];
#pragma unroll
    for (int c = 1; c < 4; ++c) o += red[0][c] * sc3 * Y[c];
#pragma unroll
    for (int c = 4; c < 9; ++c) o += red[0][c] * sc5 * Y[c];
#pragma unroll
    for (int c = 9; c < 16; ++c) o += red[0][c] * sc7 * Y[c];
    outp[b] = o;
  }
}

extern "C" void kernel_launch(void* const* d_in, const int* in_sizes, int n_in,
                              void* d_out, int out_size, void* d_ws, size_t ws_size,
                              hipStream_t stream) {
  const float* node_feat = (const float*)d_in[0];
  const float* pos       = (const float*)d_in[1];
  const float* orient    = (const float*)d_in[2];
  const float* rad1_W1   = (const float*)d_in[3];
  const float* rad1_b    = (const float*)d_in[4];
  const float* rad1_W2   = (const float*)d_in[5];
  const float* rad2_W1   = (const float*)d_in[6];
  const float* rad2_b    = (const float*)d_in[7];
  const float* rad2_W2   = (const float*)d_in[8];
  const float* Wlin      = (const float*)d_in[9];
  const float* psi1      = (const float*)d_in[10];
  const float* psi2      = (const float*)d_in[11];
  const float* psi3      = (const float*)d_in[12];
  const float* G_to      = (const float*)d_in[13];
  const float* G_from    = (const float*)d_in[14];
  const float* Ws2       = (const float*)d_in[15];
  const int*   esrc      = (const int*)d_in[16];
  const int*   edst      = (const int*)d_in[17];

  float* w = (float*)d_ws;
  size_t off = 0;
  float* u_    = w + off; off += NE;
  float* cut_  = w + off; off += NE;
  float* Y_    = w + off; off += (size_t)NE * 16;
  float* t_    = w + off; off += (size_t)NE * 128;   // t1/t2; later act partials
  float* self_ = w + off; off += (size_t)NE * 128;   // msg2 self; partial overflow
  float* h1    = w + off; off += (size_t)NN * 512;   // later: GtT/GfT/Xb (bf16)
  float* h1s   = w + off; off += (size_t)NN * 16;
  float* h2    = w + off; off += (size_t)NN * 512;
  float* enc   = w + off; off += (size_t)NB * 512;
  float* z     = w + off; off += (size_t)NB * 16 * 84;
  float* xb1   = w + off; off += (size_t)NB * 256 * 84;
  float* xb2   = w + off; off += (size_t)NB * 256 * 84;
  int* cnt    = (int*)(w + off); off += NN;
  int* offs   = (int*)(w + off); off += NN + 1;
  int* cursor = (int*)(w + off); off += NN;
  int* elist  = (int*)(w + off); off += NE;

  // act-time reuse of dead buffers:
  float* part = t_;                 // partials: up to 32*2048*84 f32 = 22 MB,
                                    // spans t_ + self_ (contiguous, both dead)
  ushort* GtT = (ushort*)h1;        // 4096*96 bf16
  ushort* GfT = GtT + 4096 * 96;    // 96*4096 bf16
  ushort* Xb  = GfT + 96 * 4096;    // up to 8192*96 bf16  (total 3.1 MB < h1)

  hipMemsetAsync(cnt, 0, NN * sizeof(int), stream);
  k_edge_prep<<<NE / 256, 256, 0, stream>>>(pos, esrc, edst, u_, cut_, Y_, cnt);
  k_scan<<<1, 256, 0, stream>>>(cnt, offs, cursor);
  k_fill<<<NE / 256, 256, 0, stream>>>(edst, cursor, elist);
  k_msg<false><<<NE / 64, 256, 0, stream>>>(u_, cut_, rad1_W1, rad1_b, rad1_W2,
                                            node_feat, esrc, t_, nullptr);
  k_gather1<<<NN, 256, 0, stream>>>(t_, Y_, offs, elist, h1, h1s);
  k_msg<true><<<NE / 64, 256, 0, stream>>>(u_, cut_, rad2_W1, rad2_b, rad2_W2,
                                           h1s, esrc, t_, self_);
  k_gather2<<<NN, 256, 0, stream>>>(t_, self_, Y_, h1, offs, elist, esrc, h2);
  k_pool<<<NB, 256, 0, stream>>>(h2, enc);
  k_zproj<<<NB, 256, 0, stream>>>(enc, Wlin, z);

  // h1 is dead now -> build bf16 weight copies inside it
  k_prep_gt<<<(4096 * 96 + 255) / 256, 256, 0, stream>>>(G_to, GtT);
  k_prep_gf<<<(96 * 4096 + 255) / 256, 256, 0, stream>>>(G_from, GfT);

  k_conv<16, 64><<<dim3(NB, 4), 256, 0, stream>>>(z, psi1, xb1);
  k_cvtx<<<(2048 * 96 + 255) / 256, 256, 0, stream>>>(xb1, Xb, 2048 * 96);
  k_act_mfma<32><<<dim3(16, 32), 256, 0, stream>>>(Xb, GtT, GfT, part, 2048);
  k_act_reduce<32><<<(2048 * 84 + 255) / 256, 256, 0, stream>>>(part, xb2, 2048 * 84);

  k_conv<64, 128><<<dim3(NB, 8), 256, 0, stream>>>(xb2, psi2, xb1);
  k_cvtx<<<(4096 * 96 + 255) / 256, 256, 0, stream>>>(xb1, Xb, 4096 * 96);
  k_act_mfma<16><<<dim3(32, 16), 256, 0, stream>>>(Xb, GtT, GfT, part, 4096);
  k_act_reduce<16><<<(4096 * 84 + 255) / 256, 256, 0, stream>>>(part, xb2, 4096 * 84);

  k_conv<128, 256><<<dim3(NB, 16), 256, 0, stream>>>(xb2, psi3, xb1);
  k_cvtx<<<(8192 * 96 + 255) / 256, 256, 0, stream>>>(xb1, Xb, 8192 * 96);
  k_act_mfma<8><<<dim3(64, 8), 256, 0, stream>>>(Xb, GtT, GfT, part, 8192);
  k_act_reduce<8><<<(8192 * 84 + 255) / 256, 256, 0, stream>>>(part, xb2, 8192 * 84);

  k_final<<<NB, 256, 0, stream>>>(xb2, Ws2, orient, (float*)d_out);
}

// Round 6
// 523.468 us; speedup vs baseline: 1.9778x; 1.2725x over previous
//
#include <hip/hip_runtime.h>
#include <math.h>

#define DEV static __device__ __forceinline__

constexpr int NN = 8192;    // nodes
constexpr int NE = 32768;   // edges
constexpr int NB = 32;      // graphs

using short8 = __attribute__((ext_vector_type(8))) short;
using f32x4  = __attribute__((ext_vector_type(4))) float;

DEV ushort f2bf(float f) {  // round-to-nearest-even f32 -> bf16 bits
  unsigned u = __float_as_uint(f);
  unsigned r = (u + 0x7FFFu + ((u >> 16) & 1u)) >> 16;
  return (ushort)r;
}
DEV float bf2f(ushort h) { return __uint_as_float(((unsigned)h) << 16); }

// split p[8] into bf16 hi + bf16 residual (hi RNE, lo truncated - lo is tiny)
DEV void split8(const float* p, short8& hi, short8& lo) {
#pragma unroll
  for (int j = 0; j < 8; ++j) {
    const ushort h = f2bf(p[j]);
    hi[j] = (short)h;
    const float r = p[j] - bf2f(h);
    lo[j] = (short)(__float_as_uint(r) >> 16);
  }
}

DEV int lidx_of(int c) { return (c == 0) ? 0 : (c < 4) ? 1 : (c < 9) ? 2 : 3; }

DEV void real_sh_f(float x, float y, float z, float* Y) {
  const float s3  = 1.7320508075688772f;
  const float s5  = 2.23606797749979f;
  const float s15 = 3.872983346207417f;
  Y[0] = 1.f;
  Y[1] = s3 * y;  Y[2] = s3 * z;  Y[3] = s3 * x;
  Y[4] = s15 * x * y;
  Y[5] = s15 * y * z;
  Y[6] = 0.5f * s5 * (3.f * z * z - 1.f);
  Y[7] = s15 * x * z;
  Y[8] = 0.5f * s15 * (x * x - y * y);
  Y[9]  = 2.091650066335189f * y * (3.f * x * x - y * y);
  Y[10] = 10.246950765959598f * x * y * z;
  Y[11] = 1.6201851746019651f * y * (5.f * z * z - 1.f);
  Y[12] = 1.3228756555322954f * (5.f * z * z * z - 3.f * z);
  Y[13] = 1.6201851746019651f * x * (5.f * z * z - 1.f);
  Y[14] = 5.123475382979799f * (x * x - y * y) * z;
  Y[15] = 2.091650066335189f * x * (x * x - 3.f * y * y);
}

// ---------------- edge geometry: Y, u, cut + degree histogram ----------------
__global__ __launch_bounds__(256) void k_edge_prep(
    const float* __restrict__ pos, const int* __restrict__ esrc,
    const int* __restrict__ edst, float* __restrict__ u_, float* __restrict__ cut_,
    float* __restrict__ Y_, int* __restrict__ cnt) {
  const int e = blockIdx.x * 256 + threadIdx.x;
  if (e >= NE) return;
  const int s = esrc[e], t = edst[e];
  const float ex = pos[t * 3 + 0] - pos[s * 3 + 0];
  const float ey = pos[t * 3 + 1] - pos[s * 3 + 1];
  const float ez = pos[t * 3 + 2] - pos[s * 3 + 2];
  const float d = sqrtf(ex * ex + ey * ey + ez * ez) + 1e-9f;
  const float inv = 1.f / d;
  float Y[16];
  real_sh_f(ex * inv, ey * inv, ez * inv, Y);
#pragma unroll
  for (int c = 0; c < 16; ++c) Y_[(size_t)e * 16 + c] = Y[c];
  const float u = d / 3.5f;
  u_[e] = u;
  cut_[e] = (u < 1.f) ? 0.5f * (cosf(3.14159265358979323846f * u) + 1.f) : 0.f;
  atomicAdd(&cnt[t], 1);
}

// ---------------- CSR build: scan + fill ----------------
__global__ __launch_bounds__(256) void k_scan(const int* __restrict__ cnt,
                                              int* __restrict__ offs,
                                              int* __restrict__ cursor) {
  __shared__ int part[256];
  const int t = threadIdx.x;
  int s = 0;
  for (int i = 0; i < 32; ++i) s += cnt[t * 32 + i];
  part[t] = s;
  __syncthreads();
  if (t == 0) {
    int run = 0;
    for (int i = 0; i < 256; ++i) { int v = part[i]; part[i] = run; run += v; }
    offs[NN] = run;
  }
  __syncthreads();
  int run = part[t];
  for (int i = 0; i < 32; ++i) {
    const int idx = t * 32 + i;
    offs[idx] = run;
    cursor[idx] = run;
    run += cnt[idx];
  }
}

__global__ __launch_bounds__(256) void k_fill(const int* __restrict__ edst,
                                              int* __restrict__ cursor,
                                              int* __restrict__ elist) {
  const int e = blockIdx.x * 256 + threadIdx.x;
  if (e < NE) {
    const int p = atomicAdd(&cursor[edst[e]], 1);
    elist[p] = e;
  }
}

// ---------------- W2^T bf16 hi/lo prep ----------------
// W2T[o][kf] = W2[(k,f),o]; msg1: flat kf*128+o ; msg2: k*2176 + f*128 + o
template <bool IS2>
__global__ __launch_bounds__(256) void k_prep_w2t(const float* __restrict__ W2,
                                                  ushort* __restrict__ Th,
                                                  ushort* __restrict__ Tl) {
  const int idx = blockIdx.x * 256 + threadIdx.x;
  if (idx >= 128 * 1024) return;
  const int o = idx >> 10, kf = idx & 1023;
  const float v = IS2 ? W2[(size_t)(kf >> 4) * 2176 + (kf & 15) * 128 + o]
                      : W2[(size_t)kf * 128 + o];
  const ushort h = f2bf(v);
  Th[idx] = h;
  Tl[idx] = (ushort)(__float_as_uint(v - bf2f(h)) >> 16);
}

// selfWT[o][k] = rad2_W2[k][2048+o]
__global__ __launch_bounds__(256) void k_prep_selfw(const float* __restrict__ W2,
                                                    ushort* __restrict__ Sh,
                                                    ushort* __restrict__ Sl) {
  const int idx = blockIdx.x * 256 + threadIdx.x;
  if (idx >= 128 * 64) return;
  const int o = idx >> 6, k = idx & 63;
  const float v = W2[(size_t)k * 2176 + 2048 + o];
  const ushort h = f2bf(v);
  Sh[idx] = h;
  Sl[idx] = (ushort)(__float_as_uint(v - bf2f(h)) >> 16);
}

// ---------------- per-edge bilinear GEMM via split-bf16 MFMA ----------------
// t[e,o] = 0.125 * sum_{kf} A[e,kf] W2[kf,o],  A[e,k*16+f] = hh[e,k]*nf[e,f]
// A-frag (16x16x32): row=lane&15, 8-elem k-chunk at (lane>>4)*8 -> single k,
// f-range (lg&1)*8..+8  =>  frag = hh_scalar * nf8.  Split A and W into bf16
// hi/lo; accumulate AhWh + AlWh + AhWl in f32 (error ~4e-6 relative).
// Block: 128 edges, 4 waves x 32 edges (2 m-tiles). Grid 256.
template <bool IS2>
__global__ __launch_bounds__(256) void k_msg_mfma(
    const float* __restrict__ u_, const float* __restrict__ cut_,
    const float* __restrict__ W1, const float* __restrict__ bvec,
    const ushort* __restrict__ W2Th, const ushort* __restrict__ W2Tl,
    const ushort* __restrict__ SWh, const ushort* __restrict__ SWl,
    const float* __restrict__ feat16, const int* __restrict__ esrc,
    float* __restrict__ t_, float* __restrict__ self_) {
  __shared__ float hhL[128 * 65];
  __shared__ float nfL[128 * 17];
  __shared__ float uL[128], cL[128];
  __shared__ int sL[128];
  const int tid = threadIdx.x;
  const int e0 = blockIdx.x * 128;
  if (tid < 128) {
    uL[tid] = u_[e0 + tid];
    cL[tid] = cut_[e0 + tid];
    sL[tid] = esrc[e0 + tid];
  }
  __syncthreads();
  for (int i = tid; i < 128 * 64; i += 256) {
    const int e = i >> 6, k = i & 63;
    hhL[e * 65 + k] = fmaxf(fmaf(uL[e], W1[k], bvec[k]), 0.f) * cL[e];
  }
  for (int i = tid; i < 128 * 16; i += 256) {
    const int e = i >> 4, f = i & 15;
    nfL[e * 17 + f] = feat16[(size_t)sL[e] * 16 + f];
  }
  __syncthreads();

  const int lane = tid & 63, wv = tid >> 6;
  const int lr = lane & 15, lg = lane >> 4;
  const int m0 = wv * 32;
  const int r0 = e0 + m0;  // this wave's first edge

  // ---- self part (msg2 only): self[e,o] = 0.5 * hh @ selfW, K=64
  if (IS2) {
    f32x4 sacc[2][8];
#pragma unroll
    for (int mt = 0; mt < 2; ++mt)
#pragma unroll
      for (int n = 0; n < 8; ++n) {
        f32x4 zz = {0.f, 0.f, 0.f, 0.f};
        sacc[mt][n] = zz;
      }
#pragma unroll
    for (int ks2 = 0; ks2 < 2; ++ks2) {
      short8 ash[2], asl[2];
#pragma unroll
      for (int mt = 0; mt < 2; ++mt) {
        float p[8];
        const float* hp = &hhL[(m0 + mt * 16 + lr) * 65 + ks2 * 32 + lg * 8];
#pragma unroll
        for (int j = 0; j < 8; ++j) p[j] = hp[j];
        split8(p, ash[mt], asl[mt]);
      }
#pragma unroll
      for (int n = 0; n < 8; ++n) {
        const short8 bh = *(const short8*)&SWh[(n * 16 + lr) * 64 + ks2 * 32 + lg * 8];
        const short8 bl = *(const short8*)&SWl[(n * 16 + lr) * 64 + ks2 * 32 + lg * 8];
#pragma unroll
        for (int mt = 0; mt < 2; ++mt) {
          sacc[mt][n] = __builtin_amdgcn_mfma_f32_16x16x32_bf16(ash[mt], bh, sacc[mt][n], 0, 0, 0);
          sacc[mt][n] = __builtin_amdgcn_mfma_f32_16x16x32_bf16(asl[mt], bh, sacc[mt][n], 0, 0, 0);
          sacc[mt][n] = __builtin_amdgcn_mfma_f32_16x16x32_bf16(ash[mt], bl, sacc[mt][n], 0, 0, 0);
        }
      }
    }
#pragma unroll
    for (int mt = 0; mt < 2; ++mt)
#pragma unroll
      for (int n = 0; n < 8; ++n)
#pragma unroll
        for (int i = 0; i < 4; ++i)
          self_[(size_t)(r0 + mt * 16 + lg * 4 + i) * 128 + n * 16 + lr] =
              sacc[mt][n][i] * 0.5f;
  }

  // ---- main: K=1024 over (k,f)
  float nf8[2][8];
#pragma unroll
  for (int mt = 0; mt < 2; ++mt)
#pragma unroll
    for (int j = 0; j < 8; ++j)
      nf8[mt][j] = nfL[(m0 + mt * 16 + lr) * 17 + (lg & 1) * 8 + j];

  f32x4 acc[2][8];
#pragma unroll
  for (int mt = 0; mt < 2; ++mt)
#pragma unroll
    for (int n = 0; n < 8; ++n) {
      f32x4 zz = {0.f, 0.f, 0.f, 0.f};
      acc[mt][n] = zz;
    }

  for (int ks = 0; ks < 32; ++ks) {
    short8 ah[2], al[2];
#pragma unroll
    for (int mt = 0; mt < 2; ++mt) {
      const float hs = hhL[(m0 + mt * 16 + lr) * 65 + 2 * ks + (lg >> 1)];
      float p[8];
#pragma unroll
      for (int j = 0; j < 8; ++j) p[j] = hs * nf8[mt][j];
      split8(p, ah[mt], al[mt]);
    }
#pragma unroll
    for (int n = 0; n < 8; ++n) {
      const short8 bh = *(const short8*)&W2Th[(size_t)(n * 16 + lr) * 1024 + ks * 32 + lg * 8];
      const short8 bl = *(const short8*)&W2Tl[(size_t)(n * 16 + lr) * 1024 + ks * 32 + lg * 8];
#pragma unroll
      for (int mt = 0; mt < 2; ++mt) {
        acc[mt][n] = __builtin_amdgcn_mfma_f32_16x16x32_bf16(ah[mt], bh, acc[mt][n], 0, 0, 0);
        acc[mt][n] = __builtin_amdgcn_mfma_f32_16x16x32_bf16(al[mt], bh, acc[mt][n], 0, 0, 0);
        acc[mt][n] = __builtin_amdgcn_mfma_f32_16x16x32_bf16(ah[mt], bl, acc[mt][n], 0, 0, 0);
      }
    }
  }
#pragma unroll
  for (int mt = 0; mt < 2; ++mt)
#pragma unroll
    for (int n = 0; n < 8; ++n)
#pragma unroll
      for (int i = 0; i < 4; ++i)
        t_[(size_t)(r0 + mt * 16 + lg * 4 + i) * 128 + n * 16 + lr] =
            acc[mt][n][i] * 0.125f;  // 1/sqrt(F)/deg
}

// ---------------- gather (segment sum over incoming edges) + gate ----------------
__global__ __launch_bounds__(256) void k_gather1(
    const float* __restrict__ t_, const float* __restrict__ Y_,
    const int* __restrict__ offs, const int* __restrict__ elist,
    float* __restrict__ h1, float* __restrict__ h1s) {
  __shared__ float tL[128], YL[16], sG[32];
  const int n = blockIdx.x, tid = threadIdx.x;
  const int beg = offs[n], end = offs[n + 1];
  const int cc = tid & 15;
  const int lx = lidx_of(cc);
  const int o0 = ((tid >> 4) << 2) + lx;
  const int o1 = o0 + 64;
  float a0 = 0.f, a1 = 0.f;
  for (int ei = beg; ei < end; ++ei) {
    const int e = elist[ei];
    __syncthreads();
    if (tid < 128) tL[tid] = t_[(size_t)e * 128 + tid];
    else if (tid < 144) YL[tid - 128] = Y_[(size_t)e * 16 + tid - 128];
    __syncthreads();
    const float yv = YL[cc];
    a0 = fmaf(tL[o0], yv, a0);
    a1 = fmaf(tL[o1], yv, a1);
  }
  if (cc == 0) { sG[tid >> 4] = a0; sG[(tid >> 4) + 16] = a1; }
  __syncthreads();
  const float s0 = sG[tid >> 4], s1 = sG[(tid >> 4) + 16];
  const float r0 = (cc == 0) ? fmaxf(a0, 0.f) : a0 * (1.f / (1.f + expf(-s0)));
  const float r1 = (cc == 0) ? fmaxf(a1, 0.f) : a1 * (1.f / (1.f + expf(-s1)));
  h1[(size_t)n * 512 + tid] = r0;
  h1[(size_t)n * 512 + tid + 256] = r1;
  if ((tid & 31) == 0) {
    h1s[n * 16 + (tid >> 5)] = r0;       // g = 0..7  (p=0,c=0)
    h1s[n * 16 + (tid >> 5) + 8] = r1;   // g = 8..15
  }
}

__global__ __launch_bounds__(256) void k_gather2(
    const float* __restrict__ t_, const float* __restrict__ self_,
    const float* __restrict__ Y_, const float* __restrict__ h1,
    const int* __restrict__ offs, const int* __restrict__ elist,
    const int* __restrict__ esrc, float* __restrict__ h2) {
  __shared__ float tL[128], wL[128], YL[16], sG[32];
  const int n = blockIdx.x, tid = threadIdx.x;
  const int beg = offs[n], end = offs[n + 1];
  const int cc = tid & 15;
  const int lx = lidx_of(cc);
  const int o0 = ((tid >> 4) << 2) + lx;
  const int o1 = o0 + 64;
  float a0 = 0.f, a1 = 0.f;
  for (int ei = beg; ei < end; ++ei) {
    const int e = elist[ei];
    __syncthreads();
    if (tid < 128) tL[tid] = t_[(size_t)e * 128 + tid];
    else wL[tid - 128] = self_[(size_t)e * 128 + tid - 128];
    if (tid < 16) YL[tid] = Y_[(size_t)e * 16 + tid];
    __syncthreads();
    const int src = esrc[e];
    const float* hr = &h1[(size_t)src * 512];
    const float yv = YL[cc];
    a0 += tL[o0] * yv + hr[tid] * wL[o0];
    a1 += tL[o1] * yv + hr[tid + 256] * wL[o1];
  }
  if (cc == 0) { sG[tid >> 4] = a0; sG[(tid >> 4) + 16] = a1; }
  __syncthreads();
  const float s0 = sG[tid >> 4], s1 = sG[(tid >> 4) + 16];
  const float r0 = (cc == 0) ? fmaxf(a0, 0.f) : a0 * (1.f / (1.f + expf(-s0)));
  const float r1 = (cc == 0) ? fmaxf(a1, 0.f) : a1 * (1.f / (1.f + expf(-s1)));
  h2[(size_t)n * 512 + tid] = r0;
  h2[(size_t)n * 512 + tid + 256] = r1;
}

// ---------------- mean pool over each graph's 256 nodes ----------------
__global__ __launch_bounds__(256) void k_pool(const float* __restrict__ h2,
                                              float* __restrict__ enc) {
  const int b = blockIdx.x, tid = threadIdx.x;
  float a0 = 0.f, a1 = 0.f;
  for (int i = 0; i < 256; ++i) {
    const float* row = &h2[(size_t)(b * 256 + i) * 512];
    a0 += row[tid];
    a1 += row[tid + 256];
  }
  enc[b * 512 + tid] = a0 * (1.f / 256.f);
  enc[b * 512 + tid + 256] = a1 * (1.f / 256.f);
}

// ---------------- z = per-l linear mix of enc (B,32,16) -> (B,16,84) ----------------
__global__ __launch_bounds__(256) void k_zproj(const float* __restrict__ enc,
                                               const float* __restrict__ Wlin,
                                               float* __restrict__ z) {
  __shared__ float eL[512];
  const int b = blockIdx.x, tid = threadIdx.x;
  eL[tid] = enc[b * 512 + tid];
  eL[tid + 256] = enc[b * 512 + tid + 256];
  __syncthreads();
  for (int idx = tid; idx < 16 * 84; idx += 256) {
    const int g = idx / 84, d3 = idx % 84;
    int o0, m0, mo;
    if (d3 < 1)       { o0 = 0;  m0 = 1; mo = 0; }
    else if (d3 < 10) { o0 = 1;  m0 = 3; mo = 1; }
    else if (d3 < 35) { o0 = 10; m0 = 5; mo = 4; }
    else              { o0 = 35; m0 = 7; mo = 9; }
    const int rem = d3 - o0;
    const int jj = rem / m0;
    const int cc2 = rem - jj * m0;
    float a = 0.f;
    for (int mu = 0; mu < 32; ++mu)
      a = fmaf(eL[mu * 16 + mo + cc2], Wlin[(mu * 16 + g) * 16 + mo + jj], a);
    z[(size_t)(b * 16 + g) * 84 + d3] = a * 0.17677669529663687f;  // 1/sqrt(32)
  }
}

// ---------------- SO3 conv: per-l matmul ----------------
template <int M, int FI, int FO>
DEV void conv_item(const float* xL, const float* __restrict__ psi, int b, int g,
                   int o0, int j, float* __restrict__ out, float scale) {
  float acc[M];
#pragma unroll
  for (int c = 0; c < M; ++c) acc[c] = 0.f;
  for (int f = 0; f < FI; ++f) {
    const float* xr = &xL[f * 84 + o0];
    const float* pr = &psi[((size_t)f * FO + g) * 84 + o0 + j];
#pragma unroll
    for (int i = 0; i < M; ++i) {
      const float pv = pr[i * M];
#pragma unroll
      for (int c = 0; c < M; ++c) acc[c] = fmaf(xr[i * M + c], pv, acc[c]);
    }
  }
  float* op = &out[((size_t)b * FO + g) * 84 + o0 + j * M];
#pragma unroll
  for (int c = 0; c < M; ++c) op[c] = acc[c] * scale;
}

template <int FI, int FO>
__global__ __launch_bounds__(256) void k_conv(const float* __restrict__ x,
                                              const float* __restrict__ psi,
                                              float* __restrict__ out) {
  __shared__ float xL[FI * 84];
  const int tid = threadIdx.x, b = blockIdx.x;
  for (int i = tid; i < FI * 84; i += 256) xL[i] = x[(size_t)b * FI * 84 + i];
  __syncthreads();
  const int g0 = blockIdx.y * 16;
  if (tid < 16) {
    conv_item<1, FI, FO>(xL, psi, b, g0 + tid, 0, 0, out, 1.f / sqrtf((float)(FI * 1)));
  } else if (tid < 64) {
    const int q = tid - 16;
    conv_item<3, FI, FO>(xL, psi, b, g0 + q / 3, 1, q % 3, out, 1.f / sqrtf((float)(FI * 3)));
  } else if (tid < 144) {
    const int q = tid - 64;
    conv_item<5, FI, FO>(xL, psi, b, g0 + q / 5, 10, q % 5, out, 1.f / sqrtf((float)(FI * 5)));
  } else {
    const int q = tid - 144;
    conv_item<7, FI, FO>(xL, psi, b, g0 + q / 7, 35, q % 7, out, 1.f / sqrtf((float)(FI * 7)));
  }
}

// ---------------- weight prep for MFMA act ----------------
__global__ __launch_bounds__(256) void k_prep_gt(const float* __restrict__ Gt,
                                                 ushort* __restrict__ GtT) {
  const int idx = blockIdx.x * 256 + threadIdx.x;
  if (idx >= 4096 * 96) return;
  const int g = idx / 96, k = idx % 96;
  GtT[idx] = (k < 84) ? f2bf(Gt[(size_t)k * 4096 + g]) : (ushort)0;
}
__global__ __launch_bounds__(256) void k_prep_gf(const float* __restrict__ Gf,
                                                 ushort* __restrict__ GfT) {
  const int idx = blockIdx.x * 256 + threadIdx.x;
  if (idx >= 96 * 4096) return;
  const int d = idx / 4096, g = idx % 4096;
  GfT[idx] = (d < 84) ? f2bf(Gf[(size_t)g * 84 + d]) : (ushort)0;
}
__global__ __launch_bounds__(256) void k_cvtx(const float* __restrict__ x,
                                              ushort* __restrict__ Xb, int total) {
  const int idx = blockIdx.x * 256 + threadIdx.x;
  if (idx >= total) return;
  const int r = idx / 96, k = idx % 96;
  Xb[idx] = (k < 84) ? f2bf(x[(size_t)r * 84 + k]) : (ushort)0;
}

// ---------------- SO3 act via bf16 MFMA (fused, g-split partials) ----------------
template <int GS>
__global__ __launch_bounds__(256) void k_act_mfma(
    const ushort* __restrict__ Xb, const ushort* __restrict__ GtT,
    const ushort* __restrict__ GfT, float* __restrict__ part, int NR) {
  constexpr int CPB = 64 / GS;
  __shared__ __align__(16) ushort ldsGt[64 * 104];  // [g][k pad 104]
  __shared__ __align__(16) ushort ldsH[128 * 72];   // [row][g pad 72]
  __shared__ __align__(16) ushort ldsGf[96 * 72];   // [d][g pad 72]
  const int tid = threadIdx.x;
  const int row0 = blockIdx.x * 128;
  const int gs = blockIdx.y;
  const int lane = tid & 63, wv = tid >> 6;
  const int lr = lane & 15, lg = lane >> 4;
  const int m0 = wv * 32;

  short8 a1[2][3];
#pragma unroll
  for (int mt = 0; mt < 2; ++mt)
#pragma unroll
    for (int ks = 0; ks < 3; ++ks)
      a1[mt][ks] = *(const short8*)&Xb[(size_t)(row0 + m0 + mt * 16 + lr) * 96 +
                                       ks * 32 + lg * 8];

  f32x4 acc2[6][2];
#pragma unroll
  for (int m2 = 0; m2 < 6; ++m2)
#pragma unroll
    for (int n2 = 0; n2 < 2; ++n2) {
      f32x4 zz = {0.f, 0.f, 0.f, 0.f};
      acc2[m2][n2] = zz;
    }

  for (int ch = gs * CPB; ch < (gs + 1) * CPB; ++ch) {
    const int g0 = ch * 64;
    __syncthreads();
    for (int i = tid; i < 768; i += 256) {
      const int row = i / 12, c = i % 12;
      *(uint4*)&ldsGt[row * 104 + c * 8] =
          *(const uint4*)&GtT[(size_t)(g0 + row) * 96 + c * 8];
    }
    for (int i = tid; i < 768; i += 256) {
      const int row = i / 8, c = i % 8;
      *(uint4*)&ldsGf[row * 72 + c * 8] =
          *(const uint4*)&GfT[(size_t)row * 4096 + g0 + c * 8];
    }
    __syncthreads();
#pragma unroll
    for (int n = 0; n < 4; ++n) {
      short8 b[3];
#pragma unroll
      for (int ks = 0; ks < 3; ++ks)
        b[ks] = *(const short8*)&ldsGt[(n * 16 + lr) * 104 + ks * 32 + lg * 8];
#pragma unroll
      for (int mt = 0; mt < 2; ++mt) {
        f32x4 c1 = {0.f, 0.f, 0.f, 0.f};
#pragma unroll
        for (int ks = 0; ks < 3; ++ks)
          c1 = __builtin_amdgcn_mfma_f32_16x16x32_bf16(a1[mt][ks], b[ks], c1, 0, 0, 0);
        ushort* hp = &ldsH[(m0 + mt * 16 + lg * 4) * 72 + n * 16 + lr];
#pragma unroll
        for (int i = 0; i < 4; ++i) hp[i * 72] = f2bf(fmaxf(c1[i], 0.f));
      }
    }
#pragma unroll
    for (int k2 = 0; k2 < 2; ++k2) {
      short8 bh[2];
#pragma unroll
      for (int n2 = 0; n2 < 2; ++n2)
        bh[n2] = *(const short8*)&ldsH[(m0 + n2 * 16 + lr) * 72 + k2 * 32 + lg * 8];
#pragma unroll
      for (int m2 = 0; m2 < 6; ++m2) {
        const short8 a2 = *(const short8*)&ldsGf[(m2 * 16 + lr) * 72 + k2 * 32 + lg * 8];
        acc2[m2][0] = __builtin_amdgcn_mfma_f32_16x16x32_bf16(a2, bh[0], acc2[m2][0], 0, 0, 0);
        acc2[m2][1] = __builtin_amdgcn_mfma_f32_16x16x32_bf16(a2, bh[1], acc2[m2][1], 0, 0, 0);
      }
    }
  }
#pragma unroll
  for (int m2 = 0; m2 < 6; ++m2)
#pragma unroll
    for (int n2 = 0; n2 < 2; ++n2)
#pragma unroll
      for (int i = 0; i < 4; ++i) {
        const int d = m2 * 16 + lg * 4 + i;
        if (d < 84) {
          const int r = row0 + m0 + n2 * 16 + lr;
          part[((size_t)gs * NR + r) * 84 + d] = acc2[m2][n2][i];
        }
      }
}

template <int GS>
__global__ __launch_bounds__(256) void k_act_reduce(const float* __restrict__ part,
                                                    float* __restrict__ out, int total) {
  const int i = blockIdx.x * 256 + threadIdx.x;
  if (i < total) {
    float s = part[i];
#pragma unroll
    for (int g = 1; g < GS; ++g) s += part[(size_t)g * total + i];
    out[i] = s * (1.f / (9.16515138991168f * 64.f));  // 1/(sqrt(84)*64)
  }
}

// ---------------- final: Ws2 contraction + orientation SH dot ----------------
__global__ __launch_bounds__(256) void k_final(const float* __restrict__ x,
                                               const float* __restrict__ Ws2,
                                               const float* __restrict__ orient,
                                               float* __restrict__ outp) {
  __shared__ float red[256][16];
  const int b = blockIdx.x, tid = threadIdx.x;
  const float* xr = &x[(size_t)(b * 256 + tid) * 84];
  const float* wr = &Ws2[tid * 16];
  float acc[16];
#pragma unroll
  for (int c = 0; c < 16; ++c) acc[c] = 0.f;
  acc[0] = fmaf(xr[0], wr[0], acc[0]);
#pragma unroll
  for (int i = 0; i < 3; ++i) {
    const float w = wr[1 + i];
#pragma unroll
    for (int c = 0; c < 3; ++c) acc[1 + c] = fmaf(xr[1 + i * 3 + c], w, acc[1 + c]);
  }
#pragma unroll
  for (int i = 0; i < 5; ++i) {
    const float w = wr[4 + i];
#pragma unroll
    for (int c = 0; c < 5; ++c) acc[4 + c] = fmaf(xr[10 + i * 5 + c], w, acc[4 + c]);
  }
#pragma unroll
  for (int i = 0; i < 7; ++i) {
    const float w = wr[9 + i];
#pragma unroll
    for (int c = 0; c < 7; ++c) acc[9 + c] = fmaf(xr[35 + i * 7 + c], w, acc[9 + c]);
  }
#pragma unroll
  for (int c = 0; c < 16; ++c) red[tid][c] = acc[c];
  __syncthreads();
  for (int off = 128; off > 0; off >>= 1) {
    if (tid < off)
#pragma unroll
      for (int c = 0; c < 16; ++c) red[tid][c] += red[tid + off][c];
    __syncthreads();
  }
  if (tid == 0) {
    const float aa = orient[b * 2 + 0], rr = orient[b * 2 + 1];
    float Y[16];
    real_sh_f(-sinf(aa) * cosf(rr), -sinf(aa) * sinf(rr), -cosf(aa), Y);
    const float sc1 = 1.f / 16.f;
    const float sc3 = 1.f / (16.f * 1.7320508075688772f);
    const float sc5 = 1.f / (16.f * 2.23606797749979f);
    const float sc7 = 1.f / (16.f * 2.6457513110645907f);
    float o = red[0][0] * sc1 * Y[0];
#pragma unroll
    for (int c = 1; c < 4; ++c) o += red[0][c] * sc3 * Y[c];
#pragma unroll
    for (int c = 4; c < 9; ++c) o += red[0][c] * sc5 * Y[c];
#pragma unroll
    for (int c = 9; c < 16; ++c) o += red[0][c] * sc7 * Y[c];
    outp[b] = o;
  }
}

extern "C" void kernel_launch(void* const* d_in, const int* in_sizes, int n_in,
                              void* d_out, int out_size, void* d_ws, size_t ws_size,
                              hipStream_t stream) {
  const float* node_feat = (const float*)d_in[0];
  const float* pos       = (const float*)d_in[1];
  const float* orient    = (const float*)d_in[2];
  const float* rad1_W1   = (const float*)d_in[3];
  const float* rad1_b    = (const float*)d_in[4];
  const float* rad1_W2   = (const float*)d_in[5];
  const float* rad2_W1   = (const float*)d_in[6];
  const float* rad2_b    = (const float*)d_in[7];
  const float* rad2_W2   = (const float*)d_in[8];
  const float* Wlin      = (const float*)d_in[9];
  const float* psi1      = (const float*)d_in[10];
  const float* psi2      = (const float*)d_in[11];
  const float* psi3      = (const float*)d_in[12];
  const float* G_to      = (const float*)d_in[13];
  const float* G_from    = (const float*)d_in[14];
  const float* Ws2       = (const float*)d_in[15];
  const int*   esrc      = (const int*)d_in[16];
  const int*   edst      = (const int*)d_in[17];

  float* w = (float*)d_ws;
  size_t off = 0;
  float* u_    = w + off; off += NE;
  float* cut_  = w + off; off += NE;
  float* Y_    = w + off; off += (size_t)NE * 16;
  float* t_    = w + off; off += (size_t)NE * 128;   // t1/t2; later act partials
  float* self_ = w + off; off += (size_t)NE * 128;   // msg2 self; partial overflow
  float* h1    = w + off; off += (size_t)NN * 512;   // later: GtT/GfT/Xb (bf16)
  float* h1s   = w + off; off += (size_t)NN * 16;
  float* h2    = w + off; off += (size_t)NN * 512;
  float* enc   = w + off; off += (size_t)NB * 512;
  float* z     = w + off; off += (size_t)NB * 16 * 84;
  float* xb1   = w + off; off += (size_t)NB * 256 * 84;
  float* xb2   = w + off; off += (size_t)NB * 256 * 84;
  int* cnt    = (int*)(w + off); off += NN;
  int* offs   = (int*)(w + off); off += NN + 1;
  int* cursor = (int*)(w + off); off += NN;
  int* elist  = (int*)(w + off); off += NE;
  ushort* W2Th = (ushort*)(w + off); off += 65536;   // 128x1024 bf16
  ushort* W2Tl = (ushort*)(w + off); off += 65536;
  ushort* SWh  = (ushort*)(w + off); off += 4096;    // 128x64 bf16
  ushort* SWl  = (ushort*)(w + off); off += 4096;

  // act-time reuse of dead buffers:
  float* part = t_;                 // spans t_ + self_ (both dead by act time)
  ushort* GtT = (ushort*)h1;        // 4096*96 bf16
  ushort* GfT = GtT + 4096 * 96;    // 96*4096 bf16
  ushort* Xb  = GfT + 96 * 4096;    // up to 8192*96 bf16

  hipMemsetAsync(cnt, 0, NN * sizeof(int), stream);
  k_edge_prep<<<NE / 256, 256, 0, stream>>>(pos, esrc, edst, u_, cut_, Y_, cnt);
  k_scan<<<1, 256, 0, stream>>>(cnt, offs, cursor);
  k_fill<<<NE / 256, 256, 0, stream>>>(edst, cursor, elist);

  k_prep_w2t<false><<<512, 256, 0, stream>>>(rad1_W2, W2Th, W2Tl);
  k_msg_mfma<false><<<256, 256, 0, stream>>>(u_, cut_, rad1_W1, rad1_b, W2Th, W2Tl,
                                             nullptr, nullptr, node_feat, esrc,
                                             t_, nullptr);
  k_gather1<<<NN, 256, 0, stream>>>(t_, Y_, offs, elist, h1, h1s);

  k_prep_w2t<true><<<512, 256, 0, stream>>>(rad2_W2, W2Th, W2Tl);
  k_prep_selfw<<<32, 256, 0, stream>>>(rad2_W2, SWh, SWl);
  k_msg_mfma<true><<<256, 256, 0, stream>>>(u_, cut_, rad2_W1, rad2_b, W2Th, W2Tl,
                                            SWh, SWl, h1s, esrc, t_, self_);
  k_gather2<<<NN, 256, 0, stream>>>(t_, self_, Y_, h1, offs, elist, esrc, h2);
  k_pool<<<NB, 256, 0, stream>>>(h2, enc);
  k_zproj<<<NB, 256, 0, stream>>>(enc, Wlin, z);

  k_prep_gt<<<(4096 * 96 + 255) / 256, 256, 0, stream>>>(G_to, GtT);
  k_prep_gf<<<(96 * 4096 + 255) / 256, 256, 0, stream>>>(G_from, GfT);

  k_conv<16, 64><<<dim3(NB, 4), 256, 0, stream>>>(z, psi1, xb1);
  k_cvtx<<<(2048 * 96 + 255) / 256, 256, 0, stream>>>(xb1, Xb, 2048 * 96);
  k_act_mfma<32><<<dim3(16, 32), 256, 0, stream>>>(Xb, GtT, GfT, part, 2048);
  k_act_reduce<32><<<(2048 * 84 + 255) / 256, 256, 0, stream>>>(part, xb2, 2048 * 84);

  k_conv<64, 128><<<dim3(NB, 8), 256, 0, stream>>>(xb2, psi2, xb1);
  k_cvtx<<<(4096 * 96 + 255) / 256, 256, 0, stream>>>(xb1, Xb, 4096 * 96);
  k_act_mfma<16><<<dim3(32, 16), 256, 0, stream>>>(Xb, GtT, GfT, part, 4096);
  k_act_reduce<16><<<(4096 * 84 + 255) / 256, 256, 0, stream>>>(part, xb2, 4096 * 84);

  k_conv<128, 256><<<dim3(NB, 16), 256, 0, stream>>>(xb2, psi3, xb1);
  k_cvtx<<<(8192 * 96 + 255) / 256, 256, 0, stream>>>(xb1, Xb, 8192 * 96);
  k_act_mfma<8><<<dim3(64, 8), 256, 0, stream>>>(Xb, GtT, GfT, part, 8192);
  k_act_reduce<8><<<(8192 * 84 + 255) / 256, 256, 0, stream>>>(part, xb2, 8192 * 84);

  k_final<<<NB, 256, 0, stream>>>(xb2, Ws2, orient, (float*)d_out);
}

// Round 7
// 471.767 us; speedup vs baseline: 2.1946x; 1.1096x over previous
//
#include <hip/hip_runtime.h>
#include <math.h>

#define DEV static __device__ __forceinline__

constexpr int NN = 8192;    // nodes
constexpr int NE = 32768;   // edges
constexpr int NB = 32;      // graphs

using short8 = __attribute__((ext_vector_type(8))) short;
using f32x4  = __attribute__((ext_vector_type(4))) float;

DEV ushort f2bf(float f) {  // round-to-nearest-even f32 -> bf16 bits
  unsigned u = __float_as_uint(f);
  unsigned r = (u + 0x7FFFu + ((u >> 16) & 1u)) >> 16;
  return (ushort)r;
}
DEV float bf2f(ushort h) { return __uint_as_float(((unsigned)h) << 16); }

// split p[8] into bf16 hi + bf16 residual
DEV void split8(const float* p, short8& hi, short8& lo) {
#pragma unroll
  for (int j = 0; j < 8; ++j) {
    const ushort h = f2bf(p[j]);
    hi[j] = (short)h;
    const float r = p[j] - bf2f(h);
    lo[j] = (short)(__float_as_uint(r) >> 16);
  }
}

DEV int lidx_of(int c) { return (c == 0) ? 0 : (c < 4) ? 1 : (c < 9) ? 2 : 3; }

DEV void real_sh_f(float x, float y, float z, float* Y) {
  const float s3  = 1.7320508075688772f;
  const float s5  = 2.23606797749979f;
  const float s15 = 3.872983346207417f;
  Y[0] = 1.f;
  Y[1] = s3 * y;  Y[2] = s3 * z;  Y[3] = s3 * x;
  Y[4] = s15 * x * y;
  Y[5] = s15 * y * z;
  Y[6] = 0.5f * s5 * (3.f * z * z - 1.f);
  Y[7] = s15 * x * z;
  Y[8] = 0.5f * s15 * (x * x - y * y);
  Y[9]  = 2.091650066335189f * y * (3.f * x * x - y * y);
  Y[10] = 10.246950765959598f * x * y * z;
  Y[11] = 1.6201851746019651f * y * (5.f * z * z - 1.f);
  Y[12] = 1.3228756555322954f * (5.f * z * z * z - 3.f * z);
  Y[13] = 1.6201851746019651f * x * (5.f * z * z - 1.f);
  Y[14] = 5.123475382979799f * (x * x - y * y) * z;
  Y[15] = 2.091650066335189f * x * (x * x - 3.f * y * y);
}

// ---------------- edge geometry: Y, u, cut + degree histogram ----------------
__global__ __launch_bounds__(256) void k_edge_prep(
    const float* __restrict__ pos, const int* __restrict__ esrc,
    const int* __restrict__ edst, float* __restrict__ u_, float* __restrict__ cut_,
    float* __restrict__ Y_, int* __restrict__ cnt) {
  const int e = blockIdx.x * 256 + threadIdx.x;
  if (e >= NE) return;
  const int s = esrc[e], t = edst[e];
  const float ex = pos[t * 3 + 0] - pos[s * 3 + 0];
  const float ey = pos[t * 3 + 1] - pos[s * 3 + 1];
  const float ez = pos[t * 3 + 2] - pos[s * 3 + 2];
  const float d = sqrtf(ex * ex + ey * ey + ez * ez) + 1e-9f;
  const float inv = 1.f / d;
  float Y[16];
  real_sh_f(ex * inv, ey * inv, ez * inv, Y);
#pragma unroll
  for (int c = 0; c < 16; ++c) Y_[(size_t)e * 16 + c] = Y[c];
  const float u = d / 3.5f;
  u_[e] = u;
  cut_[e] = (u < 1.f) ? 0.5f * (cosf(3.14159265358979323846f * u) + 1.f) : 0.f;
  atomicAdd(&cnt[t], 1);
}

// ---------------- CSR build: scan + fill ----------------
__global__ __launch_bounds__(256) void k_scan(const int* __restrict__ cnt,
                                              int* __restrict__ offs,
                                              int* __restrict__ cursor) {
  __shared__ int part[256];
  const int t = threadIdx.x;
  int s = 0;
  for (int i = 0; i < 32; ++i) s += cnt[t * 32 + i];
  part[t] = s;
  __syncthreads();
  if (t == 0) {
    int run = 0;
    for (int i = 0; i < 256; ++i) { int v = part[i]; part[i] = run; run += v; }
    offs[NN] = run;
  }
  __syncthreads();
  int run = part[t];
  for (int i = 0; i < 32; ++i) {
    const int idx = t * 32 + i;
    offs[idx] = run;
    cursor[idx] = run;
    run += cnt[idx];
  }
}

__global__ __launch_bounds__(256) void k_fill(const int* __restrict__ edst,
                                              int* __restrict__ cursor,
                                              int* __restrict__ elist) {
  const int e = blockIdx.x * 256 + threadIdx.x;
  if (e < NE) {
    const int p = atomicAdd(&cursor[edst[e]], 1);
    elist[p] = e;
  }
}

// ---------------- W2^T bf16 hi/lo prep ----------------
template <bool IS2>
__global__ __launch_bounds__(256) void k_prep_w2t(const float* __restrict__ W2,
                                                  ushort* __restrict__ Th,
                                                  ushort* __restrict__ Tl) {
  const int idx = blockIdx.x * 256 + threadIdx.x;
  if (idx >= 128 * 1024) return;
  const int o = idx >> 10, kf = idx & 1023;
  const float v = IS2 ? W2[(size_t)(kf >> 4) * 2176 + (kf & 15) * 128 + o]
                      : W2[(size_t)kf * 128 + o];
  const ushort h = f2bf(v);
  Th[idx] = h;
  Tl[idx] = (ushort)(__float_as_uint(v - bf2f(h)) >> 16);
}

__global__ __launch_bounds__(256) void k_prep_selfw(const float* __restrict__ W2,
                                                    ushort* __restrict__ Sh,
                                                    ushort* __restrict__ Sl) {
  const int idx = blockIdx.x * 256 + threadIdx.x;
  if (idx >= 128 * 64) return;
  const int o = idx >> 6, k = idx & 63;
  const float v = W2[(size_t)k * 2176 + 2048 + o];
  const ushort h = f2bf(v);
  Sh[idx] = h;
  Sl[idx] = (ushort)(__float_as_uint(v - bf2f(h)) >> 16);
}

// ---------------- per-edge bilinear GEMM via split-bf16 MFMA ----------------
// Block: 32 edges (2 m-tiles), 4 waves; wave w owns n-tiles {2w, 2w+1} (N=32).
// Grid NE/32 = 1024 blocks -> 4 blocks/CU, 16 waves/CU.
template <bool IS2>
__global__ __launch_bounds__(256) void k_msg_mfma(
    const float* __restrict__ u_, const float* __restrict__ cut_,
    const float* __restrict__ W1, const float* __restrict__ bvec,
    const ushort* __restrict__ W2Th, const ushort* __restrict__ W2Tl,
    const ushort* __restrict__ SWh, const ushort* __restrict__ SWl,
    const float* __restrict__ feat16, const int* __restrict__ esrc,
    float* __restrict__ t_, float* __restrict__ self_) {
  __shared__ float hhL[32 * 65];
  __shared__ float nfL[32 * 17];
  __shared__ float uL[32], cL[32];
  __shared__ int sL[32];
  const int tid = threadIdx.x;
  const int e0 = blockIdx.x * 32;
  if (tid < 32) {
    uL[tid] = u_[e0 + tid];
    cL[tid] = cut_[e0 + tid];
    sL[tid] = esrc[e0 + tid];
  }
  __syncthreads();
  for (int i = tid; i < 32 * 64; i += 256) {
    const int e = i >> 6, k = i & 63;
    hhL[e * 65 + k] = fmaxf(fmaf(uL[e], W1[k], bvec[k]), 0.f) * cL[e];
  }
  for (int i = tid; i < 32 * 16; i += 256) {
    const int e = i >> 4, f = i & 15;
    nfL[e * 17 + f] = feat16[(size_t)sL[e] * 16 + f];
  }
  __syncthreads();

  const int lane = tid & 63, wv = tid >> 6;
  const int lr = lane & 15, lg = lane >> 4;
  const int n0 = wv * 2;  // this wave's n-tiles: n0, n0+1

  // ---- self part (msg2 only): self[e,o] = 0.5 * hh @ selfW, K=64
  if (IS2) {
    f32x4 sacc[2][2];
#pragma unroll
    for (int mt = 0; mt < 2; ++mt)
#pragma unroll
      for (int n = 0; n < 2; ++n) {
        f32x4 zz = {0.f, 0.f, 0.f, 0.f};
        sacc[mt][n] = zz;
      }
#pragma unroll
    for (int ks2 = 0; ks2 < 2; ++ks2) {
      short8 ash[2], asl[2];
#pragma unroll
      for (int mt = 0; mt < 2; ++mt) {
        float p[8];
        const float* hp = &hhL[(mt * 16 + lr) * 65 + ks2 * 32 + lg * 8];
#pragma unroll
        for (int j = 0; j < 8; ++j) p[j] = hp[j];
        split8(p, ash[mt], asl[mt]);
      }
#pragma unroll
      for (int n = 0; n < 2; ++n) {
        const short8 bh = *(const short8*)&SWh[((n0 + n) * 16 + lr) * 64 + ks2 * 32 + lg * 8];
        const short8 bl = *(const short8*)&SWl[((n0 + n) * 16 + lr) * 64 + ks2 * 32 + lg * 8];
#pragma unroll
        for (int mt = 0; mt < 2; ++mt) {
          sacc[mt][n] = __builtin_amdgcn_mfma_f32_16x16x32_bf16(ash[mt], bh, sacc[mt][n], 0, 0, 0);
          sacc[mt][n] = __builtin_amdgcn_mfma_f32_16x16x32_bf16(asl[mt], bh, sacc[mt][n], 0, 0, 0);
          sacc[mt][n] = __builtin_amdgcn_mfma_f32_16x16x32_bf16(ash[mt], bl, sacc[mt][n], 0, 0, 0);
        }
      }
    }
#pragma unroll
    for (int mt = 0; mt < 2; ++mt)
#pragma unroll
      for (int n = 0; n < 2; ++n)
#pragma unroll
        for (int i = 0; i < 4; ++i)
          self_[(size_t)(e0 + mt * 16 + lg * 4 + i) * 128 + (n0 + n) * 16 + lr] =
              sacc[mt][n][i] * 0.5f;
  }

  // ---- main: K=1024 over (k,f)
  float nf8[2][8];
#pragma unroll
  for (int mt = 0; mt < 2; ++mt)
#pragma unroll
    for (int j = 0; j < 8; ++j)
      nf8[mt][j] = nfL[(mt * 16 + lr) * 17 + (lg & 1) * 8 + j];

  f32x4 acc[2][2];
#pragma unroll
  for (int mt = 0; mt < 2; ++mt)
#pragma unroll
    for (int n = 0; n < 2; ++n) {
      f32x4 zz = {0.f, 0.f, 0.f, 0.f};
      acc[mt][n] = zz;
    }

  for (int ks = 0; ks < 32; ++ks) {
    short8 ah[2], al[2];
#pragma unroll
    for (int mt = 0; mt < 2; ++mt) {
      const float hs = hhL[(mt * 16 + lr) * 65 + 2 * ks + (lg >> 1)];
      float p[8];
#pragma unroll
      for (int j = 0; j < 8; ++j) p[j] = hs * nf8[mt][j];
      split8(p, ah[mt], al[mt]);
    }
#pragma unroll
    for (int n = 0; n < 2; ++n) {
      const short8 bh = *(const short8*)&W2Th[(size_t)((n0 + n) * 16 + lr) * 1024 + ks * 32 + lg * 8];
      const short8 bl = *(const short8*)&W2Tl[(size_t)((n0 + n) * 16 + lr) * 1024 + ks * 32 + lg * 8];
#pragma unroll
      for (int mt = 0; mt < 2; ++mt) {
        acc[mt][n] = __builtin_amdgcn_mfma_f32_16x16x32_bf16(ah[mt], bh, acc[mt][n], 0, 0, 0);
        acc[mt][n] = __builtin_amdgcn_mfma_f32_16x16x32_bf16(al[mt], bh, acc[mt][n], 0, 0, 0);
        acc[mt][n] = __builtin_amdgcn_mfma_f32_16x16x32_bf16(ah[mt], bl, acc[mt][n], 0, 0, 0);
      }
    }
  }
#pragma unroll
  for (int mt = 0; mt < 2; ++mt)
#pragma unroll
    for (int n = 0; n < 2; ++n)
#pragma unroll
      for (int i = 0; i < 4; ++i)
        t_[(size_t)(e0 + mt * 16 + lg * 4 + i) * 128 + (n0 + n) * 16 + lr] =
            acc[mt][n][i] * 0.125f;  // 1/sqrt(F)/deg
}

// ---------------- gather (segment sum over incoming edges) + gate ----------------
__global__ __launch_bounds__(256) void k_gather1(
    const float* __restrict__ t_, const float* __restrict__ Y_,
    const int* __restrict__ offs, const int* __restrict__ elist,
    float* __restrict__ h1, float* __restrict__ h1s) {
  __shared__ float tL[128], YL[16], sG[32];
  const int n = blockIdx.x, tid = threadIdx.x;
  const int beg = offs[n], end = offs[n + 1];
  const int cc = tid & 15;
  const int lx = lidx_of(cc);
  const int o0 = ((tid >> 4) << 2) + lx;
  const int o1 = o0 + 64;
  float a0 = 0.f, a1 = 0.f;
  for (int ei = beg; ei < end; ++ei) {
    const int e = elist[ei];
    __syncthreads();
    if (tid < 128) tL[tid] = t_[(size_t)e * 128 + tid];
    else if (tid < 144) YL[tid - 128] = Y_[(size_t)e * 16 + tid - 128];
    __syncthreads();
    const float yv = YL[cc];
    a0 = fmaf(tL[o0], yv, a0);
    a1 = fmaf(tL[o1], yv, a1);
  }
  if (cc == 0) { sG[tid >> 4] = a0; sG[(tid >> 4) + 16] = a1; }
  __syncthreads();
  const float s0 = sG[tid >> 4], s1 = sG[(tid >> 4) + 16];
  const float r0 = (cc == 0) ? fmaxf(a0, 0.f) : a0 * (1.f / (1.f + expf(-s0)));
  const float r1 = (cc == 0) ? fmaxf(a1, 0.f) : a1 * (1.f / (1.f + expf(-s1)));
  h1[(size_t)n * 512 + tid] = r0;
  h1[(size_t)n * 512 + tid + 256] = r1;
  if ((tid & 31) == 0) {
    h1s[n * 16 + (tid >> 5)] = r0;       // g = 0..7  (p=0,c=0)
    h1s[n * 16 + (tid >> 5) + 8] = r1;   // g = 8..15
  }
}

__global__ __launch_bounds__(256) void k_gather2(
    const float* __restrict__ t_, const float* __restrict__ self_,
    const float* __restrict__ Y_, const float* __restrict__ h1,
    const int* __restrict__ offs, const int* __restrict__ elist,
    const int* __restrict__ esrc, float* __restrict__ h2) {
  __shared__ float tL[128], wL[128], YL[16], sG[32];
  const int n = blockIdx.x, tid = threadIdx.x;
  const int beg = offs[n], end = offs[n + 1];
  const int cc = tid & 15;
  const int lx = lidx_of(cc);
  const int o0 = ((tid >> 4) << 2) + lx;
  const int o1 = o0 + 64;
  float a0 = 0.f, a1 = 0.f;
  for (int ei = beg; ei < end; ++ei) {
    const int e = elist[ei];
    __syncthreads();
    if (tid < 128) tL[tid] = t_[(size_t)e * 128 + tid];
    else wL[tid - 128] = self_[(size_t)e * 128 + tid - 128];
    if (tid < 16) YL[tid] = Y_[(size_t)e * 16 + tid];
    __syncthreads();
    const int src = esrc[e];
    const float* hr = &h1[(size_t)src * 512];
    const float yv = YL[cc];
    a0 += tL[o0] * yv + hr[tid] * wL[o0];
    a1 += tL[o1] * yv + hr[tid + 256] * wL[o1];
  }
  if (cc == 0) { sG[tid >> 4] = a0; sG[(tid >> 4) + 16] = a1; }
  __syncthreads();
  const float s0 = sG[tid >> 4], s1 = sG[(tid >> 4) + 16];
  const float r0 = (cc == 0) ? fmaxf(a0, 0.f) : a0 * (1.f / (1.f + expf(-s0)));
  const float r1 = (cc == 0) ? fmaxf(a1, 0.f) : a1 * (1.f / (1.f + expf(-s1)));
  h2[(size_t)n * 512 + tid] = r0;
  h2[(size_t)n * 512 + tid + 256] = r1;
}

// ---------------- mean pool over each graph's 256 nodes ----------------
__global__ __launch_bounds__(256) void k_pool(const float* __restrict__ h2,
                                              float* __restrict__ enc) {
  const int b = blockIdx.x, tid = threadIdx.x;
  float a0 = 0.f, a1 = 0.f;
  for (int i = 0; i < 256; ++i) {
    const float* row = &h2[(size_t)(b * 256 + i) * 512];
    a0 += row[tid];
    a1 += row[tid + 256];
  }
  enc[b * 512 + tid] = a0 * (1.f / 256.f);
  enc[b * 512 + tid + 256] = a1 * (1.f / 256.f);
}

// ---------------- z = per-l linear mix of enc (B,32,16) -> (B,16,84) ----------------
__global__ __launch_bounds__(256) void k_zproj(const float* __restrict__ enc,
                                               const float* __restrict__ Wlin,
                                               float* __restrict__ z) {
  __shared__ float eL[512];
  const int b = blockIdx.x, tid = threadIdx.x;
  eL[tid] = enc[b * 512 + tid];
  eL[tid + 256] = enc[b * 512 + tid + 256];
  __syncthreads();
  for (int idx = tid; idx < 16 * 84; idx += 256) {
    const int g = idx / 84, d3 = idx % 84;
    int o0, m0, mo;
    if (d3 < 1)       { o0 = 0;  m0 = 1; mo = 0; }
    else if (d3 < 10) { o0 = 1;  m0 = 3; mo = 1; }
    else if (d3 < 35) { o0 = 10; m0 = 5; mo = 4; }
    else              { o0 = 35; m0 = 7; mo = 9; }
    const int rem = d3 - o0;
    const int jj = rem / m0;
    const int cc2 = rem - jj * m0;
    float a = 0.f;
    for (int mu = 0; mu < 32; ++mu)
      a = fmaf(eL[mu * 16 + mo + cc2], Wlin[(mu * 16 + g) * 16 + mo + jj], a);
    z[(size_t)(b * 16 + g) * 84 + d3] = a * 0.17677669529663687f;  // 1/sqrt(32)
  }
}

// ---------------- SO3 conv: per-l matmul ----------------
template <int M, int FI, int FO>
DEV void conv_item(const float* xL, const float* __restrict__ psi, int b, int g,
                   int o0, int j, float* __restrict__ out, float scale) {
  float acc[M];
#pragma unroll
  for (int c = 0; c < M; ++c) acc[c] = 0.f;
  for (int f = 0; f < FI; ++f) {
    const float* xr = &xL[f * 84 + o0];
    const float* pr = &psi[((size_t)f * FO + g) * 84 + o0 + j];
#pragma unroll
    for (int i = 0; i < M; ++i) {
      const float pv = pr[i * M];
#pragma unroll
      for (int c = 0; c < M; ++c) acc[c] = fmaf(xr[i * M + c], pv, acc[c]);
    }
  }
  float* op = &out[((size_t)b * FO + g) * 84 + o0 + j * M];
#pragma unroll
  for (int c = 0; c < M; ++c) op[c] = acc[c] * scale;
}

template <int FI, int FO>
__global__ __launch_bounds__(256) void k_conv(const float* __restrict__ x,
                                              const float* __restrict__ psi,
                                              float* __restrict__ out) {
  __shared__ float xL[FI * 84];
  const int tid = threadIdx.x, b = blockIdx.x;
  for (int i = tid; i < FI * 84; i += 256) xL[i] = x[(size_t)b * FI * 84 + i];
  __syncthreads();
  const int g0 = blockIdx.y * 16;
  if (tid < 16) {
    conv_item<1, FI, FO>(xL, psi, b, g0 + tid, 0, 0, out, 1.f / sqrtf((float)(FI * 1)));
  } else if (tid < 64) {
    const int q = tid - 16;
    conv_item<3, FI, FO>(xL, psi, b, g0 + q / 3, 1, q % 3, out, 1.f / sqrtf((float)(FI * 3)));
  } else if (tid < 144) {
    const int q = tid - 64;
    conv_item<5, FI, FO>(xL, psi, b, g0 + q / 5, 10, q % 5, out, 1.f / sqrtf((float)(FI * 5)));
  } else {
    const int q = tid - 144;
    conv_item<7, FI, FO>(xL, psi, b, g0 + q / 7, 35, q % 7, out, 1.f / sqrtf((float)(FI * 7)));
  }
}

// ---------------- weight prep for MFMA act ----------------
__global__ __launch_bounds__(256) void k_prep_gt(const float* __restrict__ Gt,
                                                 ushort* __restrict__ GtT) {
  const int idx = blockIdx.x * 256 + threadIdx.x;
  if (idx >= 4096 * 96) return;
  const int g = idx / 96, k = idx % 96;
  GtT[idx] = (k < 84) ? f2bf(Gt[(size_t)k * 4096 + g]) : (ushort)0;
}
__global__ __launch_bounds__(256) void k_prep_gf(const float* __restrict__ Gf,
                                                 ushort* __restrict__ GfT) {
  const int idx = blockIdx.x * 256 + threadIdx.x;
  if (idx >= 96 * 4096) return;
  const int d = idx / 4096, g = idx % 4096;
  GfT[idx] = (d < 84) ? f2bf(Gf[(size_t)g * 84 + d]) : (ushort)0;
}
__global__ __launch_bounds__(256) void k_cvtx(const float* __restrict__ x,
                                              ushort* __restrict__ Xb, int total) {
  const int idx = blockIdx.x * 256 + threadIdx.x;
  if (idx >= total) return;
  const int r = idx / 96, k = idx % 96;
  Xb[idx] = (k < 84) ? f2bf(x[(size_t)r * 84 + k]) : (ushort)0;
}

// ---------------- SO3 act via bf16 MFMA (fused, g-split partials) ----------------
template <int GS>
__global__ __launch_bounds__(256) void k_act_mfma(
    const ushort* __restrict__ Xb, const ushort* __restrict__ GtT,
    const ushort* __restrict__ GfT, float* __restrict__ part, int NR) {
  constexpr int CPB = 64 / GS;
  __shared__ __align__(16) ushort ldsGt[64 * 104];  // [g][k pad 104]
  __shared__ __align__(16) ushort ldsH[128 * 72];   // [row][g pad 72]
  __shared__ __align__(16) ushort ldsGf[96 * 72];   // [d][g pad 72]
  const int tid = threadIdx.x;
  const int row0 = blockIdx.x * 128;
  const int gs = blockIdx.y;
  const int lane = tid & 63, wv = tid >> 6;
  const int lr = lane & 15, lg = lane >> 4;
  const int m0 = wv * 32;

  short8 a1[2][3];
#pragma unroll
  for (int mt = 0; mt < 2; ++mt)
#pragma unroll
    for (int ks = 0; ks < 3; ++ks)
      a1[mt][ks] = *(const short8*)&Xb[(size_t)(row0 + m0 + mt * 16 + lr) * 96 +
                                       ks * 32 + lg * 8];

  f32x4 acc2[6][2];
#pragma unroll
  for (int m2 = 0; m2 < 6; ++m2)
#pragma unroll
    for (int n2 = 0; n2 < 2; ++n2) {
      f32x4 zz = {0.f, 0.f, 0.f, 0.f};
      acc2[m2][n2] = zz;
    }

  for (int ch = gs * CPB; ch < (gs + 1) * CPB; ++ch) {
    const int g0 = ch * 64;
    __syncthreads();
    for (int i = tid; i < 768; i += 256) {
      const int row = i / 12, c = i % 12;
      *(uint4*)&ldsGt[row * 104 + c * 8] =
          *(const uint4*)&GtT[(size_t)(g0 + row) * 96 + c * 8];
    }
    for (int i = tid; i < 768; i += 256) {
      const int row = i / 8, c = i % 8;
      *(uint4*)&ldsGf[row * 72 + c * 8] =
          *(const uint4*)&GfT[(size_t)row * 4096 + g0 + c * 8];
    }
    __syncthreads();
#pragma unroll
    for (int n = 0; n < 4; ++n) {
      short8 b[3];
#pragma unroll
      for (int ks = 0; ks < 3; ++ks)
        b[ks] = *(const short8*)&ldsGt[(n * 16 + lr) * 104 + ks * 32 + lg * 8];
#pragma unroll
      for (int mt = 0; mt < 2; ++mt) {
        f32x4 c1 = {0.f, 0.f, 0.f, 0.f};
#pragma unroll
        for (int ks = 0; ks < 3; ++ks)
          c1 = __builtin_amdgcn_mfma_f32_16x16x32_bf16(a1[mt][ks], b[ks], c1, 0, 0, 0);
        ushort* hp = &ldsH[(m0 + mt * 16 + lg * 4) * 72 + n * 16 + lr];
#pragma unroll
        for (int i = 0; i < 4; ++i) hp[i * 72] = f2bf(fmaxf(c1[i], 0.f));
      }
    }
#pragma unroll
    for (int k2 = 0; k2 < 2; ++k2) {
      short8 bh[2];
#pragma unroll
      for (int n2 = 0; n2 < 2; ++n2)
        bh[n2] = *(const short8*)&ldsH[(m0 + n2 * 16 + lr) * 72 + k2 * 32 + lg * 8];
#pragma unroll
      for (int m2 = 0; m2 < 6; ++m2) {
        const short8 a2 = *(const short8*)&ldsGf[(m2 * 16 + lr) * 72 + k2 * 32 + lg * 8];
        acc2[m2][0] = __builtin_amdgcn_mfma_f32_16x16x32_bf16(a2, bh[0], acc2[m2][0], 0, 0, 0);
        acc2[m2][1] = __builtin_amdgcn_mfma_f32_16x16x32_bf16(a2, bh[1], acc2[m2][1], 0, 0, 0);
      }
    }
  }
#pragma unroll
  for (int m2 = 0; m2 < 6; ++m2)
#pragma unroll
    for (int n2 = 0; n2 < 2; ++n2)
#pragma unroll
      for (int i = 0; i < 4; ++i) {
        const int d = m2 * 16 + lg * 4 + i;
        if (d < 84) {
          const int r = row0 + m0 + n2 * 16 + lr;
          part[((size_t)gs * NR + r) * 84 + d] = acc2[m2][n2][i];
        }
      }
}

template <int GS>
__global__ __launch_bounds__(256) void k_act_reduce(const float* __restrict__ part,
                                                    float* __restrict__ out, int total) {
  const int i = blockIdx.x * 256 + threadIdx.x;
  if (i < total) {
    float s = part[i];
#pragma unroll
    for (int g = 1; g < GS; ++g) s += part[(size_t)g * total + i];
    out[i] = s * (1.f / (9.16515138991168f * 64.f));  // 1/(sqrt(84)*64)
  }
}

// ---------------- final: Ws2 contraction + orientation SH dot ----------------
__global__ __launch_bounds__(256) void k_final(const float* __restrict__ x,
                                               const float* __restrict__ Ws2,
                                               const float* __restrict__ orient,
                                               float* __restrict__ outp) {
  __shared__ float red[256][16];
  const int b = blockIdx.x, tid = threadIdx.x;
  const float* xr = &x[(size_t)(b * 256 + tid) * 84];
  const float* wr = &Ws2[tid * 16];
  float acc[16];
#pragma unroll
  for (int c = 0; c < 16; ++c) acc[c] = 0.f;
  acc[0] = fmaf(xr[0], wr[0], acc[0]);
#pragma unroll
  for (int i = 0; i < 3; ++i) {
    const float w = wr[1 + i];
#pragma unroll
    for (int c = 0; c < 3; ++c) acc[1 + c] = fmaf(xr[1 + i * 3 + c], w, acc[1 + c]);
  }
#pragma unroll
  for (int i = 0; i < 5; ++i) {
    const float w = wr[4 + i];
#pragma unroll
    for (int c = 0; c < 5; ++c) acc[4 + c] = fmaf(xr[10 + i * 5 + c], w, acc[4 + c]);
  }
#pragma unroll
  for (int i = 0; i < 7; ++i) {
    const float w = wr[9 + i];
#pragma unroll
    for (int c = 0; c < 7; ++c) acc[9 + c] = fmaf(xr[35 + i * 7 + c], w, acc[9 + c]);
  }
#pragma unroll
  for (int c = 0; c < 16; ++c) red[tid][c] = acc[c];
  __syncthreads();
  for (int off = 128; off > 0; off >>= 1) {
    if (tid < off)
#pragma unroll
      for (int c = 0; c < 16; ++c) red[tid][c] += red[tid + off][c];
    __syncthreads();
  }
  if (tid == 0) {
    const float aa = orient[b * 2 + 0], rr = orient[b * 2 + 1];
    float Y[16];
    real_sh_f(-sinf(aa) * cosf(rr), -sinf(aa) * sinf(rr), -cosf(aa), Y);
    const float sc1 = 1.f / 16.f;
    const float sc3 = 1.f / (16.f * 1.7320508075688772f);
    const float sc5 = 1.f / (16.f * 2.23606797749979f);
    const float sc7 = 1.f / (16.f * 2.6457513110645907f);
    float o = red[0][0] * sc1 * Y[0];
#pragma unroll
    for (int c = 1; c < 4; ++c) o += red[0][c] * sc3 * Y[c];
#pragma unroll
    for (int c = 4; c < 9; ++c) o += red[0][c] * sc5 * Y[c];
#pragma unroll
    for (int c = 9; c < 16; ++c) o += red[0][c] * sc7 * Y[c];
    outp[b] = o;
  }
}

extern "C" void kernel_launch(void* const* d_in, const int* in_sizes, int n_in,
                              void* d_out, int out_size, void* d_ws, size_t ws_size,
                              hipStream_t stream) {
  const float* node_feat = (const float*)d_in[0];
  const float* pos       = (const float*)d_in[1];
  const float* orient    = (const float*)d_in[2];
  const float* rad1_W1   = (const float*)d_in[3];
  const float* rad1_b    = (const float*)d_in[4];
  const float* rad1_W2   = (const float*)d_in[5];
  const float* rad2_W1   = (const float*)d_in[6];
  const float* rad2_b    = (const float*)d_in[7];
  const float* rad2_W2   = (const float*)d_in[8];
  const float* Wlin      = (const float*)d_in[9];
  const float* psi1      = (const float*)d_in[10];
  const float* psi2      = (const float*)d_in[11];
  const float* psi3      = (const float*)d_in[12];
  const float* G_to      = (const float*)d_in[13];
  const float* G_from    = (const float*)d_in[14];
  const float* Ws2       = (const float*)d_in[15];
  const int*   esrc      = (const int*)d_in[16];
  const int*   edst      = (const int*)d_in[17];

  float* w = (float*)d_ws;
  size_t off = 0;
  float* u_    = w + off; off += NE;
  float* cut_  = w + off; off += NE;
  float* Y_    = w + off; off += (size_t)NE * 16;
  float* t_    = w + off; off += (size_t)NE * 128;   // t1/t2; later act partials
  float* self_ = w + off; off += (size_t)NE * 128;   // msg2 self; partial overflow
  float* h1    = w + off; off += (size_t)NN * 512;   // later: GtT/GfT/Xb (bf16)
  float* h1s   = w + off; off += (size_t)NN * 16;
  float* h2    = w + off; off += (size_t)NN * 512;
  float* enc   = w + off; off += (size_t)NB * 512;
  float* z     = w + off; off += (size_t)NB * 16 * 84;
  float* xb1   = w + off; off += (size_t)NB * 256 * 84;
  float* xb2   = w + off; off += (size_t)NB * 256 * 84;
  int* cnt    = (int*)(w + off); off += NN;
  int* offs   = (int*)(w + off); off += NN + 1;
  int* cursor = (int*)(w + off); off += NN;
  int* elist  = (int*)(w + off); off += NE;
  ushort* W2Th = (ushort*)(w + off); off += 65536;   // 128x1024 bf16
  ushort* W2Tl = (ushort*)(w + off); off += 65536;
  ushort* SWh  = (ushort*)(w + off); off += 4096;    // 128x64 bf16
  ushort* SWl  = (ushort*)(w + off); off += 4096;

  // act-time reuse of dead buffers:
  float* part = t_;                 // spans t_ + self_ (both dead by act time)
  ushort* GtT = (ushort*)h1;        // 4096*96 bf16
  ushort* GfT = GtT + 4096 * 96;    // 96*4096 bf16
  ushort* Xb  = GfT + 96 * 4096;    // up to 8192*96 bf16

  hipMemsetAsync(cnt, 0, NN * sizeof(int), stream);
  k_edge_prep<<<NE / 256, 256, 0, stream>>>(pos, esrc, edst, u_, cut_, Y_, cnt);
  k_scan<<<1, 256, 0, stream>>>(cnt, offs, cursor);
  k_fill<<<NE / 256, 256, 0, stream>>>(edst, cursor, elist);

  k_prep_w2t<false><<<512, 256, 0, stream>>>(rad1_W2, W2Th, W2Tl);
  k_msg_mfma<false><<<NE / 32, 256, 0, stream>>>(u_, cut_, rad1_W1, rad1_b, W2Th, W2Tl,
                                                 nullptr, nullptr, node_feat, esrc,
                                                 t_, nullptr);
  k_gather1<<<NN, 256, 0, stream>>>(t_, Y_, offs, elist, h1, h1s);

  k_prep_w2t<true><<<512, 256, 0, stream>>>(rad2_W2, W2Th, W2Tl);
  k_prep_selfw<<<32, 256, 0, stream>>>(rad2_W2, SWh, SWl);
  k_msg_mfma<true><<<NE / 32, 256, 0, stream>>>(u_, cut_, rad2_W1, rad2_b, W2Th, W2Tl,
                                                SWh, SWl, h1s, esrc, t_, self_);
  k_gather2<<<NN, 256, 0, stream>>>(t_, self_, Y_, h1, offs, elist, esrc, h2);
  k_pool<<<NB, 256, 0, stream>>>(h2, enc);
  k_zproj<<<NB, 256, 0, stream>>>(enc, Wlin, z);

  k_prep_gt<<<(4096 * 96 + 255) / 256, 256, 0, stream>>>(G_to, GtT);
  k_prep_gf<<<(96 * 4096 + 255) / 256, 256, 0, stream>>>(G_from, GfT);

  k_conv<16, 64><<<dim3(NB, 4), 256, 0, stream>>>(z, psi1, xb1);
  k_cvtx<<<(2048 * 96 + 255) / 256, 256, 0, stream>>>(xb1, Xb, 2048 * 96);
  k_act_mfma<32><<<dim3(16, 32), 256, 0, stream>>>(Xb, GtT, GfT, part, 2048);
  k_act_reduce<32><<<(2048 * 84 + 255) / 256, 256, 0, stream>>>(part, xb2, 2048 * 84);

  k_conv<64, 128><<<dim3(NB, 8), 256, 0, stream>>>(xb2, psi2, xb1);
  k_cvtx<<<(4096 * 96 + 255) / 256, 256, 0, stream>>>(xb1, Xb, 4096 * 96);
  k_act_mfma<16><<<dim3(32, 16), 256, 0, stream>>>(Xb, GtT, GfT, part, 4096);
  k_act_reduce<16><<<(4096 * 84 + 255) / 256, 256, 0, stream>>>(part, xb2, 4096 * 84);

  k_conv<128, 256><<<dim3(NB, 16), 256, 0, stream>>>(xb2, psi3, xb1);
  k_cvtx<<<(8192 * 96 + 255) / 256, 256, 0, stream>>>(xb1, Xb, 8192 * 96);
  k_act_mfma<8><<<dim3(64, 8), 256, 0, stream>>>(Xb, GtT, GfT, part, 8192);
  k_act_reduce<8><<<(8192 * 84 + 255) / 256, 256, 0, stream>>>(part, xb2, 8192 * 84);

  k_final<<<NB, 256, 0, stream>>>(xb2, Ws2, orient, (float*)d_out);
}

// Round 8
// 468.823 us; speedup vs baseline: 2.2084x; 1.0063x over previous
//
#include <hip/hip_runtime.h>
#include <math.h>

#define DEV static __device__ __forceinline__

constexpr int NN = 8192;    // nodes
constexpr int NE = 32768;   // edges
constexpr int NB = 32;      // graphs

using short8 = __attribute__((ext_vector_type(8))) short;
using f32x4  = __attribute__((ext_vector_type(4))) float;

DEV ushort f2bf(float f) {  // round-to-nearest-even f32 -> bf16 bits
  unsigned u = __float_as_uint(f);
  unsigned r = (u + 0x7FFFu + ((u >> 16) & 1u)) >> 16;
  return (ushort)r;
}
DEV float bf2f(ushort h) { return __uint_as_float(((unsigned)h) << 16); }

// split p[8] into bf16 hi + bf16 residual
DEV void split8(const float* p, short8& hi, short8& lo) {
#pragma unroll
  for (int j = 0; j < 8; ++j) {
    const ushort h = f2bf(p[j]);
    hi[j] = (short)h;
    const float r = p[j] - bf2f(h);
    lo[j] = (short)(__float_as_uint(r) >> 16);
  }
}

DEV int lidx_of(int c) { return (c == 0) ? 0 : (c < 4) ? 1 : (c < 9) ? 2 : 3; }

DEV void real_sh_f(float x, float y, float z, float* Y) {
  const float s3  = 1.7320508075688772f;
  const float s5  = 2.23606797749979f;
  const float s15 = 3.872983346207417f;
  Y[0] = 1.f;
  Y[1] = s3 * y;  Y[2] = s3 * z;  Y[3] = s3 * x;
  Y[4] = s15 * x * y;
  Y[5] = s15 * y * z;
  Y[6] = 0.5f * s5 * (3.f * z * z - 1.f);
  Y[7] = s15 * x * z;
  Y[8] = 0.5f * s15 * (x * x - y * y);
  Y[9]  = 2.091650066335189f * y * (3.f * x * x - y * y);
  Y[10] = 10.246950765959598f * x * y * z;
  Y[11] = 1.6201851746019651f * y * (5.f * z * z - 1.f);
  Y[12] = 1.3228756555322954f * (5.f * z * z * z - 3.f * z);
  Y[13] = 1.6201851746019651f * x * (5.f * z * z - 1.f);
  Y[14] = 5.123475382979799f * (x * x - y * y) * z;
  Y[15] = 2.091650066335189f * x * (x * x - 3.f * y * y);
}

// ---------------- edge geometry: Y, u, cut + degree histogram ----------------
__global__ __launch_bounds__(256) void k_edge_prep(
    const float* __restrict__ pos, const int* __restrict__ esrc,
    const int* __restrict__ edst, float* __restrict__ u_, float* __restrict__ cut_,
    float* __restrict__ Y_, int* __restrict__ cnt) {
  const int e = blockIdx.x * 256 + threadIdx.x;
  if (e >= NE) return;
  const int s = esrc[e], t = edst[e];
  const float ex = pos[t * 3 + 0] - pos[s * 3 + 0];
  const float ey = pos[t * 3 + 1] - pos[s * 3 + 1];
  const float ez = pos[t * 3 + 2] - pos[s * 3 + 2];
  const float d = sqrtf(ex * ex + ey * ey + ez * ez) + 1e-9f;
  const float inv = 1.f / d;
  float Y[16];
  real_sh_f(ex * inv, ey * inv, ez * inv, Y);
#pragma unroll
  for (int c = 0; c < 16; ++c) Y_[(size_t)e * 16 + c] = Y[c];
  const float u = d / 3.5f;
  u_[e] = u;
  cut_[e] = (u < 1.f) ? 0.5f * (cosf(3.14159265358979323846f * u) + 1.f) : 0.f;
  atomicAdd(&cnt[t], 1);
}

// ---------------- CSR build: scan + fill ----------------
__global__ __launch_bounds__(256) void k_scan(const int* __restrict__ cnt,
                                              int* __restrict__ offs,
                                              int* __restrict__ cursor) {
  __shared__ int part[256];
  const int t = threadIdx.x;
  int s = 0;
  for (int i = 0; i < 32; ++i) s += cnt[t * 32 + i];
  part[t] = s;
  __syncthreads();
  if (t == 0) {
    int run = 0;
    for (int i = 0; i < 256; ++i) { int v = part[i]; part[i] = run; run += v; }
    offs[NN] = run;
  }
  __syncthreads();
  int run = part[t];
  for (int i = 0; i < 32; ++i) {
    const int idx = t * 32 + i;
    offs[idx] = run;
    cursor[idx] = run;
    run += cnt[idx];
  }
}

__global__ __launch_bounds__(256) void k_fill(const int* __restrict__ edst,
                                              int* __restrict__ cursor,
                                              int* __restrict__ elist) {
  const int e = blockIdx.x * 256 + threadIdx.x;
  if (e < NE) {
    const int p = atomicAdd(&cursor[edst[e]], 1);
    elist[p] = e;
  }
}

// ---------------- W2^T bf16 hi/lo prep ----------------
template <bool IS2>
__global__ __launch_bounds__(256) void k_prep_w2t(const float* __restrict__ W2,
                                                  ushort* __restrict__ Th,
                                                  ushort* __restrict__ Tl) {
  const int idx = blockIdx.x * 256 + threadIdx.x;
  if (idx >= 128 * 1024) return;
  const int o = idx >> 10, kf = idx & 1023;
  const float v = IS2 ? W2[(size_t)(kf >> 4) * 2176 + (kf & 15) * 128 + o]
                      : W2[(size_t)kf * 128 + o];
  const ushort h = f2bf(v);
  Th[idx] = h;
  Tl[idx] = (ushort)(__float_as_uint(v - bf2f(h)) >> 16);
}

__global__ __launch_bounds__(256) void k_prep_selfw(const float* __restrict__ W2,
                                                    ushort* __restrict__ Sh,
                                                    ushort* __restrict__ Sl) {
  const int idx = blockIdx.x * 256 + threadIdx.x;
  if (idx >= 128 * 64) return;
  const int o = idx >> 6, k = idx & 63;
  const float v = W2[(size_t)k * 2176 + 2048 + o];
  const ushort h = f2bf(v);
  Sh[idx] = h;
  Sl[idx] = (ushort)(__float_as_uint(v - bf2f(h)) >> 16);
}

// ---------------- per-edge bilinear GEMM via split-bf16 MFMA ----------------
template <bool IS2>
__global__ __launch_bounds__(256) void k_msg_mfma(
    const float* __restrict__ u_, const float* __restrict__ cut_,
    const float* __restrict__ W1, const float* __restrict__ bvec,
    const ushort* __restrict__ W2Th, const ushort* __restrict__ W2Tl,
    const ushort* __restrict__ SWh, const ushort* __restrict__ SWl,
    const float* __restrict__ feat16, const int* __restrict__ esrc,
    float* __restrict__ t_, float* __restrict__ self_) {
  __shared__ float hhL[32 * 65];
  __shared__ float nfL[32 * 17];
  __shared__ float uL[32], cL[32];
  __shared__ int sL[32];
  const int tid = threadIdx.x;
  const int e0 = blockIdx.x * 32;
  if (tid < 32) {
    uL[tid] = u_[e0 + tid];
    cL[tid] = cut_[e0 + tid];
    sL[tid] = esrc[e0 + tid];
  }
  __syncthreads();
  for (int i = tid; i < 32 * 64; i += 256) {
    const int e = i >> 6, k = i & 63;
    hhL[e * 65 + k] = fmaxf(fmaf(uL[e], W1[k], bvec[k]), 0.f) * cL[e];
  }
  for (int i = tid; i < 32 * 16; i += 256) {
    const int e = i >> 4, f = i & 15;
    nfL[e * 17 + f] = feat16[(size_t)sL[e] * 16 + f];
  }
  __syncthreads();

  const int lane = tid & 63, wv = tid >> 6;
  const int lr = lane & 15, lg = lane >> 4;
  const int n0 = wv * 2;  // this wave's n-tiles: n0, n0+1

  if (IS2) {
    f32x4 sacc[2][2];
#pragma unroll
    for (int mt = 0; mt < 2; ++mt)
#pragma unroll
      for (int n = 0; n < 2; ++n) {
        f32x4 zz = {0.f, 0.f, 0.f, 0.f};
        sacc[mt][n] = zz;
      }
#pragma unroll
    for (int ks2 = 0; ks2 < 2; ++ks2) {
      short8 ash[2], asl[2];
#pragma unroll
      for (int mt = 0; mt < 2; ++mt) {
        float p[8];
        const float* hp = &hhL[(mt * 16 + lr) * 65 + ks2 * 32 + lg * 8];
#pragma unroll
        for (int j = 0; j < 8; ++j) p[j] = hp[j];
        split8(p, ash[mt], asl[mt]);
      }
#pragma unroll
      for (int n = 0; n < 2; ++n) {
        const short8 bh = *(const short8*)&SWh[((n0 + n) * 16 + lr) * 64 + ks2 * 32 + lg * 8];
        const short8 bl = *(const short8*)&SWl[((n0 + n) * 16 + lr) * 64 + ks2 * 32 + lg * 8];
#pragma unroll
        for (int mt = 0; mt < 2; ++mt) {
          sacc[mt][n] = __builtin_amdgcn_mfma_f32_16x16x32_bf16(ash[mt], bh, sacc[mt][n], 0, 0, 0);
          sacc[mt][n] = __builtin_amdgcn_mfma_f32_16x16x32_bf16(asl[mt], bh, sacc[mt][n], 0, 0, 0);
          sacc[mt][n] = __builtin_amdgcn_mfma_f32_16x16x32_bf16(ash[mt], bl, sacc[mt][n], 0, 0, 0);
        }
      }
    }
#pragma unroll
    for (int mt = 0; mt < 2; ++mt)
#pragma unroll
      for (int n = 0; n < 2; ++n)
#pragma unroll
        for (int i = 0; i < 4; ++i)
          self_[(size_t)(e0 + mt * 16 + lg * 4 + i) * 128 + (n0 + n) * 16 + lr] =
              sacc[mt][n][i] * 0.5f;
  }

  float nf8[2][8];
#pragma unroll
  for (int mt = 0; mt < 2; ++mt)
#pragma unroll
    for (int j = 0; j < 8; ++j)
      nf8[mt][j] = nfL[(mt * 16 + lr) * 17 + (lg & 1) * 8 + j];

  f32x4 acc[2][2];
#pragma unroll
  for (int mt = 0; mt < 2; ++mt)
#pragma unroll
    for (int n = 0; n < 2; ++n) {
      f32x4 zz = {0.f, 0.f, 0.f, 0.f};
      acc[mt][n] = zz;
    }

  for (int ks = 0; ks < 32; ++ks) {
    short8 ah[2], al[2];
#pragma unroll
    for (int mt = 0; mt < 2; ++mt) {
      const float hs = hhL[(mt * 16 + lr) * 65 + 2 * ks + (lg >> 1)];
      float p[8];
#pragma unroll
      for (int j = 0; j < 8; ++j) p[j] = hs * nf8[mt][j];
      split8(p, ah[mt], al[mt]);
    }
#pragma unroll
    for (int n = 0; n < 2; ++n) {
      const short8 bh = *(const short8*)&W2Th[(size_t)((n0 + n) * 16 + lr) * 1024 + ks * 32 + lg * 8];
      const short8 bl = *(const short8*)&W2Tl[(size_t)((n0 + n) * 16 + lr) * 1024 + ks * 32 + lg * 8];
#pragma unroll
      for (int mt = 0; mt < 2; ++mt) {
        acc[mt][n] = __builtin_amdgcn_mfma_f32_16x16x32_bf16(ah[mt], bh, acc[mt][n], 0, 0, 0);
        acc[mt][n] = __builtin_amdgcn_mfma_f32_16x16x32_bf16(al[mt], bh, acc[mt][n], 0, 0, 0);
        acc[mt][n] = __builtin_amdgcn_mfma_f32_16x16x32_bf16(ah[mt], bl, acc[mt][n], 0, 0, 0);
      }
    }
  }
#pragma unroll
  for (int mt = 0; mt < 2; ++mt)
#pragma unroll
    for (int n = 0; n < 2; ++n)
#pragma unroll
      for (int i = 0; i < 4; ++i)
        t_[(size_t)(e0 + mt * 16 + lg * 4 + i) * 128 + (n0 + n) * 16 + lr] =
            acc[mt][n][i] * 0.125f;  // 1/sqrt(F)/deg
}

// ---------------- gather (segment sum over incoming edges) + gate ----------------
__global__ __launch_bounds__(256) void k_gather1(
    const float* __restrict__ t_, const float* __restrict__ Y_,
    const int* __restrict__ offs, const int* __restrict__ elist,
    float* __restrict__ h1, float* __restrict__ h1s) {
  __shared__ float tL[128], YL[16], sG[32];
  const int n = blockIdx.x, tid = threadIdx.x;
  const int beg = offs[n], end = offs[n + 1];
  const int cc = tid & 15;
  const int lx = lidx_of(cc);
  const int o0 = ((tid >> 4) << 2) + lx;
  const int o1 = o0 + 64;
  float a0 = 0.f, a1 = 0.f;
  for (int ei = beg; ei < end; ++ei) {
    const int e = elist[ei];
    __syncthreads();
    if (tid < 128) tL[tid] = t_[(size_t)e * 128 + tid];
    else if (tid < 144) YL[tid - 128] = Y_[(size_t)e * 16 + tid - 128];
    __syncthreads();
    const float yv = YL[cc];
    a0 = fmaf(tL[o0], yv, a0);
    a1 = fmaf(tL[o1], yv, a1);
  }
  if (cc == 0) { sG[tid >> 4] = a0; sG[(tid >> 4) + 16] = a1; }
  __syncthreads();
  const float s0 = sG[tid >> 4], s1 = sG[(tid >> 4) + 16];
  const float r0 = (cc == 0) ? fmaxf(a0, 0.f) : a0 * (1.f / (1.f + expf(-s0)));
  const float r1 = (cc == 0) ? fmaxf(a1, 0.f) : a1 * (1.f / (1.f + expf(-s1)));
  h1[(size_t)n * 512 + tid] = r0;
  h1[(size_t)n * 512 + tid + 256] = r1;
  if ((tid & 31) == 0) {
    h1s[n * 16 + (tid >> 5)] = r0;       // g = 0..7  (p=0,c=0)
    h1s[n * 16 + (tid >> 5) + 8] = r1;   // g = 8..15
  }
}

__global__ __launch_bounds__(256) void k_gather2(
    const float* __restrict__ t_, const float* __restrict__ self_,
    const float* __restrict__ Y_, const float* __restrict__ h1,
    const int* __restrict__ offs, const int* __restrict__ elist,
    const int* __restrict__ esrc, float* __restrict__ h2) {
  __shared__ float tL[128], wL[128], YL[16], sG[32];
  const int n = blockIdx.x, tid = threadIdx.x;
  const int beg = offs[n], end = offs[n + 1];
  const int cc = tid & 15;
  const int lx = lidx_of(cc);
  const int o0 = ((tid >> 4) << 2) + lx;
  const int o1 = o0 + 64;
  float a0 = 0.f, a1 = 0.f;
  for (int ei = beg; ei < end; ++ei) {
    const int e = elist[ei];
    __syncthreads();
    if (tid < 128) tL[tid] = t_[(size_t)e * 128 + tid];
    else wL[tid - 128] = self_[(size_t)e * 128 + tid - 128];
    if (tid < 16) YL[tid] = Y_[(size_t)e * 16 + tid];
    __syncthreads();
    const int src = esrc[e];
    const float* hr = &h1[(size_t)src * 512];
    const float yv = YL[cc];
    a0 += tL[o0] * yv + hr[tid] * wL[o0];
    a1 += tL[o1] * yv + hr[tid + 256] * wL[o1];
  }
  if (cc == 0) { sG[tid >> 4] = a0; sG[(tid >> 4) + 16] = a1; }
  __syncthreads();
  const float s0 = sG[tid >> 4], s1 = sG[(tid >> 4) + 16];
  const float r0 = (cc == 0) ? fmaxf(a0, 0.f) : a0 * (1.f / (1.f + expf(-s0)));
  const float r1 = (cc == 0) ? fmaxf(a1, 0.f) : a1 * (1.f / (1.f + expf(-s1)));
  h2[(size_t)n * 512 + tid] = r0;
  h2[(size_t)n * 512 + tid + 256] = r1;
}

// ---------------- mean pool over each graph's 256 nodes ----------------
__global__ __launch_bounds__(256) void k_pool(const float* __restrict__ h2,
                                              float* __restrict__ enc) {
  const int b = blockIdx.x, tid = threadIdx.x;
  float a0 = 0.f, a1 = 0.f;
  for (int i = 0; i < 256; ++i) {
    const float* row = &h2[(size_t)(b * 256 + i) * 512];
    a0 += row[tid];
    a1 += row[tid + 256];
  }
  enc[b * 512 + tid] = a0 * (1.f / 256.f);
  enc[b * 512 + tid + 256] = a1 * (1.f / 256.f);
}

// ---------------- z = per-l linear mix of enc (B,32,16) -> (B,16,84) ----------------
__global__ __launch_bounds__(256) void k_zproj(const float* __restrict__ enc,
                                               const float* __restrict__ Wlin,
                                               float* __restrict__ z) {
  __shared__ float eL[512];
  const int b = blockIdx.x, tid = threadIdx.x;
  eL[tid] = enc[b * 512 + tid];
  eL[tid + 256] = enc[b * 512 + tid + 256];
  __syncthreads();
  for (int idx = tid; idx < 16 * 84; idx += 256) {
    const int g = idx / 84, d3 = idx % 84;
    int o0, m0, mo;
    if (d3 < 1)       { o0 = 0;  m0 = 1; mo = 0; }
    else if (d3 < 10) { o0 = 1;  m0 = 3; mo = 1; }
    else if (d3 < 35) { o0 = 10; m0 = 5; mo = 4; }
    else              { o0 = 35; m0 = 7; mo = 9; }
    const int rem = d3 - o0;
    const int jj = rem / m0;
    const int cc2 = rem - jj * m0;
    float a = 0.f;
    for (int mu = 0; mu < 32; ++mu)
      a = fmaf(eL[mu * 16 + mo + cc2], Wlin[(mu * 16 + g) * 16 + mo + jj], a);
    z[(size_t)(b * 16 + g) * 84 + d3] = a * 0.17677669529663687f;  // 1/sqrt(32)
  }
}

// ---------------- SO3 conv: per-l matmul (XCD-swizzled 1-D grid) ----------------
template <int M, int FI, int FO>
DEV void conv_item(const float* xL, const float* __restrict__ psi, int b, int g,
                   int o0, int j, float* __restrict__ out, float scale) {
  float acc[M];
#pragma unroll
  for (int c = 0; c < M; ++c) acc[c] = 0.f;
  for (int f = 0; f < FI; ++f) {
    const float* xr = &xL[f * 84 + o0];
    const float* pr = &psi[((size_t)f * FO + g) * 84 + o0 + j];
#pragma unroll
    for (int i = 0; i < M; ++i) {
      const float pv = pr[i * M];
#pragma unroll
      for (int c = 0; c < M; ++c) acc[c] = fmaf(xr[i * M + c], pv, acc[c]);
    }
  }
  float* op = &out[((size_t)b * FO + g) * 84 + o0 + j * M];
#pragma unroll
  for (int c = 0; c < M; ++c) op[c] = acc[c] * scale;
}

// Grid: NB*GB linear, id = b*GB + gb so XCD(id%8) = gb%8 (GB multiple of 8 for
// stages 2/3): all b-blocks sharing a psi g-slice land on one XCD's L2.
template <int FI, int FO>
__global__ __launch_bounds__(256) void k_conv(const float* __restrict__ x,
                                              const float* __restrict__ psi,
                                              float* __restrict__ out) {
  constexpr int GB = FO / 16;
  __shared__ float xL[FI * 84];
  const int tid = threadIdx.x;
  const int id = blockIdx.x;
  const int b = id / GB;
  const int g0 = (id % GB) * 16;
  for (int i = tid; i < FI * 84; i += 256) xL[i] = x[(size_t)b * FI * 84 + i];
  __syncthreads();
  if (tid < 16) {
    conv_item<1, FI, FO>(xL, psi, b, g0 + tid, 0, 0, out, 1.f / sqrtf((float)(FI * 1)));
  } else if (tid < 64) {
    const int q = tid - 16;
    conv_item<3, FI, FO>(xL, psi, b, g0 + q / 3, 1, q % 3, out, 1.f / sqrtf((float)(FI * 3)));
  } else if (tid < 144) {
    const int q = tid - 64;
    conv_item<5, FI, FO>(xL, psi, b, g0 + q / 5, 10, q % 5, out, 1.f / sqrtf((float)(FI * 5)));
  } else {
    const int q = tid - 144;
    conv_item<7, FI, FO>(xL, psi, b, g0 + q / 7, 35, q % 7, out, 1.f / sqrtf((float)(FI * 7)));
  }
}

// ---------------- weight prep for MFMA act ----------------
__global__ __launch_bounds__(256) void k_prep_gt(const float* __restrict__ Gt,
                                                 ushort* __restrict__ GtT) {
  const int idx = blockIdx.x * 256 + threadIdx.x;
  if (idx >= 4096 * 96) return;
  const int g = idx / 96, k = idx % 96;
  GtT[idx] = (k < 84) ? f2bf(Gt[(size_t)k * 4096 + g]) : (ushort)0;
}
__global__ __launch_bounds__(256) void k_prep_gf(const float* __restrict__ Gf,
                                                 ushort* __restrict__ GfT) {
  const int idx = blockIdx.x * 256 + threadIdx.x;
  if (idx >= 96 * 4096) return;
  const int d = idx / 4096, g = idx % 4096;
  GfT[idx] = (d < 84) ? f2bf(Gf[(size_t)g * 84 + d]) : (ushort)0;
}
__global__ __launch_bounds__(256) void k_cvtx(const float* __restrict__ x,
                                              ushort* __restrict__ Xb, int total) {
  const int idx = blockIdx.x * 256 + threadIdx.x;
  if (idx >= total) return;
  const int r = idx / 96, k = idx % 96;
  Xb[idx] = (k < 84) ? f2bf(x[(size_t)r * 84 + k]) : (ushort)0;
}

// ---------------- SO3 act via bf16 MFMA (fused, g-split partials) ----------------
// Grid: (GS, NR/128) so XCD(id%8) = gs%8 (GS multiple of 8): blocks sharing a
// Gt/Gf chunk-range colocate per XCD.
template <int GS>
__global__ __launch_bounds__(256) void k_act_mfma(
    const ushort* __restrict__ Xb, const ushort* __restrict__ GtT,
    const ushort* __restrict__ GfT, float* __restrict__ part, int NR) {
  constexpr int CPB = 64 / GS;
  __shared__ __align__(16) ushort ldsGt[64 * 104];  // [g][k pad 104]
  __shared__ __align__(16) ushort ldsH[128 * 72];   // [row][g pad 72]
  __shared__ __align__(16) ushort ldsGf[96 * 72];   // [d][g pad 72]
  const int tid = threadIdx.x;
  const int gs = blockIdx.x;
  const int row0 = blockIdx.y * 128;
  const int lane = tid & 63, wv = tid >> 6;
  const int lr = lane & 15, lg = lane >> 4;
  const int m0 = wv * 32;

  short8 a1[2][3];
#pragma unroll
  for (int mt = 0; mt < 2; ++mt)
#pragma unroll
    for (int ks = 0; ks < 3; ++ks)
      a1[mt][ks] = *(const short8*)&Xb[(size_t)(row0 + m0 + mt * 16 + lr) * 96 +
                                       ks * 32 + lg * 8];

  f32x4 acc2[6][2];
#pragma unroll
  for (int m2 = 0; m2 < 6; ++m2)
#pragma unroll
    for (int n2 = 0; n2 < 2; ++n2) {
      f32x4 zz = {0.f, 0.f, 0.f, 0.f};
      acc2[m2][n2] = zz;
    }

  for (int ch = gs * CPB; ch < (gs + 1) * CPB; ++ch) {
    const int g0 = ch * 64;
    __syncthreads();
    for (int i = tid; i < 768; i += 256) {
      const int row = i / 12, c = i % 12;
      *(uint4*)&ldsGt[row * 104 + c * 8] =
          *(const uint4*)&GtT[(size_t)(g0 + row) * 96 + c * 8];
    }
    for (int i = tid; i < 768; i += 256) {
      const int row = i / 8, c = i % 8;
      *(uint4*)&ldsGf[row * 72 + c * 8] =
          *(const uint4*)&GfT[(size_t)row * 4096 + g0 + c * 8];
    }
    __syncthreads();
#pragma unroll
    for (int n = 0; n < 4; ++n) {
      short8 b[3];
#pragma unroll
      for (int ks = 0; ks < 3; ++ks)
        b[ks] = *(const short8*)&ldsGt[(n * 16 + lr) * 104 + ks * 32 + lg * 8];
#pragma unroll
      for (int mt = 0; mt < 2; ++mt) {
        f32x4 c1 = {0.f, 0.f, 0.f, 0.f};
#pragma unroll
        for (int ks = 0; ks < 3; ++ks)
          c1 = __builtin_amdgcn_mfma_f32_16x16x32_bf16(a1[mt][ks], b[ks], c1, 0, 0, 0);
        ushort* hp = &ldsH[(m0 + mt * 16 + lg * 4) * 72 + n * 16 + lr];
#pragma unroll
        for (int i = 0; i < 4; ++i) hp[i * 72] = f2bf(fmaxf(c1[i], 0.f));
      }
    }
#pragma unroll
    for (int k2 = 0; k2 < 2; ++k2) {
      short8 bh[2];
#pragma unroll
      for (int n2 = 0; n2 < 2; ++n2)
        bh[n2] = *(const short8*)&ldsH[(m0 + n2 * 16 + lr) * 72 + k2 * 32 + lg * 8];
#pragma unroll
      for (int m2 = 0; m2 < 6; ++m2) {
        const short8 a2 = *(const short8*)&ldsGf[(m2 * 16 + lr) * 72 + k2 * 32 + lg * 8];
        acc2[m2][0] = __builtin_amdgcn_mfma_f32_16x16x32_bf16(a2, bh[0], acc2[m2][0], 0, 0, 0);
        acc2[m2][1] = __builtin_amdgcn_mfma_f32_16x16x32_bf16(a2, bh[1], acc2[m2][1], 0, 0, 0);
      }
    }
  }
#pragma unroll
  for (int m2 = 0; m2 < 6; ++m2)
#pragma unroll
    for (int n2 = 0; n2 < 2; ++n2)
#pragma unroll
      for (int i = 0; i < 4; ++i) {
        const int d = m2 * 16 + lg * 4 + i;
        if (d < 84) {
          const int r = row0 + m0 + n2 * 16 + lr;
          part[((size_t)gs * NR + r) * 84 + d] = acc2[m2][n2][i];
        }
      }
}

template <int GS>
__global__ __launch_bounds__(256) void k_act_reduce(const float* __restrict__ part,
                                                    float* __restrict__ out, int total) {
  const int i = blockIdx.x * 256 + threadIdx.x;
  if (i < total) {
    float s = part[i];
#pragma unroll
    for (int g = 1; g < GS; ++g) s += part[(size_t)g * total + i];
    out[i] = s * (1.f / (9.16515138991168f * 64.f));  // 1/(sqrt(84)*64)
  }
}

// ---------------- final: Ws2 contraction + orientation SH dot ----------------
__global__ __launch_bounds__(256) void k_final(const float* __restrict__ x,
                                               const float* __restrict__ Ws2,
                                               const float* __restrict__ orient,
                                               float* __restrict__ outp) {
  __shared__ float red[256][16];
  const int b = blockIdx.x, tid = threadIdx.x;
  const float* xr = &x[(size_t)(b * 256 + tid) * 84];
  const float* wr = &Ws2[tid * 16];
  float acc[16];
#pragma unroll
  for (int c = 0; c < 16; ++c) acc[c] = 0.f;
  acc[0] = fmaf(xr[0], wr[0], acc[0]);
#pragma unroll
  for (int i = 0; i < 3; ++i) {
    const float w = wr[1 + i];
#pragma unroll
    for (int c = 0; c < 3; ++c) acc[1 + c] = fmaf(xr[1 + i * 3 + c], w, acc[1 + c]);
  }
#pragma unroll
  for (int i = 0; i < 5; ++i) {
    const float w = wr[4 + i];
#pragma unroll
    for (int c = 0; c < 5; ++c) acc[4 + c] = fmaf(xr[10 + i * 5 + c], w, acc[4 + c]);
  }
#pragma unroll
  for (int i = 0; i < 7; ++i) {
    const float w = wr[9 + i];
#pragma unroll
    for (int c = 0; c < 7; ++c) acc[9 + c] = fmaf(xr[35 + i * 7 + c], w, acc[9 + c]);
  }
#pragma unroll
  for (int c = 0; c < 16; ++c) red[tid][c] = acc[c];
  __syncthreads();
  for (int off = 128; off > 0; off >>= 1) {
    if (tid < off)
#pragma unroll
      for (int c = 0; c < 16; ++c) red[tid][c] += red[tid + off][c];
    __syncthreads();
  }
  if (tid == 0) {
    const float aa = orient[b * 2 + 0], rr = orient[b * 2 + 1];
    float Y[16];
    real_sh_f(-sinf(aa) * cosf(rr), -sinf(aa) * sinf(rr), -cosf(aa), Y);
    const float sc1 = 1.f / 16.f;
    const float sc3 = 1.f / (16.f * 1.7320508075688772f);
    const float sc5 = 1.f / (16.f * 2.23606797749979f);
    const float sc7 = 1.f / (16.f * 2.6457513110645907f);
    float o = red[0][0] * sc1 * Y[0];
#pragma unroll
    for (int c = 1; c < 4; ++c) o += red[0][c] * sc3 * Y[c];
#pragma unroll
    for (int c = 4; c < 9; ++c) o += red[0][c] * sc5 * Y[c];
#pragma unroll
    for (int c = 9; c < 16; ++c) o += red[0][c] * sc7 * Y[c];
    outp[b] = o;
  }
}

extern "C" void kernel_launch(void* const* d_in, const int* in_sizes, int n_in,
                              void* d_out, int out_size, void* d_ws, size_t ws_size,
                              hipStream_t stream) {
  const float* node_feat = (const float*)d_in[0];
  const float* pos       = (const float*)d_in[1];
  const float* orient    = (const float*)d_in[2];
  const float* rad1_W1   = (const float*)d_in[3];
  const float* rad1_b    = (const float*)d_in[4];
  const float* rad1_W2   = (const float*)d_in[5];
  const float* rad2_W1   = (const float*)d_in[6];
  const float* rad2_b    = (const float*)d_in[7];
  const float* rad2_W2   = (const float*)d_in[8];
  const float* Wlin      = (const float*)d_in[9];
  const float* psi1      = (const float*)d_in[10];
  const float* psi2      = (const float*)d_in[11];
  const float* psi3      = (const float*)d_in[12];
  const float* G_to      = (const float*)d_in[13];
  const float* G_from    = (const float*)d_in[14];
  const float* Ws2       = (const float*)d_in[15];
  const int*   esrc      = (const int*)d_in[16];
  const int*   edst      = (const int*)d_in[17];

  float* w = (float*)d_ws;
  size_t off = 0;
  float* u_    = w + off; off += NE;
  float* cut_  = w + off; off += NE;
  float* Y_    = w + off; off += (size_t)NE * 16;
  float* t_    = w + off; off += (size_t)NE * 128;   // t1/t2; later act partials
  float* self_ = w + off; off += (size_t)NE * 128;   // msg2 self; partial overflow
  float* h1    = w + off; off += (size_t)NN * 512;   // later: GtT/GfT/Xb (bf16)
  float* h1s   = w + off; off += (size_t)NN * 16;
  float* h2    = w + off; off += (size_t)NN * 512;
  float* enc   = w + off; off += (size_t)NB * 512;
  float* z     = w + off; off += (size_t)NB * 16 * 84;
  float* xb1   = w + off; off += (size_t)NB * 256 * 84;
  float* xb2   = w + off; off += (size_t)NB * 256 * 84;
  int* cnt    = (int*)(w + off); off += NN;
  int* offs   = (int*)(w + off); off += NN + 1;
  int* cursor = (int*)(w + off); off += NN;
  int* elist  = (int*)(w + off); off += NE;
  ushort* W2Th = (ushort*)(w + off); off += 65536;   // 128x1024 bf16
  ushort* W2Tl = (ushort*)(w + off); off += 65536;
  ushort* SWh  = (ushort*)(w + off); off += 4096;    // 128x64 bf16
  ushort* SWl  = (ushort*)(w + off); off += 4096;

  // act-time reuse of dead buffers:
  float* part = t_;                 // spans t_ + self_ (both dead by act time)
  ushort* GtT = (ushort*)h1;        // 4096*96 bf16
  ushort* GfT = GtT + 4096 * 96;    // 96*4096 bf16
  ushort* Xb  = GfT + 96 * 4096;    // up to 8192*96 bf16

  hipMemsetAsync(cnt, 0, NN * sizeof(int), stream);
  k_edge_prep<<<NE / 256, 256, 0, stream>>>(pos, esrc, edst, u_, cut_, Y_, cnt);
  k_scan<<<1, 256, 0, stream>>>(cnt, offs, cursor);
  k_fill<<<NE / 256, 256, 0, stream>>>(edst, cursor, elist);

  k_prep_w2t<false><<<512, 256, 0, stream>>>(rad1_W2, W2Th, W2Tl);
  k_msg_mfma<false><<<NE / 32, 256, 0, stream>>>(u_, cut_, rad1_W1, rad1_b, W2Th, W2Tl,
                                                 nullptr, nullptr, node_feat, esrc,
                                                 t_, nullptr);
  k_gather1<<<NN, 256, 0, stream>>>(t_, Y_, offs, elist, h1, h1s);

  k_prep_w2t<true><<<512, 256, 0, stream>>>(rad2_W2, W2Th, W2Tl);
  k_prep_selfw<<<32, 256, 0, stream>>>(rad2_W2, SWh, SWl);
  k_msg_mfma<true><<<NE / 32, 256, 0, stream>>>(u_, cut_, rad2_W1, rad2_b, W2Th, W2Tl,
                                                SWh, SWl, h1s, esrc, t_, self_);
  k_gather2<<<NN, 256, 0, stream>>>(t_, self_, Y_, h1, offs, elist, esrc, h2);
  k_pool<<<NB, 256, 0, stream>>>(h2, enc);
  k_zproj<<<NB, 256, 0, stream>>>(enc, Wlin, z);

  k_prep_gt<<<(4096 * 96 + 255) / 256, 256, 0, stream>>>(G_to, GtT);
  k_prep_gf<<<(96 * 4096 + 255) / 256, 256, 0, stream>>>(G_from, GfT);

  k_conv<16, 64><<<NB * 4, 256, 0, stream>>>(z, psi1, xb1);
  k_cvtx<<<(2048 * 96 + 255) / 256, 256, 0, stream>>>(xb1, Xb, 2048 * 96);
  k_act_mfma<32><<<dim3(32, 16), 256, 0, stream>>>(Xb, GtT, GfT, part, 2048);
  k_act_reduce<32><<<(2048 * 84 + 255) / 256, 256, 0, stream>>>(part, xb2, 2048 * 84);

  k_conv<64, 128><<<NB * 8, 256, 0, stream>>>(xb2, psi2, xb1);
  k_cvtx<<<(4096 * 96 + 255) / 256, 256, 0, stream>>>(xb1, Xb, 4096 * 96);
  k_act_mfma<16><<<dim3(16, 32), 256, 0, stream>>>(Xb, GtT, GfT, part, 4096);
  k_act_reduce<16><<<(4096 * 84 + 255) / 256, 256, 0, stream>>>(part, xb2, 4096 * 84);

  k_conv<128, 256><<<NB * 16, 256, 0, stream>>>(xb2, psi3, xb1);
  k_cvtx<<<(8192 * 96 + 255) / 256, 256, 0, stream>>>(xb1, Xb, 8192 * 96);
  k_act_mfma<8><<<dim3(8, 64), 256, 0, stream>>>(Xb, GtT, GfT, part, 8192);
  k_act_reduce<8><<<(8192 * 84 + 255) / 256, 256, 0, stream>>>(part, xb2, 8192 * 84);

  k_final<<<NB, 256, 0, stream>>>(xb2, Ws2, orient, (float*)d_out);
}

// Round 9
// 430.378 us; speedup vs baseline: 2.4056x; 1.0893x over previous
//
#include <hip/hip_runtime.h>
#include <math.h>

#define DEV static __device__ __forceinline__

constexpr int NN = 8192;    // nodes
constexpr int NE = 32768;   // edges
constexpr int NB = 32;      // graphs

using short8 = __attribute__((ext_vector_type(8))) short;
using f32x4  = __attribute__((ext_vector_type(4))) float;

DEV ushort f2bf(float f) {  // round-to-nearest-even f32 -> bf16 bits
  unsigned u = __float_as_uint(f);
  unsigned r = (u + 0x7FFFu + ((u >> 16) & 1u)) >> 16;
  return (ushort)r;
}
DEV float bf2f(ushort h) { return __uint_as_float(((unsigned)h) << 16); }

// split p[8] into bf16 hi + bf16 residual
DEV void split8(const float* p, short8& hi, short8& lo) {
#pragma unroll
  for (int j = 0; j < 8; ++j) {
    const ushort h = f2bf(p[j]);
    hi[j] = (short)h;
    const float r = p[j] - bf2f(h);
    lo[j] = (short)(__float_as_uint(r) >> 16);
  }
}

DEV int lidx_of(int c) { return (c == 0) ? 0 : (c < 4) ? 1 : (c < 9) ? 2 : 3; }

DEV void real_sh_f(float x, float y, float z, float* Y) {
  const float s3  = 1.7320508075688772f;
  const float s5  = 2.23606797749979f;
  const float s15 = 3.872983346207417f;
  Y[0] = 1.f;
  Y[1] = s3 * y;  Y[2] = s3 * z;  Y[3] = s3 * x;
  Y[4] = s15 * x * y;
  Y[5] = s15 * y * z;
  Y[6] = 0.5f * s5 * (3.f * z * z - 1.f);
  Y[7] = s15 * x * z;
  Y[8] = 0.5f * s15 * (x * x - y * y);
  Y[9]  = 2.091650066335189f * y * (3.f * x * x - y * y);
  Y[10] = 10.246950765959598f * x * y * z;
  Y[11] = 1.6201851746019651f * y * (5.f * z * z - 1.f);
  Y[12] = 1.3228756555322954f * (5.f * z * z * z - 3.f * z);
  Y[13] = 1.6201851746019651f * x * (5.f * z * z - 1.f);
  Y[14] = 5.123475382979799f * (x * x - y * y) * z;
  Y[15] = 2.091650066335189f * x * (x * x - 3.f * y * y);
}

// ---------------- edge geometry: Y, u, cut + degree histogram ----------------
__global__ __launch_bounds__(256) void k_edge_prep(
    const float* __restrict__ pos, const int* __restrict__ esrc,
    const int* __restrict__ edst, float* __restrict__ u_, float* __restrict__ cut_,
    float* __restrict__ Y_, int* __restrict__ cnt) {
  const int e = blockIdx.x * 256 + threadIdx.x;
  if (e >= NE) return;
  const int s = esrc[e], t = edst[e];
  const float ex = pos[t * 3 + 0] - pos[s * 3 + 0];
  const float ey = pos[t * 3 + 1] - pos[s * 3 + 1];
  const float ez = pos[t * 3 + 2] - pos[s * 3 + 2];
  const float d = sqrtf(ex * ex + ey * ey + ez * ez) + 1e-9f;
  const float inv = 1.f / d;
  float Y[16];
  real_sh_f(ex * inv, ey * inv, ez * inv, Y);
#pragma unroll
  for (int c = 0; c < 16; ++c) Y_[(size_t)e * 16 + c] = Y[c];
  const float u = d / 3.5f;
  u_[e] = u;
  cut_[e] = (u < 1.f) ? 0.5f * (cosf(3.14159265358979323846f * u) + 1.f) : 0.f;
  atomicAdd(&cnt[t], 1);
}

// ---------------- CSR build: scan + fill ----------------
__global__ __launch_bounds__(256) void k_scan(const int* __restrict__ cnt,
                                              int* __restrict__ offs,
                                              int* __restrict__ cursor) {
  __shared__ int part[256];
  const int t = threadIdx.x;
  int s = 0;
  for (int i = 0; i < 32; ++i) s += cnt[t * 32 + i];
  part[t] = s;
  __syncthreads();
  if (t == 0) {
    int run = 0;
    for (int i = 0; i < 256; ++i) { int v = part[i]; part[i] = run; run += v; }
    offs[NN] = run;
  }
  __syncthreads();
  int run = part[t];
  for (int i = 0; i < 32; ++i) {
    const int idx = t * 32 + i;
    offs[idx] = run;
    cursor[idx] = run;
    run += cnt[idx];
  }
}

__global__ __launch_bounds__(256) void k_fill(const int* __restrict__ edst,
                                              int* __restrict__ cursor,
                                              int* __restrict__ elist) {
  const int e = blockIdx.x * 256 + threadIdx.x;
  if (e < NE) {
    const int p = atomicAdd(&cursor[edst[e]], 1);
    elist[p] = e;
  }
}

// ---------------- W2^T bf16 hi/lo prep ----------------
template <bool IS2>
__global__ __launch_bounds__(256) void k_prep_w2t(const float* __restrict__ W2,
                                                  ushort* __restrict__ Th,
                                                  ushort* __restrict__ Tl) {
  const int idx = blockIdx.x * 256 + threadIdx.x;
  if (idx >= 128 * 1024) return;
  const int o = idx >> 10, kf = idx & 1023;
  const float v = IS2 ? W2[(size_t)(kf >> 4) * 2176 + (kf & 15) * 128 + o]
                      : W2[(size_t)kf * 128 + o];
  const ushort h = f2bf(v);
  Th[idx] = h;
  Tl[idx] = (ushort)(__float_as_uint(v - bf2f(h)) >> 16);
}

__global__ __launch_bounds__(256) void k_prep_selfw(const float* __restrict__ W2,
                                                    ushort* __restrict__ Sh,
                                                    ushort* __restrict__ Sl) {
  const int idx = blockIdx.x * 256 + threadIdx.x;
  if (idx >= 128 * 64) return;
  const int o = idx >> 6, k = idx & 63;
  const float v = W2[(size_t)k * 2176 + 2048 + o];
  const ushort h = f2bf(v);
  Sh[idx] = h;
  Sl[idx] = (ushort)(__float_as_uint(v - bf2f(h)) >> 16);
}

// ---------------- per-edge bilinear GEMM via split-bf16 MFMA ----------------
template <bool IS2>
__global__ __launch_bounds__(256) void k_msg_mfma(
    const float* __restrict__ u_, const float* __restrict__ cut_,
    const float* __restrict__ W1, const float* __restrict__ bvec,
    const ushort* __restrict__ W2Th, const ushort* __restrict__ W2Tl,
    const ushort* __restrict__ SWh, const ushort* __restrict__ SWl,
    const float* __restrict__ feat16, const int* __restrict__ esrc,
    float* __restrict__ t_, float* __restrict__ self_) {
  __shared__ float hhL[32 * 65];
  __shared__ float nfL[32 * 17];
  __shared__ float uL[32], cL[32];
  __shared__ int sL[32];
  const int tid = threadIdx.x;
  const int e0 = blockIdx.x * 32;
  if (tid < 32) {
    uL[tid] = u_[e0 + tid];
    cL[tid] = cut_[e0 + tid];
    sL[tid] = esrc[e0 + tid];
  }
  __syncthreads();
  for (int i = tid; i < 32 * 64; i += 256) {
    const int e = i >> 6, k = i & 63;
    hhL[e * 65 + k] = fmaxf(fmaf(uL[e], W1[k], bvec[k]), 0.f) * cL[e];
  }
  for (int i = tid; i < 32 * 16; i += 256) {
    const int e = i >> 4, f = i & 15;
    nfL[e * 17 + f] = feat16[(size_t)sL[e] * 16 + f];
  }
  __syncthreads();

  const int lane = tid & 63, wv = tid >> 6;
  const int lr = lane & 15, lg = lane >> 4;
  const int n0 = wv * 2;

  if (IS2) {
    f32x4 sacc[2][2];
#pragma unroll
    for (int mt = 0; mt < 2; ++mt)
#pragma unroll
      for (int n = 0; n < 2; ++n) {
        f32x4 zz = {0.f, 0.f, 0.f, 0.f};
        sacc[mt][n] = zz;
      }
#pragma unroll
    for (int ks2 = 0; ks2 < 2; ++ks2) {
      short8 ash[2], asl[2];
#pragma unroll
      for (int mt = 0; mt < 2; ++mt) {
        float p[8];
        const float* hp = &hhL[(mt * 16 + lr) * 65 + ks2 * 32 + lg * 8];
#pragma unroll
        for (int j = 0; j < 8; ++j) p[j] = hp[j];
        split8(p, ash[mt], asl[mt]);
      }
#pragma unroll
      for (int n = 0; n < 2; ++n) {
        const short8 bh = *(const short8*)&SWh[((n0 + n) * 16 + lr) * 64 + ks2 * 32 + lg * 8];
        const short8 bl = *(const short8*)&SWl[((n0 + n) * 16 + lr) * 64 + ks2 * 32 + lg * 8];
#pragma unroll
        for (int mt = 0; mt < 2; ++mt) {
          sacc[mt][n] = __builtin_amdgcn_mfma_f32_16x16x32_bf16(ash[mt], bh, sacc[mt][n], 0, 0, 0);
          sacc[mt][n] = __builtin_amdgcn_mfma_f32_16x16x32_bf16(asl[mt], bh, sacc[mt][n], 0, 0, 0);
          sacc[mt][n] = __builtin_amdgcn_mfma_f32_16x16x32_bf16(ash[mt], bl, sacc[mt][n], 0, 0, 0);
        }
      }
    }
#pragma unroll
    for (int mt = 0; mt < 2; ++mt)
#pragma unroll
      for (int n = 0; n < 2; ++n)
#pragma unroll
        for (int i = 0; i < 4; ++i)
          self_[(size_t)(e0 + mt * 16 + lg * 4 + i) * 128 + (n0 + n) * 16 + lr] =
              sacc[mt][n][i] * 0.5f;
  }

  float nf8[2][8];
#pragma unroll
  for (int mt = 0; mt < 2; ++mt)
#pragma unroll
    for (int j = 0; j < 8; ++j)
      nf8[mt][j] = nfL[(mt * 16 + lr) * 17 + (lg & 1) * 8 + j];

  f32x4 acc[2][2];
#pragma unroll
  for (int mt = 0; mt < 2; ++mt)
#pragma unroll
    for (int n = 0; n < 2; ++n) {
      f32x4 zz = {0.f, 0.f, 0.f, 0.f};
      acc[mt][n] = zz;
    }

  for (int ks = 0; ks < 32; ++ks) {
    short8 ah[2], al[2];
#pragma unroll
    for (int mt = 0; mt < 2; ++mt) {
      const float hs = hhL[(mt * 16 + lr) * 65 + 2 * ks + (lg >> 1)];
      float p[8];
#pragma unroll
      for (int j = 0; j < 8; ++j) p[j] = hs * nf8[mt][j];
      split8(p, ah[mt], al[mt]);
    }
#pragma unroll
    for (int n = 0; n < 2; ++n) {
      const short8 bh = *(const short8*)&W2Th[(size_t)((n0 + n) * 16 + lr) * 1024 + ks * 32 + lg * 8];
      const short8 bl = *(const short8*)&W2Tl[(size_t)((n0 + n) * 16 + lr) * 1024 + ks * 32 + lg * 8];
#pragma unroll
      for (int mt = 0; mt < 2; ++mt) {
        acc[mt][n] = __builtin_amdgcn_mfma_f32_16x16x32_bf16(ah[mt], bh, acc[mt][n], 0, 0, 0);
        acc[mt][n] = __builtin_amdgcn_mfma_f32_16x16x32_bf16(al[mt], bh, acc[mt][n], 0, 0, 0);
        acc[mt][n] = __builtin_amdgcn_mfma_f32_16x16x32_bf16(ah[mt], bl, acc[mt][n], 0, 0, 0);
      }
    }
  }
#pragma unroll
  for (int mt = 0; mt < 2; ++mt)
#pragma unroll
    for (int n = 0; n < 2; ++n)
#pragma unroll
      for (int i = 0; i < 4; ++i)
        t_[(size_t)(e0 + mt * 16 + lg * 4 + i) * 128 + (n0 + n) * 16 + lr] =
            acc[mt][n][i] * 0.125f;  // 1/sqrt(F)/deg
}

// ---------------- gather (segment sum over incoming edges) + gate ----------------
__global__ __launch_bounds__(256) void k_gather1(
    const float* __restrict__ t_, const float* __restrict__ Y_,
    const int* __restrict__ offs, const int* __restrict__ elist,
    float* __restrict__ h1, float* __restrict__ h1s) {
  __shared__ float tL[128], YL[16], sG[32];
  const int n = blockIdx.x, tid = threadIdx.x;
  const int beg = offs[n], end = offs[n + 1];
  const int cc = tid & 15;
  const int lx = lidx_of(cc);
  const int o0 = ((tid >> 4) << 2) + lx;
  const int o1 = o0 + 64;
  float a0 = 0.f, a1 = 0.f;
  for (int ei = beg; ei < end; ++ei) {
    const int e = elist[ei];
    __syncthreads();
    if (tid < 128) tL[tid] = t_[(size_t)e * 128 + tid];
    else if (tid < 144) YL[tid - 128] = Y_[(size_t)e * 16 + tid - 128];
    __syncthreads();
    const float yv = YL[cc];
    a0 = fmaf(tL[o0], yv, a0);
    a1 = fmaf(tL[o1], yv, a1);
  }
  if (cc == 0) { sG[tid >> 4] = a0; sG[(tid >> 4) + 16] = a1; }
  __syncthreads();
  const float s0 = sG[tid >> 4], s1 = sG[(tid >> 4) + 16];
  const float r0 = (cc == 0) ? fmaxf(a0, 0.f) : a0 * (1.f / (1.f + expf(-s0)));
  const float r1 = (cc == 0) ? fmaxf(a1, 0.f) : a1 * (1.f / (1.f + expf(-s1)));
  h1[(size_t)n * 512 + tid] = r0;
  h1[(size_t)n * 512 + tid + 256] = r1;
  if ((tid & 31) == 0) {
    h1s[n * 16 + (tid >> 5)] = r0;
    h1s[n * 16 + (tid >> 5) + 8] = r1;
  }
}

__global__ __launch_bounds__(256) void k_gather2(
    const float* __restrict__ t_, const float* __restrict__ self_,
    const float* __restrict__ Y_, const float* __restrict__ h1,
    const int* __restrict__ offs, const int* __restrict__ elist,
    const int* __restrict__ esrc, float* __restrict__ h2) {
  __shared__ float tL[128], wL[128], YL[16], sG[32];
  const int n = blockIdx.x, tid = threadIdx.x;
  const int beg = offs[n], end = offs[n + 1];
  const int cc = tid & 15;
  const int lx = lidx_of(cc);
  const int o0 = ((tid >> 4) << 2) + lx;
  const int o1 = o0 + 64;
  float a0 = 0.f, a1 = 0.f;
  for (int ei = beg; ei < end; ++ei) {
    const int e = elist[ei];
    __syncthreads();
    if (tid < 128) tL[tid] = t_[(size_t)e * 128 + tid];
    else wL[tid - 128] = self_[(size_t)e * 128 + tid - 128];
    if (tid < 16) YL[tid] = Y_[(size_t)e * 16 + tid];
    __syncthreads();
    const int src = esrc[e];
    const float* hr = &h1[(size_t)src * 512];
    const float yv = YL[cc];
    a0 += tL[o0] * yv + hr[tid] * wL[o0];
    a1 += tL[o1] * yv + hr[tid + 256] * wL[o1];
  }
  if (cc == 0) { sG[tid >> 4] = a0; sG[(tid >> 4) + 16] = a1; }
  __syncthreads();
  const float s0 = sG[tid >> 4], s1 = sG[(tid >> 4) + 16];
  const float r0 = (cc == 0) ? fmaxf(a0, 0.f) : a0 * (1.f / (1.f + expf(-s0)));
  const float r1 = (cc == 0) ? fmaxf(a1, 0.f) : a1 * (1.f / (1.f + expf(-s1)));
  h2[(size_t)n * 512 + tid] = r0;
  h2[(size_t)n * 512 + tid + 256] = r1;
}

// ---------------- mean pool over each graph's 256 nodes ----------------
__global__ __launch_bounds__(256) void k_pool(const float* __restrict__ h2,
                                              float* __restrict__ enc) {
  const int b = blockIdx.x, tid = threadIdx.x;
  float a0 = 0.f, a1 = 0.f;
  for (int i = 0; i < 256; ++i) {
    const float* row = &h2[(size_t)(b * 256 + i) * 512];
    a0 += row[tid];
    a1 += row[tid + 256];
  }
  enc[b * 512 + tid] = a0 * (1.f / 256.f);
  enc[b * 512 + tid + 256] = a1 * (1.f / 256.f);
}

// ---------------- z = per-l linear mix of enc (B,32,16) -> (B,16,84) ----------------
__global__ __launch_bounds__(256) void k_zproj(const float* __restrict__ enc,
                                               const float* __restrict__ Wlin,
                                               float* __restrict__ z) {
  __shared__ float eL[512];
  const int b = blockIdx.x, tid = threadIdx.x;
  eL[tid] = enc[b * 512 + tid];
  eL[tid + 256] = enc[b * 512 + tid + 256];
  __syncthreads();
  for (int idx = tid; idx < 16 * 84; idx += 256) {
    const int g = idx / 84, d3 = idx % 84;
    int o0, m0, mo;
    if (d3 < 1)       { o0 = 0;  m0 = 1; mo = 0; }
    else if (d3 < 10) { o0 = 1;  m0 = 3; mo = 1; }
    else if (d3 < 35) { o0 = 10; m0 = 5; mo = 4; }
    else              { o0 = 35; m0 = 7; mo = 9; }
    const int rem = d3 - o0;
    const int jj = rem / m0;
    const int cc2 = rem - jj * m0;
    float a = 0.f;
    for (int mu = 0; mu < 32; ++mu)
      a = fmaf(eL[mu * 16 + mo + cc2], Wlin[(mu * 16 + g) * 16 + mo + jj], a);
    z[(size_t)(b * 16 + g) * 84 + d3] = a * 0.17677669529663687f;  // 1/sqrt(32)
  }
}

// ---------------- SO3 conv as split-bf16 MFMA GEMMs ----------------
// Per l: O[R=(b,c)][C=(g,j)] = sum_K A[R][K=(f,i)] * Psi[C][K], K padded to 32.
// X repack: Xp_l[r][k] (bf16 hi/lo), r=b*m+c, k=f*m+i
template <int FI>
__global__ __launch_bounds__(256) void k_prep_xg(const float* __restrict__ x,
                                                 ushort* __restrict__ Xh,
                                                 ushort* __restrict__ Xl) {
  constexpr int KP0 = (FI + 31) & ~31, KP1 = (3 * FI + 31) & ~31;
  constexpr int KP2 = (5 * FI + 31) & ~31, KP3 = (7 * FI + 31) & ~31;
  constexpr int XO1 = 32 * KP0, XO2 = XO1 + 96 * KP1, XO3 = XO2 + 160 * KP2;
  constexpr int TOT = XO3 + 224 * KP3;
  const int idx = blockIdx.x * 256 + threadIdx.x;
  if (idx >= TOT) return;
  int m, o0, base, KP;
  if (idx < XO1)      { m = 1; o0 = 0;  base = 0;   KP = KP0; }
  else if (idx < XO2) { m = 3; o0 = 1;  base = XO1; KP = KP1; }
  else if (idx < XO3) { m = 5; o0 = 10; base = XO2; KP = KP2; }
  else                { m = 7; o0 = 35; base = XO3; KP = KP3; }
  const int rel = idx - base;
  const int r = rel / KP, k = rel % KP;
  ushort h = 0, lo = 0;
  if (k < FI * m) {
    const int f = k / m, i = k % m, b = r / m, c = r % m;
    const float v = x[((size_t)b * FI + f) * 84 + o0 + i * m + c];
    h = f2bf(v);
    lo = (ushort)(__float_as_uint(v - bf2f(h)) >> 16);
  }
  Xh[idx] = h;
  Xl[idx] = lo;
}

// Psi repack: Pp_l[n][k] (bf16 hi/lo), n=g*m+j, k=f*m+i
template <int FI, int FO>
__global__ __launch_bounds__(256) void k_prep_psig(const float* __restrict__ psi,
                                                   ushort* __restrict__ Ph,
                                                   ushort* __restrict__ Pl) {
  constexpr int KP0 = (FI + 31) & ~31, KP1 = (3 * FI + 31) & ~31;
  constexpr int KP2 = (5 * FI + 31) & ~31, KP3 = (7 * FI + 31) & ~31;
  constexpr int PO1 = FO * KP0, PO2 = PO1 + 3 * FO * KP1, PO3 = PO2 + 5 * FO * KP2;
  constexpr int TOT = PO3 + 7 * FO * KP3;
  const int idx = blockIdx.x * 256 + threadIdx.x;
  if (idx >= TOT) return;
  int m, o0, base, KP;
  if (idx < PO1)      { m = 1; o0 = 0;  base = 0;   KP = KP0; }
  else if (idx < PO2) { m = 3; o0 = 1;  base = PO1; KP = KP1; }
  else if (idx < PO3) { m = 5; o0 = 10; base = PO2; KP = KP2; }
  else                { m = 7; o0 = 35; base = PO3; KP = KP3; }
  const int rel = idx - base;
  const int n = rel / KP, k = rel % KP;
  ushort h = 0, lo = 0;
  if (k < FI * m) {
    const int f = k / m, i = k % m, g = n / m, j = n % m;
    const float v = psi[((size_t)f * FO + g) * 84 + o0 + i * m + j];
    h = f2bf(v);
    lo = (ushort)(__float_as_uint(v - bf2f(h)) >> 16);
  }
  Ph[idx] = h;
  Pl[idx] = lo;
}

// GEMM: waves enumerate 32x32 tiles across all l. 4 waves/block, no LDS.
template <int FI, int FO>
__global__ __launch_bounds__(256) void k_conv_gemm(
    const ushort* __restrict__ Xh, const ushort* __restrict__ Xl,
    const ushort* __restrict__ Ph, const ushort* __restrict__ Pl,
    float* __restrict__ out) {
  constexpr int KP0 = (FI + 31) & ~31, KP1 = (3 * FI + 31) & ~31;
  constexpr int KP2 = (5 * FI + 31) & ~31, KP3 = (7 * FI + 31) & ~31;
  constexpr int XO1 = 32 * KP0, XO2 = XO1 + 96 * KP1, XO3 = XO2 + 160 * KP2;
  constexpr int PO1 = FO * KP0, PO2 = PO1 + 3 * FO * KP1, PO3 = PO2 + 5 * FO * KP2;
  constexpr int NT0 = 1 * (FO / 32), NT1 = 3 * (3 * FO / 32);
  constexpr int NT2 = 5 * (5 * FO / 32), NT3 = 7 * (7 * FO / 32);
  constexpr int TB1 = NT0, TB2 = TB1 + NT1, TB3 = TB2 + NT2, TOT = TB3 + NT3;

  const int wt = blockIdx.x * 4 + (threadIdx.x >> 6);
  if (wt >= TOT) return;
  int m, o0, Mt, KP, Xo, Po, loc;
  if (wt < TB1)      { m = 1; o0 = 0;  Mt = 1; KP = KP0; Xo = 0;   Po = 0;   loc = wt; }
  else if (wt < TB2) { m = 3; o0 = 1;  Mt = 3; KP = KP1; Xo = XO1; Po = PO1; loc = wt - TB1; }
  else if (wt < TB3) { m = 5; o0 = 10; Mt = 5; KP = KP2; Xo = XO2; Po = PO2; loc = wt - TB2; }
  else               { m = 7; o0 = 35; Mt = 7; KP = KP3; Xo = XO3; Po = PO3; loc = wt - TB3; }
  const int mt0 = (loc % Mt) * 32;
  const int nt0 = (loc / Mt) * 32;
  const int lane = threadIdx.x & 63, lr = lane & 15, lg = lane >> 4;

  f32x4 acc[2][2];
#pragma unroll
  for (int mt = 0; mt < 2; ++mt)
#pragma unroll
    for (int nt = 0; nt < 2; ++nt) {
      f32x4 zz = {0.f, 0.f, 0.f, 0.f};
      acc[mt][nt] = zz;
    }

  const int nks = KP >> 5;
  for (int ks = 0; ks < nks; ++ks) {
    short8 ah[2], al[2], bh[2], bl[2];
#pragma unroll
    for (int t = 0; t < 2; ++t) {
      const size_t xa = (size_t)Xo + (size_t)(mt0 + t * 16 + lr) * KP + ks * 32 + lg * 8;
      ah[t] = *(const short8*)&Xh[xa];
      al[t] = *(const short8*)&Xl[xa];
      const size_t pa = (size_t)Po + (size_t)(nt0 + t * 16 + lr) * KP + ks * 32 + lg * 8;
      bh[t] = *(const short8*)&Ph[pa];
      bl[t] = *(const short8*)&Pl[pa];
    }
#pragma unroll
    for (int nt = 0; nt < 2; ++nt)
#pragma unroll
      for (int mt = 0; mt < 2; ++mt) {
        acc[mt][nt] = __builtin_amdgcn_mfma_f32_16x16x32_bf16(ah[mt], bh[nt], acc[mt][nt], 0, 0, 0);
        acc[mt][nt] = __builtin_amdgcn_mfma_f32_16x16x32_bf16(al[mt], bh[nt], acc[mt][nt], 0, 0, 0);
        acc[mt][nt] = __builtin_amdgcn_mfma_f32_16x16x32_bf16(ah[mt], bl[nt], acc[mt][nt], 0, 0, 0);
      }
  }

  const float scale = 1.f / sqrtf((float)(FI * m));
#pragma unroll
  for (int mt = 0; mt < 2; ++mt)
#pragma unroll
    for (int nt = 0; nt < 2; ++nt)
#pragma unroll
      for (int i = 0; i < 4; ++i) {
        const int R = mt0 + mt * 16 + lg * 4 + i;
        const int C2 = nt0 + nt * 16 + lr;
        const int b = R / m, c = R - b * m;
        const int g = C2 / m, j = C2 - g * m;
        out[((size_t)b * FO + g) * 84 + o0 + j * m + c] = acc[mt][nt][i] * scale;
      }
}

// ---------------- weight prep for MFMA act ----------------
__global__ __launch_bounds__(256) void k_prep_gt(const float* __restrict__ Gt,
                                                 ushort* __restrict__ GtT) {
  const int idx = blockIdx.x * 256 + threadIdx.x;
  if (idx >= 4096 * 96) return;
  const int g = idx / 96, k = idx % 96;
  GtT[idx] = (k < 84) ? f2bf(Gt[(size_t)k * 4096 + g]) : (ushort)0;
}
__global__ __launch_bounds__(256) void k_prep_gf(const float* __restrict__ Gf,
                                                 ushort* __restrict__ GfT) {
  const int idx = blockIdx.x * 256 + threadIdx.x;
  if (idx >= 96 * 4096) return;
  const int d = idx / 4096, g = idx % 4096;
  GfT[idx] = (d < 84) ? f2bf(Gf[(size_t)g * 84 + d]) : (ushort)0;
}
__global__ __launch_bounds__(256) void k_cvtx(const float* __restrict__ x,
                                              ushort* __restrict__ Xb, int total) {
  const int idx = blockIdx.x * 256 + threadIdx.x;
  if (idx >= total) return;
  const int r = idx / 96, k = idx % 96;
  Xb[idx] = (k < 84) ? f2bf(x[(size_t)r * 84 + k]) : (ushort)0;
}

// ---------------- SO3 act via bf16 MFMA (fused, g-split partials) ----------------
template <int GS>
__global__ __launch_bounds__(256) void k_act_mfma(
    const ushort* __restrict__ Xb, const ushort* __restrict__ GtT,
    const ushort* __restrict__ GfT, float* __restrict__ part, int NR) {
  constexpr int CPB = 64 / GS;
  __shared__ __align__(16) ushort ldsGt[64 * 104];
  __shared__ __align__(16) ushort ldsH[128 * 72];
  __shared__ __align__(16) ushort ldsGf[96 * 72];
  const int tid = threadIdx.x;
  const int gs = blockIdx.x;
  const int row0 = blockIdx.y * 128;
  const int lane = tid & 63, wv = tid >> 6;
  const int lr = lane & 15, lg = lane >> 4;
  const int m0 = wv * 32;

  short8 a1[2][3];
#pragma unroll
  for (int mt = 0; mt < 2; ++mt)
#pragma unroll
    for (int ks = 0; ks < 3; ++ks)
      a1[mt][ks] = *(const short8*)&Xb[(size_t)(row0 + m0 + mt * 16 + lr) * 96 +
                                       ks * 32 + lg * 8];

  f32x4 acc2[6][2];
#pragma unroll
  for (int m2 = 0; m2 < 6; ++m2)
#pragma unroll
    for (int n2 = 0; n2 < 2; ++n2) {
      f32x4 zz = {0.f, 0.f, 0.f, 0.f};
      acc2[m2][n2] = zz;
    }

  for (int ch = gs * CPB; ch < (gs + 1) * CPB; ++ch) {
    const int g0 = ch * 64;
    __syncthreads();
    for (int i = tid; i < 768; i += 256) {
      const int row = i / 12, c = i % 12;
      *(uint4*)&ldsGt[row * 104 + c * 8] =
          *(const uint4*)&GtT[(size_t)(g0 + row) * 96 + c * 8];
    }
    for (int i = tid; i < 768; i += 256) {
      const int row = i / 8, c = i % 8;
      *(uint4*)&ldsGf[row * 72 + c * 8] =
          *(const uint4*)&GfT[(size_t)row * 4096 + g0 + c * 8];
    }
    __syncthreads();
#pragma unroll
    for (int n = 0; n < 4; ++n) {
      short8 b[3];
#pragma unroll
      for (int ks = 0; ks < 3; ++ks)
        b[ks] = *(const short8*)&ldsGt[(n * 16 + lr) * 104 + ks * 32 + lg * 8];
#pragma unroll
      for (int mt = 0; mt < 2; ++mt) {
        f32x4 c1 = {0.f, 0.f, 0.f, 0.f};
#pragma unroll
        for (int ks = 0; ks < 3; ++ks)
          c1 = __builtin_amdgcn_mfma_f32_16x16x32_bf16(a1[mt][ks], b[ks], c1, 0, 0, 0);
        ushort* hp = &ldsH[(m0 + mt * 16 + lg * 4) * 72 + n * 16 + lr];
#pragma unroll
        for (int i = 0; i < 4; ++i) hp[i * 72] = f2bf(fmaxf(c1[i], 0.f));
      }
    }
#pragma unroll
    for (int k2 = 0; k2 < 2; ++k2) {
      short8 bh[2];
#pragma unroll
      for (int n2 = 0; n2 < 2; ++n2)
        bh[n2] = *(const short8*)&ldsH[(m0 + n2 * 16 + lr) * 72 + k2 * 32 + lg * 8];
#pragma unroll
      for (int m2 = 0; m2 < 6; ++m2) {
        const short8 a2 = *(const short8*)&ldsGf[(m2 * 16 + lr) * 72 + k2 * 32 + lg * 8];
        acc2[m2][0] = __builtin_amdgcn_mfma_f32_16x16x32_bf16(a2, bh[0], acc2[m2][0], 0, 0, 0);
        acc2[m2][1] = __builtin_amdgcn_mfma_f32_16x16x32_bf16(a2, bh[1], acc2[m2][1], 0, 0, 0);
      }
    }
  }
#pragma unroll
  for (int m2 = 0; m2 < 6; ++m2)
#pragma unroll
    for (int n2 = 0; n2 < 2; ++n2)
#pragma unroll
      for (int i = 0; i < 4; ++i) {
        const int d = m2 * 16 + lg * 4 + i;
        if (d < 84) {
          const int r = row0 + m0 + n2 * 16 + lr;
          part[((size_t)gs * NR + r) * 84 + d] = acc2[m2][n2][i];
        }
      }
}

template <int GS>
__global__ __launch_bounds__(256) void k_act_reduce(const float* __restrict__ part,
                                                    float* __restrict__ out, int total) {
  const int i = blockIdx.x * 256 + threadIdx.x;
  if (i < total) {
    float s = part[i];
#pragma unroll
    for (int g = 1; g < GS; ++g) s += part[(size_t)g * total + i];
    out[i] = s * (1.f / (9.16515138991168f * 64.f));
  }
}

// ---------------- final: Ws2 contraction + orientation SH dot ----------------
__global__ __launch_bounds__(256) void k_final(const float* __restrict__ x,
                                               const float* __restrict__ Ws2,
                                               const float* __restrict__ orient,
                                               float* __restrict__ outp) {
  __shared__ float red[256][16];
  const int b = blockIdx.x, tid = threadIdx.x;
  const float* xr = &x[(size_t)(b * 256 + tid) * 84];
  const float* wr = &Ws2[tid * 16];
  float acc[16];
#pragma unroll
  for (int c = 0; c < 16; ++c) acc[c] = 0.f;
  acc[0] = fmaf(xr[0], wr[0], acc[0]);
#pragma unroll
  for (int i = 0; i < 3; ++i) {
    const float w = wr[1 + i];
#pragma unroll
    for (int c = 0; c < 3; ++c) acc[1 + c] = fmaf(xr[1 + i * 3 + c], w, acc[1 + c]);
  }
#pragma unroll
  for (int i = 0; i < 5; ++i) {
    const float w = wr[4 + i];
#pragma unroll
    for (int c = 0; c < 5; ++c) acc[4 + c] = fmaf(xr[10 + i * 5 + c], w, acc[4 + c]);
  }
#pragma unroll
  for (int i = 0; i < 7; ++i) {
    const float w = wr[9 + i];
#pragma unroll
    for (int c = 0; c < 7; ++c) acc[9 + c] = fmaf(xr[35 + i * 7 + c], w, acc[9 + c]);
  }
#pragma unroll
  for (int c = 0; c < 16; ++c) red[tid][c] = acc[c];
  __syncthreads();
  for (int off = 128; off > 0; off >>= 1) {
    if (tid < off)
#pragma unroll
      for (int c = 0; c < 16; ++c) red[tid][c] += red[tid + off][c];
    __syncthreads();
  }
  if (tid == 0) {
    const float aa = orient[b * 2 + 0], rr = orient[b * 2 + 1];
    float Y[16];
    real_sh_f(-sinf(aa) * cosf(rr), -sinf(aa) * sinf(rr), -cosf(aa), Y);
    const float sc1 = 1.f / 16.f;
    const float sc3 = 1.f / (16.f * 1.7320508075688772f);
    const float sc5 = 1.f / (16.f * 2.23606797749979f);
    const float sc7 = 1.f / (16.f * 2.6457513110645907f);
    float o = red[0][0] * sc1 * Y[0];
#pragma unroll
    for (int c = 1; c < 4; ++c) o += red[0][c] * sc3 * Y[c];
#pragma unroll
    for (int c = 4; c < 9; ++c) o += red[0][c] * sc5 * Y[c];
#pragma unroll
    for (int c = 9; c < 16; ++c) o += red[0][c] * sc7 * Y[c];
    outp[b] = o;
  }
}

extern "C" void kernel_launch(void* const* d_in, const int* in_sizes, int n_in,
                              void* d_out, int out_size, void* d_ws, size_t ws_size,
                              hipStream_t stream) {
  const float* node_feat = (const float*)d_in[0];
  const float* pos       = (const float*)d_in[1];
  const float* orient    = (const float*)d_in[2];
  const float* rad1_W1   = (const float*)d_in[3];
  const float* rad1_b    = (const float*)d_in[4];
  const float* rad1_W2   = (const float*)d_in[5];
  const float* rad2_W1   = (const float*)d_in[6];
  const float* rad2_b    = (const float*)d_in[7];
  const float* rad2_W2   = (const float*)d_in[8];
  const float* Wlin      = (const float*)d_in[9];
  const float* psi1      = (const float*)d_in[10];
  const float* psi2      = (const float*)d_in[11];
  const float* psi3      = (const float*)d_in[12];
  const float* G_to      = (const float*)d_in[13];
  const float* G_from    = (const float*)d_in[14];
  const float* Ws2       = (const float*)d_in[15];
  const int*   esrc      = (const int*)d_in[16];
  const int*   edst      = (const int*)d_in[17];

  float* w = (float*)d_ws;
  size_t off = 0;
  float* u_    = w + off; off += NE;
  float* cut_  = w + off; off += NE;
  float* Y_    = w + off; off += (size_t)NE * 16;   // later: Xp hi/lo (bf16)
  float* t_    = w + off; off += (size_t)NE * 128;  // t1/t2; later act partials
  float* self_ = w + off; off += (size_t)NE * 128;
  float* h1    = w + off; off += (size_t)NN * 512;  // later: GtT/GfT/Xb (bf16)
  float* h1s   = w + off; off += (size_t)NN * 16;
  float* h2    = w + off; off += (size_t)NN * 512;  // later: Psi-p hi/lo (bf16)
  float* enc   = w + off; off += (size_t)NB * 512;
  float* z     = w + off; off += (size_t)NB * 16 * 84;
  float* xb1   = w + off; off += (size_t)NB * 256 * 84;
  float* xb2   = w + off; off += (size_t)NB * 256 * 84;
  int* cnt    = (int*)(w + off); off += NN;
  int* offs   = (int*)(w + off); off += NN + 1;
  int* cursor = (int*)(w + off); off += NN;
  int* elist  = (int*)(w + off); off += NE;
  ushort* W2Th = (ushort*)(w + off); off += 65536;
  ushort* W2Tl = (ushort*)(w + off); off += 65536;
  ushort* SWh  = (ushort*)(w + off); off += 4096;
  ushort* SWl  = (ushort*)(w + off); off += 4096;

  // reuse of dead buffers during conv/act chain:
  float* part = t_;                 // act partials (t_+self_ region, dead)
  ushort* GtT = (ushort*)h1;        // 4096*96 bf16
  ushort* GfT = GtT + 4096 * 96;
  ushort* Xb  = GfT + 96 * 4096;
  ushort* Xph = (ushort*)Y_;        // conv X repack: max 344064 elems each
  ushort* Xpl = Xph + 344064;       // (fits in Y_ = 2 MB; Y_ dead after gather2)
  ushort* Pph = (ushort*)h2;        // conv Psi repack: max 2752512 elems each
  ushort* Ppl = Pph + 2752512;      // (fits in h2 = 16 MB; h2 dead after pool)

  hipMemsetAsync(cnt, 0, NN * sizeof(int), stream);
  k_edge_prep<<<NE / 256, 256, 0, stream>>>(pos, esrc, edst, u_, cut_, Y_, cnt);
  k_scan<<<1, 256, 0, stream>>>(cnt, offs, cursor);
  k_fill<<<NE / 256, 256, 0, stream>>>(edst, cursor, elist);

  k_prep_w2t<false><<<512, 256, 0, stream>>>(rad1_W2, W2Th, W2Tl);
  k_msg_mfma<false><<<NE / 32, 256, 0, stream>>>(u_, cut_, rad1_W1, rad1_b, W2Th, W2Tl,
                                                 nullptr, nullptr, node_feat, esrc,
                                                 t_, nullptr);
  k_gather1<<<NN, 256, 0, stream>>>(t_, Y_, offs, elist, h1, h1s);

  k_prep_w2t<true><<<512, 256, 0, stream>>>(rad2_W2, W2Th, W2Tl);
  k_prep_selfw<<<32, 256, 0, stream>>>(rad2_W2, SWh, SWl);
  k_msg_mfma<true><<<NE / 32, 256, 0, stream>>>(u_, cut_, rad2_W1, rad2_b, W2Th, W2Tl,
                                                SWh, SWl, h1s, esrc, t_, self_);
  k_gather2<<<NN, 256, 0, stream>>>(t_, self_, Y_, h1, offs, elist, esrc, h2);
  k_pool<<<NB, 256, 0, stream>>>(h2, enc);
  k_zproj<<<NB, 256, 0, stream>>>(enc, Wlin, z);

  k_prep_gt<<<(4096 * 96 + 255) / 256, 256, 0, stream>>>(G_to, GtT);
  k_prep_gf<<<(96 * 4096 + 255) / 256, 256, 0, stream>>>(G_from, GfT);

  // ---- stage 1: conv(z, psi1) -> xb1 ; act -> xb2
  k_prep_psig<16, 64><<<(102400 + 255) / 256, 256, 0, stream>>>(psi1, Pph, Ppl);
  k_prep_xg<16><<<(51200 + 255) / 256, 256, 0, stream>>>(z, Xph, Xpl);
  k_conv_gemm<16, 64><<<42, 256, 0, stream>>>(Xph, Xpl, Pph, Ppl, xb1);
  k_cvtx<<<(2048 * 96 + 255) / 256, 256, 0, stream>>>(xb1, Xb, 2048 * 96);
  k_act_mfma<32><<<dim3(32, 16), 256, 0, stream>>>(Xb, GtT, GfT, part, 2048);
  k_act_reduce<32><<<(2048 * 84 + 255) / 256, 256, 0, stream>>>(part, xb2, 2048 * 84);

  // ---- stage 2
  k_prep_psig<64, 128><<<(688128 + 255) / 256, 256, 0, stream>>>(psi2, Pph, Ppl);
  k_prep_xg<64><<<(172032 + 255) / 256, 256, 0, stream>>>(xb2, Xph, Xpl);
  k_conv_gemm<64, 128><<<84, 256, 0, stream>>>(Xph, Xpl, Pph, Ppl, xb1);
  k_cvtx<<<(4096 * 96 + 255) / 256, 256, 0, stream>>>(xb1, Xb, 4096 * 96);
  k_act_mfma<16><<<dim3(16, 32), 256, 0, stream>>>(Xb, GtT, GfT, part, 4096);
  k_act_reduce<16><<<(4096 * 84 + 255) / 256, 256, 0, stream>>>(part, xb2, 4096 * 84);

  // ---- stage 3
  k_prep_psig<128, 256><<<(2752512 + 255) / 256, 256, 0, stream>>>(psi3, Pph, Ppl);
  k_prep_xg<128><<<(344064 + 255) / 256, 256, 0, stream>>>(xb2, Xph, Xpl);
  k_conv_gemm<128, 256><<<168, 256, 0, stream>>>(Xph, Xpl, Pph, Ppl, xb1);
  k_cvtx<<<(8192 * 96 + 255) / 256, 256, 0, stream>>>(xb1, Xb, 8192 * 96);
  k_act_mfma<8><<<dim3(8, 64), 256, 0, stream>>>(Xb, GtT, GfT, part, 8192);
  k_act_reduce<8><<<(8192 * 84 + 255) / 256, 256, 0, stream>>>(part, xb2, 8192 * 84);

  k_final<<<NB, 256, 0, stream>>>(xb2, Ws2, orient, (float*)d_out);
}